// Round 7
// baseline (4629.830 us; speedup 1.0000x reference)
//
#include <hip/hip_runtime.h>
#include <hip/hip_bf16.h>

#define NN 20000   // nodes
#define NE 320000  // edges
#define NB 64      // graphs
#define DIN 16
#define DE 8
#define HE 128
#define D 32
#define TST 8
#define S2S 12

typedef __attribute__((ext_vector_type(8))) short short8x;   // 8 bf16 = 4 VGPRs (MFMA A/B frag)
typedef __attribute__((ext_vector_type(4))) float f32x4;     // MFMA C/D frag

__device__ __forceinline__ float sigf(float x) { return 1.f / (1.f + expf(-x)); }

__device__ __forceinline__ void split_bf16(float x, unsigned short& hi, unsigned short& lo) {
    __hip_bfloat16 h = __float2bfloat16(x);
    hi = *(unsigned short*)&h;
    float r = x - __bfloat162float(h);
    __hip_bfloat16 l = __float2bfloat16(r);
    lo = *(unsigned short*)&l;
}

// XOR-swizzled element offset of an A-frag within a 1024-el k-row of Wt.
// unit u = eidx*4+quad (16B units); low3 ^= high3 spreads LDS bank groups.
__device__ __forceinline__ int swz_off(int eidx, int quad, int tile) {
    const int u = eidx * 4 + quad;
    const int s = u ^ ((u >> 3) & 7);
    return tile * 512 + s * 8;
}

// -------- graph segment starts: start[b] = lower_bound(batch, b), start[NB]=NN
__global__ void k_graph_start(const int* __restrict__ batch, int* __restrict__ start) {
    int b = threadIdx.x;
    if (b > NB) return;
    int lo = 0, hi = NN;
    while (lo < hi) {
        int mid = (lo + hi) >> 1;
        if (batch[mid] < b) lo = mid + 1; else hi = mid;
    }
    start[b] = lo;
}

// -------- Wt[k][swz(f,d)] = We2[k][d*32+f] (k<128), row 128 = be2; hi/lo bf16
__global__ __launch_bounds__(256) void k_prep_w(
    const float* __restrict__ We2, const float* __restrict__ be2,
    unsigned short* __restrict__ wth, unsigned short* __restrict__ wtl) {
    int idx = blockIdx.x * 256 + threadIdx.x;  // = k*1024 + f*32 + d (logical)
    if (idx >= 129 * 1024) return;
    int k = idx >> 10, rem = idx & 1023, f = rem >> 5, d = rem & 31;
    float v = (k < 128) ? We2[k * 1024 + d * 32 + f] : be2[d * 32 + f];
    unsigned short hi, lo;
    split_bf16(v, hi, lo);
    const int pos = k * 1024 + swz_off(f & 15, d >> 3, f >> 4) + (d & 7);
    wth[pos] = hi;
    wtl[pos] = lo;
}

// -------- z precompute (once; z depends only on edge_data), k-major zb[k][e]
__global__ __launch_bounds__(256) void k_prep_z(
    const float* __restrict__ ed, const float* __restrict__ We1,
    const float* __restrict__ be1, float* __restrict__ zb) {
    const int tid = threadIdx.x;
    const int e = blockIdx.x * 256 + tid;
    __shared__ float we1s[DE * HE];
    __shared__ float be1s[HE];
    for (int i = tid; i < DE * HE; i += 256) we1s[i] = We1[i];
    if (tid < HE) be1s[tid] = be1[tid];
    const float4 v0 = *(const float4*)(ed + (size_t)e * 8);
    const float4 v1 = *(const float4*)(ed + (size_t)e * 8 + 4);
    __syncthreads();
    float edr[8];
    edr[0] = v0.x; edr[1] = v0.y; edr[2] = v0.z; edr[3] = v0.w;
    edr[4] = v1.x; edr[5] = v1.y; edr[6] = v1.z; edr[7] = v1.w;
    for (int k = 0; k < 128; ++k) {
        float acc = be1s[k];
#pragma unroll
        for (int j = 0; j < 8; ++j) acc += edr[j] * we1s[j * HE + k];
        zb[(size_t)k * NE + e] = fmaxf(acc, 0.f);
    }
}

// -------- h0 = x @ W_in + b_in  (+ optional bf16 hi/lo split emit)
__global__ __launch_bounds__(256) void k_input_linear(
    const float* __restrict__ x, const float* __restrict__ Win,
    const float* __restrict__ bin, float* __restrict__ h,
    unsigned short* __restrict__ hhi, unsigned short* __restrict__ hlo) {
    int idx = blockIdx.x * 256 + threadIdx.x;  // n*32+f, grid exact
    int n = idx >> 5, f = idx & 31;
    float acc = bin[f];
#pragma unroll
    for (int d = 0; d < DIN; ++d) acc += x[n * DIN + d] * Win[d * D + f];
    h[idx] = acc;
    if (hhi) {
        unsigned short hi, lo;
        split_bf16(acc, hi, lo);
        hhi[idx] = hi;
        hlo[idx] = lo;
    }
}

// -------- MFMA msg v5: block = 256 edges (4 waves x 64 edges, 4 e-tiles).
// W(hi/lo)+z staged per 8-k chunk into 2x40KB LDS dbuf via PROVEN idiom:
// global->VGPR (issued one chunk ahead) -> ds_write_b128 -> one barrier/chunk.
// Swizzled W layout kills b128 bank conflicts. Math identical to R5 (exact).
#define CHB 40960  // per-chunk buffer: Whi 16K | Wlo 16K | z 8K
__global__ __launch_bounds__(256) void k_msg_mfma5(
    const float* __restrict__ zb,
    const unsigned short* __restrict__ wth, const unsigned short* __restrict__ wtl,
    const unsigned short* __restrict__ hhi, const unsigned short* __restrict__ hlo,
    const int* __restrict__ src, const int* __restrict__ dst,
    float* __restrict__ agg) {
    const int tid = threadIdx.x;
    const int e0 = blockIdx.x * 256;

    __shared__ __align__(16) char sW[2][CHB];

    const int lane = tid & 63;
    const int wv = tid >> 6;
    const int eidx = lane & 15;
    const int quad = lane >> 4;
    const int d0 = quad * 8;
    const int swz0 = swz_off(eidx, quad, 0);
    const int swz1 = swz_off(eidx, quad, 1);

    // prologue vmem: dst ids + B-frags (h hi/lo) for 4 e-tiles
    int dn[4];
    short8x bhi[4], blo[4];
#pragma unroll
    for (int et = 0; et < 4; ++et) {
        const int e = e0 + wv * 64 + et * 16 + eidx;
        dn[et] = dst[e];
        const size_t hb = (size_t)src[e] * 32 + d0;
        bhi[et] = *(const short8x*)(hhi + hb);
        blo[et] = *(const short8x*)(hlo + hb);
    }

    // staging registers for one chunk: W hi 4x16B, W lo 4x16B, z 2x16B
    uint4 rh[4], rl[4], rz[2];
    auto gload = [&](int c) {
        const char* gh = (const char*)wth + (size_t)c * 16384;
        const char* gl = (const char*)wtl + (size_t)c * 16384;
#pragma unroll
        for (int r = 0; r < 4; ++r) {
            rh[r] = *(const uint4*)(gh + r * 4096 + tid * 16);
            rl[r] = *(const uint4*)(gl + r * 4096 + tid * 16);
        }
#pragma unroll
        for (int r = 0; r < 2; ++r) {
            const int idx = r * 4096 + tid * 16;        // byte index in 8KB z chunk
            const int row = idx >> 10, col = idx & 1023;  // row = k-in-chunk
            rz[r] = *(const uint4*)((const char*)(zb + (size_t)(c * 8 + row) * NE + e0) + col);
        }
    };
    auto lstore = [&](int b) {
        char* p = sW[b];
#pragma unroll
        for (int r = 0; r < 4; ++r) {
            *(uint4*)(p + r * 4096 + tid * 16) = rh[r];
            *(uint4*)(p + 16384 + r * 4096 + tid * 16) = rl[r];
        }
#pragma unroll
        for (int r = 0; r < 2; ++r)
            *(uint4*)(p + 32768 + r * 4096 + tid * 16) = rz[r];
    };

    f32x4 macc[4][2];
#pragma unroll
    for (int et = 0; et < 4; ++et) {
        macc[et][0] = (f32x4){0.f, 0.f, 0.f, 0.f};
        macc[et][1] = (f32x4){0.f, 0.f, 0.f, 0.f};
    }

    gload(0);
    lstore(0);
    gload(1);          // regs hold chunk 1 entering the loop
    __syncthreads();   // buf0 visible

    for (int c = 0; c < 16; ++c) {
        const int b = c & 1;
        if (c + 1 < 16) lstore(b ^ 1);  // buf b^1 free since barrier at end of c-1
        if (c + 2 < 16) gload(c + 2);   // latency covered by compute of chunk c

        const unsigned short* whp = (const unsigned short*)sW[b];
        const unsigned short* wlp = (const unsigned short*)(sW[b] + 16384);
        const float* zp = (const float*)(sW[b] + 32768);
#pragma unroll
        for (int m = 0; m < 8; ++m) {
            float zk[4];
#pragma unroll
            for (int et = 0; et < 4; ++et) zk[et] = zp[m * 256 + wv * 64 + et * 16 + eidx];
            const int mb = m * 1024;
            const short8x fh0 = *(const short8x*)(whp + mb + swz0);
            const short8x fh1 = *(const short8x*)(whp + mb + swz1);
            const short8x fl0 = *(const short8x*)(wlp + mb + swz0);
            const short8x fl1 = *(const short8x*)(wlp + mb + swz1);
#pragma unroll
            for (int et = 0; et < 4; ++et) {
                f32x4 t0 = {0.f, 0.f, 0.f, 0.f}, t1 = {0.f, 0.f, 0.f, 0.f};
                t0 = __builtin_amdgcn_mfma_f32_16x16x32_bf16(fh0, bhi[et], t0, 0, 0, 0);
                t1 = __builtin_amdgcn_mfma_f32_16x16x32_bf16(fh1, bhi[et], t1, 0, 0, 0);
                t0 = __builtin_amdgcn_mfma_f32_16x16x32_bf16(fl0, bhi[et], t0, 0, 0, 0);
                t1 = __builtin_amdgcn_mfma_f32_16x16x32_bf16(fl1, bhi[et], t1, 0, 0, 0);
                t0 = __builtin_amdgcn_mfma_f32_16x16x32_bf16(fh0, blo[et], t0, 0, 0, 0);
                t1 = __builtin_amdgcn_mfma_f32_16x16x32_bf16(fh1, blo[et], t1, 0, 0, 0);
                macc[et][0] += zk[et] * t0;
                macc[et][1] += zk[et] * t1;
            }
        }
        __syncthreads();  // all waves done with buf b; next chunk's stores visible
    }

    {   // k = 128: be2 virtual row, z == 1; frags direct from global (once)
        const unsigned short* bh = wth + 128 * 1024;
        const unsigned short* bl = wtl + 128 * 1024;
        const short8x fh0 = *(const short8x*)(bh + swz0);
        const short8x fh1 = *(const short8x*)(bh + swz1);
        const short8x fl0 = *(const short8x*)(bl + swz0);
        const short8x fl1 = *(const short8x*)(bl + swz1);
#pragma unroll
        for (int et = 0; et < 4; ++et) {
            f32x4 t0 = {0.f, 0.f, 0.f, 0.f}, t1 = {0.f, 0.f, 0.f, 0.f};
            t0 = __builtin_amdgcn_mfma_f32_16x16x32_bf16(fh0, bhi[et], t0, 0, 0, 0);
            t1 = __builtin_amdgcn_mfma_f32_16x16x32_bf16(fh1, bhi[et], t1, 0, 0, 0);
            t0 = __builtin_amdgcn_mfma_f32_16x16x32_bf16(fl0, bhi[et], t0, 0, 0, 0);
            t1 = __builtin_amdgcn_mfma_f32_16x16x32_bf16(fl1, bhi[et], t1, 0, 0, 0);
            t0 = __builtin_amdgcn_mfma_f32_16x16x32_bf16(fh0, blo[et], t0, 0, 0, 0);
            t1 = __builtin_amdgcn_mfma_f32_16x16x32_bf16(fh1, blo[et], t1, 0, 0, 0);
            macc[et][0] += t0;
            macc[et][1] += t1;
        }
    }

    // epilogue: lane holds msg^T rows f = tile*16 + quad*4 + r, col = edge
#pragma unroll
    for (int et = 0; et < 4; ++et) {
        float* ap = agg + (size_t)dn[et] * 32 + quad * 4;
        atomicAdd(ap + 0, macc[et][0].x);
        atomicAdd(ap + 1, macc[et][0].y);
        atomicAdd(ap + 2, macc[et][0].z);
        atomicAdd(ap + 3, macc[et][0].w);
        atomicAdd(ap + 16 + 0, macc[et][1].x);
        atomicAdd(ap + 16 + 1, macc[et][1].y);
        atomicAdd(ap + 16 + 2, macc[et][1].z);
        atomicAdd(ap + 16 + 3, macc[et][1].w);
    }
}

// -------- MFMA msg v2 (fallback when zb doesn't fit): ring prefetch, z in regs
#define LDFRAG(slot, kk)                                          \
    do {                                                          \
        const unsigned short* _ph = wth + ((size_t)(kk) << 10);   \
        const unsigned short* _pl = wtl + ((size_t)(kk) << 10);   \
        ring[slot][0] = *(const short8x*)(_ph + b0);              \
        ring[slot][1] = *(const short8x*)(_ph + b1);              \
        ring[slot][2] = *(const short8x*)(_pl + b0);              \
        ring[slot][3] = *(const short8x*)(_pl + b1);              \
    } while (0)

__global__ __launch_bounds__(256) void k_msg_mfma(
    const float* __restrict__ ed, const float* __restrict__ We1,
    const float* __restrict__ be1,
    const unsigned short* __restrict__ wth, const unsigned short* __restrict__ wtl,
    const unsigned short* __restrict__ hhi, const unsigned short* __restrict__ hlo,
    const int* __restrict__ src, const int* __restrict__ dst,
    float* __restrict__ agg) {
    const int tid = threadIdx.x;
    const int e0 = blockIdx.x * 64;

    __shared__ float we1s[DE * HE];
    __shared__ float be1s[HE];

    for (int i = tid; i < DE * HE; i += 256) we1s[i] = We1[i];
    if (tid < HE) be1s[tid] = be1[tid];

    const int lane = tid & 63;
    const int wv = tid >> 6;
    const int eidx = lane & 15;
    const int quad = lane >> 4;
    const int eloc = wv * 16 + eidx;
    const int e = e0 + eloc;
    const int d0 = quad * 8;

    const int sn = src[e];
    const int dn = dst[e];

    const int b0 = swz_off(eidx, quad, 0);
    const int b1 = swz_off(eidx, quad, 1);

    const size_t hb = (size_t)sn * 32 + d0;
    const short8x bhi = *(const short8x*)(hhi + hb);
    const short8x blo = *(const short8x*)(hlo + hb);
    const float4 edv0 = *(const float4*)(ed + (size_t)e * 8);
    const float4 edv1 = *(const float4*)(ed + (size_t)e * 8 + 4);

    short8x ring[4][4];
    LDFRAG(0, 0);
    LDFRAG(1, 1);
    LDFRAG(2, 2);

    __syncthreads();

    float edr[8];
    edr[0] = edv0.x; edr[1] = edv0.y; edr[2] = edv0.z; edr[3] = edv0.w;
    edr[4] = edv1.x; edr[5] = edv1.y; edr[6] = edv1.z; edr[7] = edv1.w;
    float zreg[32];
#pragma unroll
    for (int m = 0; m < 32; ++m) {
        const int kk = (quad << 5) + m;
        float acc = be1s[kk];
#pragma unroll
        for (int j = 0; j < 8; ++j) acc += edr[j] * we1s[j * 128 + kk];
        zreg[m] = fmaxf(acc, 0.f);
    }

    f32x4 m0 = {0.f, 0.f, 0.f, 0.f}, m1 = {0.f, 0.f, 0.f, 0.f};

    for (int q = 0; q < 4; ++q) {
        const int bsrc = q * 16 + eidx;
#pragma unroll
        for (int m = 0; m < 32; ++m) {
            const int k = q * 32 + m;
            const int slot = m & 3;
            const int pslot = (m + 3) & 3;
            int kn = k + 3;
            kn = (kn > 128) ? 128 : kn;
            LDFRAG(pslot, kn);

            const float zk = __shfl(zreg[m], bsrc);

            f32x4 t0 = {0.f, 0.f, 0.f, 0.f}, t1 = {0.f, 0.f, 0.f, 0.f};
            t0 = __builtin_amdgcn_mfma_f32_16x16x32_bf16(ring[slot][0], bhi, t0, 0, 0, 0);
            t1 = __builtin_amdgcn_mfma_f32_16x16x32_bf16(ring[slot][1], bhi, t1, 0, 0, 0);
            t0 = __builtin_amdgcn_mfma_f32_16x16x32_bf16(ring[slot][2], bhi, t0, 0, 0, 0);
            t1 = __builtin_amdgcn_mfma_f32_16x16x32_bf16(ring[slot][3], bhi, t1, 0, 0, 0);
            t0 = __builtin_amdgcn_mfma_f32_16x16x32_bf16(ring[slot][0], blo, t0, 0, 0, 0);
            t1 = __builtin_amdgcn_mfma_f32_16x16x32_bf16(ring[slot][1], blo, t1, 0, 0, 0);

            m0 += zk * t0;
            m1 += zk * t1;
        }
    }
    {
        f32x4 t0 = {0.f, 0.f, 0.f, 0.f}, t1 = {0.f, 0.f, 0.f, 0.f};
        t0 = __builtin_amdgcn_mfma_f32_16x16x32_bf16(ring[0][0], bhi, t0, 0, 0, 0);
        t1 = __builtin_amdgcn_mfma_f32_16x16x32_bf16(ring[0][1], bhi, t1, 0, 0, 0);
        t0 = __builtin_amdgcn_mfma_f32_16x16x32_bf16(ring[0][2], bhi, t0, 0, 0, 0);
        t1 = __builtin_amdgcn_mfma_f32_16x16x32_bf16(ring[0][3], bhi, t1, 0, 0, 0);
        t0 = __builtin_amdgcn_mfma_f32_16x16x32_bf16(ring[0][0], blo, t0, 0, 0, 0);
        t1 = __builtin_amdgcn_mfma_f32_16x16x32_bf16(ring[0][1], blo, t1, 0, 0, 0);
        m0 += t0;
        m1 += t1;
    }

    float* ap = agg + (size_t)dn * 32 + quad * 4;
    atomicAdd(ap + 0, m0.x);
    atomicAdd(ap + 1, m0.y);
    atomicAdd(ap + 2, m0.z);
    atomicAdd(ap + 3, m0.w);
    atomicAdd(ap + 16 + 0, m1.x);
    atomicAdd(ap + 16 + 1, m1.y);
    atomicAdd(ap + 16 + 2, m1.z);
    atomicAdd(ap + 16 + 3, m1.w);
}

// -------- fallback (proven R2 path): recompute z per edge, fp32 VALU bilinear
__global__ __launch_bounds__(256) void k_msg_fused(
    const float* __restrict__ ed, const float* __restrict__ We1,
    const float* __restrict__ be1, const float* __restrict__ We2,
    const float* __restrict__ h, const int* __restrict__ src,
    const int* __restrict__ dst, float* __restrict__ agg) {
    const int tid = threadIdx.x;
    const int e0 = blockIdx.x * 64;
    __shared__ float we1s[DE * HE];
    __shared__ float be1s[HE];
    __shared__ float eds[64][9];
    __shared__ float zs[HE][64];
    __shared__ float hs[64][33];
    __shared__ float ws2s[4][1024];
    __shared__ int srcs[64];

    for (int i = tid; i < DE * HE; i += 256) we1s[i] = We1[i];
    if (tid < HE) be1s[tid] = be1[tid];
    if (tid < 64) srcs[tid] = src[e0 + tid];
    for (int i = tid; i < 64 * DE; i += 256) eds[i >> 3][i & 7] = ed[(size_t)e0 * DE + i];
    __syncthreads();

    {
        const int e = tid & 63, kb = tid >> 6;
        float edr[8];
#pragma unroll
        for (int j = 0; j < 8; ++j) edr[j] = eds[e][j];
        for (int m = 0; m < 32; ++m) {
            const int k = kb * 32 + m;
            float acc = be1s[k];
#pragma unroll
            for (int j = 0; j < 8; ++j) acc += edr[j] * we1s[j * HE + k];
            zs[k][e] = fmaxf(acc, 0.f);
        }
    }
    for (int i = tid; i < 64 * 32; i += 256) {
        const int e = i >> 5, d = i & 31;
        hs[e][d] = h[(size_t)srcs[e] * D + d];
    }
    __syncthreads();

    const int ep = tid & 31, fg = tid >> 5;
    float hr[2][32];
#pragma unroll
    for (int d = 0; d < 32; ++d) {
        hr[0][d] = hs[ep * 2][d];
        hr[1][d] = hs[ep * 2 + 1][d];
    }
    float acc[2][4];
#pragma unroll
    for (int i = 0; i < 2; ++i)
#pragma unroll
        for (int j = 0; j < 4; ++j) acc[i][j] = 0.f;

    for (int kc = 0; kc < 32; ++kc) {
        __syncthreads();
#pragma unroll
        for (int r = 0; r < 4; ++r) {
            const int idx4 = tid + 256 * r;
            const int kr = idx4 >> 8, c4 = idx4 & 255;
            *(float4*)&ws2s[kr][c4 * 4] =
                *(const float4*)(We2 + (size_t)(kc * 4 + kr) * 1024 + c4 * 4);
        }
        __syncthreads();
#pragma unroll
        for (int kk = 0; kk < 4; ++kk) {
            const int k = kc * 4 + kk;
            const float z0 = zs[k][ep * 2], z1 = zs[k][ep * 2 + 1];
#pragma unroll
            for (int d = 0; d < 32; ++d) {
                const float4 w4 = *(const float4*)&ws2s[kk][d * 32 + fg * 4];
                const float c0 = z0 * hr[0][d], c1 = z1 * hr[1][d];
                acc[0][0] += c0 * w4.x; acc[0][1] += c0 * w4.y;
                acc[0][2] += c0 * w4.z; acc[0][3] += c0 * w4.w;
                acc[1][0] += c1 * w4.x; acc[1][1] += c1 * w4.y;
                acc[1][2] += c1 * w4.z; acc[1][3] += c1 * w4.w;
            }
        }
    }
#pragma unroll
    for (int i = 0; i < 2; ++i) {
        const int e = e0 + ep * 2 + i;
        float* ap = &agg[(size_t)dst[e] * D + fg * 4];
#pragma unroll
        for (int j = 0; j < 4; ++j) atomicAdd(ap + j, acc[i][j]);
    }
}

// -------- GRU cell per node (8 nodes x 32 f per block) (+ optional split emit)
__global__ __launch_bounds__(256) void k_gru(
    const float* __restrict__ h, const float* __restrict__ agg,
    const float* __restrict__ Wroot, const float* __restrict__ bconv,
    const float* __restrict__ Wih, const float* __restrict__ Whh,
    const float* __restrict__ bih, const float* __restrict__ bhh,
    float* __restrict__ hout,
    unsigned short* __restrict__ hhi, unsigned short* __restrict__ hlo) {
    const int idx = blockIdx.x * 256 + threadIdx.x;  // grid exact: NN*D/256
    const int n = idx >> 5, f = idx & 31, nl = threadIdx.x >> 5;
    __shared__ float hsh[8][33], msh[8][33];
    const float hv = h[n * D + f];
    hsh[nl][f] = hv;
    __syncthreads();
    float m = bconv[f] + agg[n * D + f];
#pragma unroll
    for (int d = 0; d < 32; ++d) m += hsh[nl][d] * Wroot[d * D + f];
    m = fmaxf(m, 0.f);
    msh[nl][f] = m;
    __syncthreads();
    float gir = bih[f], giz = bih[D + f], gin = bih[2 * D + f];
    float ghr = bhh[f], ghz = bhh[D + f], ghn = bhh[2 * D + f];
#pragma unroll
    for (int d = 0; d < 32; ++d) {
        const float md = msh[nl][d], hd = hsh[nl][d];
        gir += md * Wih[f * D + d];
        giz += md * Wih[(D + f) * D + d];
        gin += md * Wih[(2 * D + f) * D + d];
        ghr += hd * Whh[f * D + d];
        ghz += hd * Whh[(D + f) * D + d];
        ghn += hd * Whh[(2 * D + f) * D + d];
    }
    const float r = sigf(gir + ghr);
    const float z = sigf(giz + ghz);
    const float nn2 = tanhf(gin + r * ghn);
    const float ho = (1.f - z) * nn2 + z * hv;
    hout[n * D + f] = ho;
    if (hhi) {
        unsigned short hi, lo;
        split_bf16(ho, hi, lo);
        hhi[idx] = hi;
        hlo[idx] = lo;
    }
}

// -------- one Set2Set step: LSTM cell + segment softmax attention, block = graph
__global__ __launch_bounds__(256) void k_s2s(
    const float* __restrict__ h, const int* __restrict__ start,
    float* __restrict__ qstar, float* __restrict__ hl, float* __restrict__ cl,
    const float* __restrict__ Wih, const float* __restrict__ Whh,
    const float* __restrict__ bih, const float* __restrict__ bhh,
    float* __restrict__ ebuf) {
    const int b = blockIdx.x, t = threadIdx.x;
    __shared__ float qst[64], hls[32], gates[128], qs[32];
    __shared__ float red[256];
    __shared__ float rsum[8][33];
    if (t < 64) qst[t] = qstar[b * 64 + t];
    if (t < 32) hls[t] = hl[b * 32 + t];
    __syncthreads();
    if (t < 128) {
        float g = bih[t] + bhh[t];
#pragma unroll 8
        for (int j = 0; j < 64; ++j) g += qst[j] * Wih[t * 64 + j];
#pragma unroll 8
        for (int j = 0; j < 32; ++j) g += hls[j] * Whh[t * 32 + j];
        gates[t] = g;
    }
    __syncthreads();
    if (t < 32) {  // i,f,g,o order
        const float ig = sigf(gates[t]);
        const float fg = sigf(gates[32 + t]);
        const float gg = tanhf(gates[64 + t]);
        const float og = sigf(gates[96 + t]);
        const float c = fg * cl[b * 32 + t] + ig * gg;
        const float q = og * tanhf(c);
        cl[b * 32 + t] = c;
        hl[b * 32 + t] = q;
        qstar[b * 64 + t] = q;
        qs[t] = q;
    }
    __syncthreads();
    const int s0 = start[b], s1 = start[b + 1];
    float lmax = -3.4e38f;
    for (int n = s0 + t; n < s1; n += 256) {
        const float4* hv = (const float4*)(h + (size_t)n * D);
        float e = 0.f;
#pragma unroll
        for (int u = 0; u < 8; ++u) {
            const float4 v = hv[u];
            e += v.x * qs[u * 4] + v.y * qs[u * 4 + 1] + v.z * qs[u * 4 + 2] + v.w * qs[u * 4 + 3];
        }
        ebuf[n] = e;
        lmax = fmaxf(lmax, e);
    }
    red[t] = lmax;
    __syncthreads();
    for (int s = 128; s > 0; s >>= 1) {
        if (t < s) red[t] = fmaxf(red[t], red[t + s]);
        __syncthreads();
    }
    const float smax = red[0];
    __syncthreads();
    float lsum = 0.f;
    for (int n = s0 + t; n < s1; n += 256) {
        const float w = expf(ebuf[n] - smax);
        ebuf[n] = w;
        lsum += w;
    }
    red[t] = lsum;
    __syncthreads();
    for (int s = 128; s > 0; s >>= 1) {
        if (t < s) red[t] += red[t + s];
        __syncthreads();
    }
    const float den = red[0];
    const float inv = (den > 0.f) ? 1.f / den : 0.f;
    const int fl = t & 31, sl = t >> 5;
    float racc = 0.f;
    for (int n = s0 + sl; n < s1; n += 8) racc += ebuf[n] * h[(size_t)n * D + fl];
    rsum[sl][fl] = racc;
    __syncthreads();
    if (sl == 0) {
        float rv = 0.f;
#pragma unroll
        for (int u = 0; u < 8; ++u) rv += rsum[u][fl];
        qstar[b * 64 + 32 + fl] = rv * inv;
    }
}

// -------- out = q_star @ W_out + b_out
__global__ void k_out(const float* __restrict__ qstar, const float* __restrict__ Wout,
                      const float* __restrict__ bout, float* __restrict__ out) {
    int b = threadIdx.x;
    if (b < NB) {
        float acc = bout[0];
#pragma unroll 8
        for (int j = 0; j < 64; ++j) acc += qstar[b * 64 + j] * Wout[j];
        out[b] = acc;
    }
}

extern "C" void kernel_launch(void* const* d_in, const int* in_sizes, int n_in,
                              void* d_out, int out_size, void* d_ws, size_t ws_size,
                              hipStream_t stream) {
    const float* x     = (const float*)d_in[0];
    // d_in[1] adj unused; d_in[2] T == 8 (module constant)
    const float* ed    = (const float*)d_in[3];
    const int*   edges = (const int*)d_in[4];
    const int*   batch = (const int*)d_in[5];
    const float* Wi    = (const float*)d_in[6];
    const float* bi    = (const float*)d_in[7];
    const float* We1   = (const float*)d_in[8];
    const float* be1   = (const float*)d_in[9];
    const float* We2   = (const float*)d_in[10];
    const float* be2   = (const float*)d_in[11];
    const float* Wroot = (const float*)d_in[12];
    const float* bconv = (const float*)d_in[13];
    const float* gWih  = (const float*)d_in[14];
    const float* gWhh  = (const float*)d_in[15];
    const float* gbih  = (const float*)d_in[16];
    const float* gbhh  = (const float*)d_in[17];
    const float* lWih  = (const float*)d_in[18];
    const float* lWhh  = (const float*)d_in[19];
    const float* lbih  = (const float*)d_in[20];
    const float* lbhh  = (const float*)d_in[21];
    const float* Wout  = (const float*)d_in[22];
    const float* bout  = (const float*)d_in[23];
    float* out = (float*)d_out;

    const int* srcp = edges;
    const int* dstp = edges + NE;

    char* ws = (char*)d_ws;
    size_t off = 0;
    auto alloc = [&](size_t bytes) -> char* {
        char* p = ws + off;
        off += (bytes + 255) & ~(size_t)255;
        return p;
    };
    float* hA    = (float*)alloc((size_t)NN * D * 4);
    float* hB    = (float*)alloc((size_t)NN * D * 4);
    float* agg   = (float*)alloc((size_t)NN * D * 4);
    float* ebuf  = (float*)alloc((size_t)NN * 4);
    float* qstar = (float*)alloc((size_t)NB * 64 * 4);  // qstar,hl,cl contiguous
    float* hl    = (float*)alloc((size_t)NB * 32 * 4);
    float* cl    = (float*)alloc((size_t)NB * 32 * 4);
    int*   gst   = (int*)alloc((NB + 1) * 4);
    // MFMA-path extras (~5.6 MB)
    unsigned short* hhiA = (unsigned short*)alloc((size_t)NN * D * 2);
    unsigned short* hloA = (unsigned short*)alloc((size_t)NN * D * 2);
    unsigned short* hhiB = (unsigned short*)alloc((size_t)NN * D * 2);
    unsigned short* hloB = (unsigned short*)alloc((size_t)NN * D * 2);
    unsigned short* wth  = (unsigned short*)alloc((size_t)129 * 1024 * 2);
    unsigned short* wtl  = (unsigned short*)alloc((size_t)129 * 1024 * 2);
    const size_t base_off = off;
    const bool mfma_path = (ws_size >= base_off);
    // v5 extra: precomputed z, k-major [128][NE] fp32 (~164 MB)
    float* zb = (float*)alloc((size_t)128 * NE * 4);
    const bool mfma5_path = (ws_size >= off);

    hipLaunchKernelGGL(k_graph_start, dim3(1), dim3(128), 0, stream, batch, gst);
    hipLaunchKernelGGL(k_input_linear, dim3(NN * D / 256), dim3(256), 0, stream, x, Wi, bi, hA,
                       mfma_path ? hhiA : (unsigned short*)nullptr,
                       mfma_path ? hloA : (unsigned short*)nullptr);
    if (mfma_path)
        hipLaunchKernelGGL(k_prep_w, dim3((129 * 1024 + 255) / 256), dim3(256), 0, stream,
                           We2, be2, wth, wtl);
    if (mfma5_path)
        hipLaunchKernelGGL(k_prep_z, dim3(NE / 256), dim3(256), 0, stream, ed, We1, be1, zb);
    hipMemsetAsync(qstar, 0, (size_t)(NB * 64 + NB * 32 + NB * 32) * 4, stream);

    float* hcur = hA;
    float* hnxt = hB;
    unsigned short *hhic = hhiA, *hloc = hloA, *hhin = hhiB, *hlon = hloB;
    for (int t = 0; t < TST; ++t) {
        hipMemsetAsync(agg, 0, (size_t)NN * D * 4, stream);
        if (mfma5_path)
            hipLaunchKernelGGL(k_msg_mfma5, dim3(NE / 256), dim3(256), 0, stream,
                               zb, wth, wtl, hhic, hloc, srcp, dstp, agg);
        else if (mfma_path)
            hipLaunchKernelGGL(k_msg_mfma, dim3(NE / 64), dim3(256), 0, stream,
                               ed, We1, be1, wth, wtl, hhic, hloc, srcp, dstp, agg);
        else
            hipLaunchKernelGGL(k_msg_fused, dim3(NE / 64), dim3(256), 0, stream,
                               ed, We1, be1, We2, hcur, srcp, dstp, agg);
        hipLaunchKernelGGL(k_gru, dim3(NN * D / 256), dim3(256), 0, stream,
                           hcur, agg, Wroot, bconv, gWih, gWhh, gbih, gbhh, hnxt,
                           mfma_path ? hhin : (unsigned short*)nullptr,
                           mfma_path ? hlon : (unsigned short*)nullptr);
        float* tf = hcur; hcur = hnxt; hnxt = tf;
        unsigned short* ts;
        ts = hhic; hhic = hhin; hhin = ts;
        ts = hloc; hloc = hlon; hlon = ts;
    }

    for (int s = 0; s < S2S; ++s)
        hipLaunchKernelGGL(k_s2s, dim3(NB), dim3(256), 0, stream,
                           hcur, gst, qstar, hl, cl, lWih, lWhh, lbih, lbhh, ebuf);

    hipLaunchKernelGGL(k_out, dim3(1), dim3(64), 0, stream, qstar, Wout, bout, out);
    (void)in_sizes; (void)n_in; (void)out_size;
}

// Round 8
// 3486.565 us; speedup vs baseline: 1.3279x; 1.3279x over previous
//
#include <hip/hip_runtime.h>
#include <hip/hip_bf16.h>

#define NN 20000   // nodes
#define NE 320000  // edges
#define NB 64      // graphs
#define DIN 16
#define DE 8
#define HE 128
#define D 32
#define TST 8
#define S2S 12

typedef __attribute__((ext_vector_type(8))) short short8x;   // 8 bf16 = 4 VGPRs (MFMA A/B frag)
typedef __attribute__((ext_vector_type(4))) float f32x4;     // MFMA C/D frag

__device__ __forceinline__ float sigf(float x) { return 1.f / (1.f + expf(-x)); }

__device__ __forceinline__ void split_bf16(float x, unsigned short& hi, unsigned short& lo) {
    __hip_bfloat16 h = __float2bfloat16(x);
    hi = *(unsigned short*)&h;
    float r = x - __bfloat162float(h);
    __hip_bfloat16 l = __float2bfloat16(r);
    lo = *(unsigned short*)&l;
}

// XOR-swizzled element offset of an A-frag within a 1024-el k-row of Wt.
// unit u = eidx*4+quad (16B units); low3 ^= high3 spreads LDS bank groups.
__device__ __forceinline__ int swz_off(int eidx, int quad, int tile) {
    const int u = eidx * 4 + quad;
    const int s = u ^ ((u >> 3) & 7);
    return tile * 512 + s * 8;
}

// -------- graph segment starts: start[b] = lower_bound(batch, b), start[NB]=NN
__global__ void k_graph_start(const int* __restrict__ batch, int* __restrict__ start) {
    int b = threadIdx.x;
    if (b > NB) return;
    int lo = 0, hi = NN;
    while (lo < hi) {
        int mid = (lo + hi) >> 1;
        if (batch[mid] < b) lo = mid + 1; else hi = mid;
    }
    start[b] = lo;
}

// -------- Wt[k][swz(f,d)] = We2[k][d*32+f] (k<128), row 128 = be2; hi/lo bf16
__global__ __launch_bounds__(256) void k_prep_w(
    const float* __restrict__ We2, const float* __restrict__ be2,
    unsigned short* __restrict__ wth, unsigned short* __restrict__ wtl) {
    int idx = blockIdx.x * 256 + threadIdx.x;  // = k*1024 + f*32 + d (logical)
    if (idx >= 129 * 1024) return;
    int k = idx >> 10, rem = idx & 1023, f = rem >> 5, d = rem & 31;
    float v = (k < 128) ? We2[k * 1024 + d * 32 + f] : be2[d * 32 + f];
    unsigned short hi, lo;
    split_bf16(v, hi, lo);
    const int pos = k * 1024 + swz_off(f & 15, d >> 3, f >> 4) + (d & 7);
    wth[pos] = hi;
    wtl[pos] = lo;
}

// -------- z precompute (once; z depends only on edge_data), k-major zb[k][e]
__global__ __launch_bounds__(256) void k_prep_z(
    const float* __restrict__ ed, const float* __restrict__ We1,
    const float* __restrict__ be1, float* __restrict__ zb) {
    const int tid = threadIdx.x;
    const int e = blockIdx.x * 256 + tid;
    __shared__ float we1s[DE * HE];
    __shared__ float be1s[HE];
    for (int i = tid; i < DE * HE; i += 256) we1s[i] = We1[i];
    if (tid < HE) be1s[tid] = be1[tid];
    const float4 v0 = *(const float4*)(ed + (size_t)e * 8);
    const float4 v1 = *(const float4*)(ed + (size_t)e * 8 + 4);
    __syncthreads();
    float edr[8];
    edr[0] = v0.x; edr[1] = v0.y; edr[2] = v0.z; edr[3] = v0.w;
    edr[4] = v1.x; edr[5] = v1.y; edr[6] = v1.z; edr[7] = v1.w;
    for (int k = 0; k < 128; ++k) {
        float acc = be1s[k];
#pragma unroll
        for (int j = 0; j < 8; ++j) acc += edr[j] * we1s[j * HE + k];
        zb[(size_t)k * NE + e] = fmaxf(acc, 0.f);
    }
}

// -------- h0 = x @ W_in + b_in  (+ optional bf16 hi/lo split emit)
__global__ __launch_bounds__(256) void k_input_linear(
    const float* __restrict__ x, const float* __restrict__ Win,
    const float* __restrict__ bin, float* __restrict__ h,
    unsigned short* __restrict__ hhi, unsigned short* __restrict__ hlo) {
    int idx = blockIdx.x * 256 + threadIdx.x;  // n*32+f, grid exact
    int n = idx >> 5, f = idx & 31;
    float acc = bin[f];
#pragma unroll
    for (int d = 0; d < DIN; ++d) acc += x[n * DIN + d] * Win[d * D + f];
    h[idx] = acc;
    if (hhi) {
        unsigned short hi, lo;
        split_bf16(acc, hi, lo);
        hhi[idx] = hi;
        hlo[idx] = lo;
    }
}

// -------- MFMA msg v6: same proven pipeline as v5 (R7, exact), but 4-k chunks
// (20 KB/chunk, 40 KB dbuf) + launch_bounds(256,3) => 3 blocks/CU co-resident.
#define CHB 20480  // per-chunk buffer: Whi 8K | Wlo 8K | z 4K
__global__ __launch_bounds__(256, 3) void k_msg_mfma6(
    const float* __restrict__ zb,
    const unsigned short* __restrict__ wth, const unsigned short* __restrict__ wtl,
    const unsigned short* __restrict__ hhi, const unsigned short* __restrict__ hlo,
    const int* __restrict__ src, const int* __restrict__ dst,
    float* __restrict__ agg) {
    const int tid = threadIdx.x;
    const int e0 = blockIdx.x * 256;

    __shared__ __align__(16) char sW[2][CHB];

    const int lane = tid & 63;
    const int wv = tid >> 6;
    const int eidx = lane & 15;
    const int quad = lane >> 4;
    const int d0 = quad * 8;
    const int swz0 = swz_off(eidx, quad, 0);
    const int swz1 = swz_off(eidx, quad, 1);

    // prologue vmem: dst ids + B-frags (h hi/lo) for 4 e-tiles
    int dn[4];
    short8x bhi[4], blo[4];
#pragma unroll
    for (int et = 0; et < 4; ++et) {
        const int e = e0 + wv * 64 + et * 16 + eidx;
        dn[et] = dst[e];
        const size_t hb = (size_t)src[e] * 32 + d0;
        bhi[et] = *(const short8x*)(hhi + hb);
        blo[et] = *(const short8x*)(hlo + hb);
    }

    // staging registers for one 4-k chunk: W hi 2x16B, W lo 2x16B, z 1x16B
    uint4 rh[2], rl[2], rz;
    auto gload = [&](int c) {
        const char* gh = (const char*)wth + (size_t)c * 8192;
        const char* gl = (const char*)wtl + (size_t)c * 8192;
#pragma unroll
        for (int r = 0; r < 2; ++r) {
            rh[r] = *(const uint4*)(gh + r * 4096 + tid * 16);
            rl[r] = *(const uint4*)(gl + r * 4096 + tid * 16);
        }
        {
            const int idx = tid * 16;                     // byte index in 4KB z chunk
            const int row = idx >> 10, col = idx & 1023;  // row = k-in-chunk
            rz = *(const uint4*)((const char*)(zb + (size_t)(c * 4 + row) * NE + e0) + col);
        }
    };
    auto lstore = [&](int b) {
        char* p = sW[b];
#pragma unroll
        for (int r = 0; r < 2; ++r) {
            *(uint4*)(p + r * 4096 + tid * 16) = rh[r];
            *(uint4*)(p + 8192 + r * 4096 + tid * 16) = rl[r];
        }
        *(uint4*)(p + 16384 + tid * 16) = rz;
    };

    f32x4 macc[4][2];
#pragma unroll
    for (int et = 0; et < 4; ++et) {
        macc[et][0] = (f32x4){0.f, 0.f, 0.f, 0.f};
        macc[et][1] = (f32x4){0.f, 0.f, 0.f, 0.f};
    }

    gload(0);
    lstore(0);
    gload(1);          // regs hold chunk 1 entering the loop
    __syncthreads();   // buf0 visible

    for (int c = 0; c < 32; ++c) {
        const int b = c & 1;
        if (c + 1 < 32) lstore(b ^ 1);  // buf b^1 free since barrier at end of c-1
        if (c + 2 < 32) gload(c + 2);   // latency covered by compute of chunk c

        const unsigned short* whp = (const unsigned short*)sW[b];
        const unsigned short* wlp = (const unsigned short*)(sW[b] + 8192);
        const float* zp = (const float*)(sW[b] + 16384);
#pragma unroll
        for (int m = 0; m < 4; ++m) {
            float zk[4];
#pragma unroll
            for (int et = 0; et < 4; ++et) zk[et] = zp[m * 256 + wv * 64 + et * 16 + eidx];
            const int mb = m * 1024;
            const short8x fh0 = *(const short8x*)(whp + mb + swz0);
            const short8x fh1 = *(const short8x*)(whp + mb + swz1);
            const short8x fl0 = *(const short8x*)(wlp + mb + swz0);
            const short8x fl1 = *(const short8x*)(wlp + mb + swz1);
#pragma unroll
            for (int et = 0; et < 4; ++et) {
                f32x4 t0 = {0.f, 0.f, 0.f, 0.f}, t1 = {0.f, 0.f, 0.f, 0.f};
                t0 = __builtin_amdgcn_mfma_f32_16x16x32_bf16(fh0, bhi[et], t0, 0, 0, 0);
                t1 = __builtin_amdgcn_mfma_f32_16x16x32_bf16(fh1, bhi[et], t1, 0, 0, 0);
                t0 = __builtin_amdgcn_mfma_f32_16x16x32_bf16(fl0, bhi[et], t0, 0, 0, 0);
                t1 = __builtin_amdgcn_mfma_f32_16x16x32_bf16(fl1, bhi[et], t1, 0, 0, 0);
                t0 = __builtin_amdgcn_mfma_f32_16x16x32_bf16(fh0, blo[et], t0, 0, 0, 0);
                t1 = __builtin_amdgcn_mfma_f32_16x16x32_bf16(fh1, blo[et], t1, 0, 0, 0);
                macc[et][0] += zk[et] * t0;
                macc[et][1] += zk[et] * t1;
            }
        }
        __syncthreads();  // all waves done with buf b; next chunk's stores visible
    }

    {   // k = 128: be2 virtual row, z == 1; frags direct from global (once)
        const unsigned short* bh = wth + 128 * 1024;
        const unsigned short* bl = wtl + 128 * 1024;
        const short8x fh0 = *(const short8x*)(bh + swz0);
        const short8x fh1 = *(const short8x*)(bh + swz1);
        const short8x fl0 = *(const short8x*)(bl + swz0);
        const short8x fl1 = *(const short8x*)(bl + swz1);
#pragma unroll
        for (int et = 0; et < 4; ++et) {
            f32x4 t0 = {0.f, 0.f, 0.f, 0.f}, t1 = {0.f, 0.f, 0.f, 0.f};
            t0 = __builtin_amdgcn_mfma_f32_16x16x32_bf16(fh0, bhi[et], t0, 0, 0, 0);
            t1 = __builtin_amdgcn_mfma_f32_16x16x32_bf16(fh1, bhi[et], t1, 0, 0, 0);
            t0 = __builtin_amdgcn_mfma_f32_16x16x32_bf16(fl0, bhi[et], t0, 0, 0, 0);
            t1 = __builtin_amdgcn_mfma_f32_16x16x32_bf16(fl1, bhi[et], t1, 0, 0, 0);
            t0 = __builtin_amdgcn_mfma_f32_16x16x32_bf16(fh0, blo[et], t0, 0, 0, 0);
            t1 = __builtin_amdgcn_mfma_f32_16x16x32_bf16(fh1, blo[et], t1, 0, 0, 0);
            macc[et][0] += t0;
            macc[et][1] += t1;
        }
    }

    // epilogue: lane holds msg^T rows f = tile*16 + quad*4 + r, col = edge
#pragma unroll
    for (int et = 0; et < 4; ++et) {
        float* ap = agg + (size_t)dn[et] * 32 + quad * 4;
        atomicAdd(ap + 0, macc[et][0].x);
        atomicAdd(ap + 1, macc[et][0].y);
        atomicAdd(ap + 2, macc[et][0].z);
        atomicAdd(ap + 3, macc[et][0].w);
        atomicAdd(ap + 16 + 0, macc[et][1].x);
        atomicAdd(ap + 16 + 1, macc[et][1].y);
        atomicAdd(ap + 16 + 2, macc[et][1].z);
        atomicAdd(ap + 16 + 3, macc[et][1].w);
    }
}

// -------- MFMA msg v2 (fallback when zb doesn't fit): ring prefetch, z in regs
#define LDFRAG(slot, kk)                                          \
    do {                                                          \
        const unsigned short* _ph = wth + ((size_t)(kk) << 10);   \
        const unsigned short* _pl = wtl + ((size_t)(kk) << 10);   \
        ring[slot][0] = *(const short8x*)(_ph + b0);              \
        ring[slot][1] = *(const short8x*)(_ph + b1);              \
        ring[slot][2] = *(const short8x*)(_pl + b0);              \
        ring[slot][3] = *(const short8x*)(_pl + b1);              \
    } while (0)

__global__ __launch_bounds__(256) void k_msg_mfma(
    const float* __restrict__ ed, const float* __restrict__ We1,
    const float* __restrict__ be1,
    const unsigned short* __restrict__ wth, const unsigned short* __restrict__ wtl,
    const unsigned short* __restrict__ hhi, const unsigned short* __restrict__ hlo,
    const int* __restrict__ src, const int* __restrict__ dst,
    float* __restrict__ agg) {
    const int tid = threadIdx.x;
    const int e0 = blockIdx.x * 64;

    __shared__ float we1s[DE * HE];
    __shared__ float be1s[HE];

    for (int i = tid; i < DE * HE; i += 256) we1s[i] = We1[i];
    if (tid < HE) be1s[tid] = be1[tid];

    const int lane = tid & 63;
    const int wv = tid >> 6;
    const int eidx = lane & 15;
    const int quad = lane >> 4;
    const int eloc = wv * 16 + eidx;
    const int e = e0 + eloc;
    const int d0 = quad * 8;

    const int sn = src[e];
    const int dn = dst[e];

    const int b0 = swz_off(eidx, quad, 0);
    const int b1 = swz_off(eidx, quad, 1);

    const size_t hb = (size_t)sn * 32 + d0;
    const short8x bhi = *(const short8x*)(hhi + hb);
    const short8x blo = *(const short8x*)(hlo + hb);
    const float4 edv0 = *(const float4*)(ed + (size_t)e * 8);
    const float4 edv1 = *(const float4*)(ed + (size_t)e * 8 + 4);

    short8x ring[4][4];
    LDFRAG(0, 0);
    LDFRAG(1, 1);
    LDFRAG(2, 2);

    __syncthreads();

    float edr[8];
    edr[0] = edv0.x; edr[1] = edv0.y; edr[2] = edv0.z; edr[3] = edv0.w;
    edr[4] = edv1.x; edr[5] = edv1.y; edr[6] = edv1.z; edr[7] = edv1.w;
    float zreg[32];
#pragma unroll
    for (int m = 0; m < 32; ++m) {
        const int kk = (quad << 5) + m;
        float acc = be1s[kk];
#pragma unroll
        for (int j = 0; j < 8; ++j) acc += edr[j] * we1s[j * 128 + kk];
        zreg[m] = fmaxf(acc, 0.f);
    }

    f32x4 m0 = {0.f, 0.f, 0.f, 0.f}, m1 = {0.f, 0.f, 0.f, 0.f};

    for (int q = 0; q < 4; ++q) {
        const int bsrc = q * 16 + eidx;
#pragma unroll
        for (int m = 0; m < 32; ++m) {
            const int k = q * 32 + m;
            const int slot = m & 3;
            const int pslot = (m + 3) & 3;
            int kn = k + 3;
            kn = (kn > 128) ? 128 : kn;
            LDFRAG(pslot, kn);

            const float zk = __shfl(zreg[m], bsrc);

            f32x4 t0 = {0.f, 0.f, 0.f, 0.f}, t1 = {0.f, 0.f, 0.f, 0.f};
            t0 = __builtin_amdgcn_mfma_f32_16x16x32_bf16(ring[slot][0], bhi, t0, 0, 0, 0);
            t1 = __builtin_amdgcn_mfma_f32_16x16x32_bf16(ring[slot][1], bhi, t1, 0, 0, 0);
            t0 = __builtin_amdgcn_mfma_f32_16x16x32_bf16(ring[slot][2], bhi, t0, 0, 0, 0);
            t1 = __builtin_amdgcn_mfma_f32_16x16x32_bf16(ring[slot][3], bhi, t1, 0, 0, 0);
            t0 = __builtin_amdgcn_mfma_f32_16x16x32_bf16(ring[slot][0], blo, t0, 0, 0, 0);
            t1 = __builtin_amdgcn_mfma_f32_16x16x32_bf16(ring[slot][1], blo, t1, 0, 0, 0);

            m0 += zk * t0;
            m1 += zk * t1;
        }
    }
    {
        f32x4 t0 = {0.f, 0.f, 0.f, 0.f}, t1 = {0.f, 0.f, 0.f, 0.f};
        t0 = __builtin_amdgcn_mfma_f32_16x16x32_bf16(ring[0][0], bhi, t0, 0, 0, 0);
        t1 = __builtin_amdgcn_mfma_f32_16x16x32_bf16(ring[0][1], bhi, t1, 0, 0, 0);
        t0 = __builtin_amdgcn_mfma_f32_16x16x32_bf16(ring[0][2], bhi, t0, 0, 0, 0);
        t1 = __builtin_amdgcn_mfma_f32_16x16x32_bf16(ring[0][3], bhi, t1, 0, 0, 0);
        t0 = __builtin_amdgcn_mfma_f32_16x16x32_bf16(ring[0][0], blo, t0, 0, 0, 0);
        t1 = __builtin_amdgcn_mfma_f32_16x16x32_bf16(ring[0][1], blo, t1, 0, 0, 0);
        m0 += t0;
        m1 += t1;
    }

    float* ap = agg + (size_t)dn * 32 + quad * 4;
    atomicAdd(ap + 0, m0.x);
    atomicAdd(ap + 1, m0.y);
    atomicAdd(ap + 2, m0.z);
    atomicAdd(ap + 3, m0.w);
    atomicAdd(ap + 16 + 0, m1.x);
    atomicAdd(ap + 16 + 1, m1.y);
    atomicAdd(ap + 16 + 2, m1.z);
    atomicAdd(ap + 16 + 3, m1.w);
}

// -------- fallback (proven R2 path): recompute z per edge, fp32 VALU bilinear
__global__ __launch_bounds__(256) void k_msg_fused(
    const float* __restrict__ ed, const float* __restrict__ We1,
    const float* __restrict__ be1, const float* __restrict__ We2,
    const float* __restrict__ h, const int* __restrict__ src,
    const int* __restrict__ dst, float* __restrict__ agg) {
    const int tid = threadIdx.x;
    const int e0 = blockIdx.x * 64;
    __shared__ float we1s[DE * HE];
    __shared__ float be1s[HE];
    __shared__ float eds[64][9];
    __shared__ float zs[HE][64];
    __shared__ float hs[64][33];
    __shared__ float ws2s[4][1024];
    __shared__ int srcs[64];

    for (int i = tid; i < DE * HE; i += 256) we1s[i] = We1[i];
    if (tid < HE) be1s[tid] = be1[tid];
    if (tid < 64) srcs[tid] = src[e0 + tid];
    for (int i = tid; i < 64 * DE; i += 256) eds[i >> 3][i & 7] = ed[(size_t)e0 * DE + i];
    __syncthreads();

    {
        const int e = tid & 63, kb = tid >> 6;
        float edr[8];
#pragma unroll
        for (int j = 0; j < 8; ++j) edr[j] = eds[e][j];
        for (int m = 0; m < 32; ++m) {
            const int k = kb * 32 + m;
            float acc = be1s[k];
#pragma unroll
            for (int j = 0; j < 8; ++j) acc += edr[j] * we1s[j * HE + k];
            zs[k][e] = fmaxf(acc, 0.f);
        }
    }
    for (int i = tid; i < 64 * 32; i += 256) {
        const int e = i >> 5, d = i & 31;
        hs[e][d] = h[(size_t)srcs[e] * D + d];
    }
    __syncthreads();

    const int ep = tid & 31, fg = tid >> 5;
    float hr[2][32];
#pragma unroll
    for (int d = 0; d < 32; ++d) {
        hr[0][d] = hs[ep * 2][d];
        hr[1][d] = hs[ep * 2 + 1][d];
    }
    float acc[2][4];
#pragma unroll
    for (int i = 0; i < 2; ++i)
#pragma unroll
        for (int j = 0; j < 4; ++j) acc[i][j] = 0.f;

    for (int kc = 0; kc < 32; ++kc) {
        __syncthreads();
#pragma unroll
        for (int r = 0; r < 4; ++r) {
            const int idx4 = tid + 256 * r;
            const int kr = idx4 >> 8, c4 = idx4 & 255;
            *(float4*)&ws2s[kr][c4 * 4] =
                *(const float4*)(We2 + (size_t)(kc * 4 + kr) * 1024 + c4 * 4);
        }
        __syncthreads();
#pragma unroll
        for (int kk = 0; kk < 4; ++kk) {
            const int k = kc * 4 + kk;
            const float z0 = zs[k][ep * 2], z1 = zs[k][ep * 2 + 1];
#pragma unroll
            for (int d = 0; d < 32; ++d) {
                const float4 w4 = *(const float4*)&ws2s[kk][d * 32 + fg * 4];
                const float c0 = z0 * hr[0][d], c1 = z1 * hr[1][d];
                acc[0][0] += c0 * w4.x; acc[0][1] += c0 * w4.y;
                acc[0][2] += c0 * w4.z; acc[0][3] += c0 * w4.w;
                acc[1][0] += c1 * w4.x; acc[1][1] += c1 * w4.y;
                acc[1][2] += c1 * w4.z; acc[1][3] += c1 * w4.w;
            }
        }
    }
#pragma unroll
    for (int i = 0; i < 2; ++i) {
        const int e = e0 + ep * 2 + i;
        float* ap = &agg[(size_t)dst[e] * D + fg * 4];
#pragma unroll
        for (int j = 0; j < 4; ++j) atomicAdd(ap + j, acc[i][j]);
    }
}

// -------- GRU cell per node (8 nodes x 32 f per block) (+ optional split emit)
__global__ __launch_bounds__(256) void k_gru(
    const float* __restrict__ h, const float* __restrict__ agg,
    const float* __restrict__ Wroot, const float* __restrict__ bconv,
    const float* __restrict__ Wih, const float* __restrict__ Whh,
    const float* __restrict__ bih, const float* __restrict__ bhh,
    float* __restrict__ hout,
    unsigned short* __restrict__ hhi, unsigned short* __restrict__ hlo) {
    const int idx = blockIdx.x * 256 + threadIdx.x;  // grid exact: NN*D/256
    const int n = idx >> 5, f = idx & 31, nl = threadIdx.x >> 5;
    __shared__ float hsh[8][33], msh[8][33];
    const float hv = h[n * D + f];
    hsh[nl][f] = hv;
    __syncthreads();
    float m = bconv[f] + agg[n * D + f];
#pragma unroll
    for (int d = 0; d < 32; ++d) m += hsh[nl][d] * Wroot[d * D + f];
    m = fmaxf(m, 0.f);
    msh[nl][f] = m;
    __syncthreads();
    float gir = bih[f], giz = bih[D + f], gin = bih[2 * D + f];
    float ghr = bhh[f], ghz = bhh[D + f], ghn = bhh[2 * D + f];
#pragma unroll
    for (int d = 0; d < 32; ++d) {
        const float md = msh[nl][d], hd = hsh[nl][d];
        gir += md * Wih[f * D + d];
        giz += md * Wih[(D + f) * D + d];
        gin += md * Wih[(2 * D + f) * D + d];
        ghr += hd * Whh[f * D + d];
        ghz += hd * Whh[(D + f) * D + d];
        ghn += hd * Whh[(2 * D + f) * D + d];
    }
    const float r = sigf(gir + ghr);
    const float z = sigf(giz + ghz);
    const float nn2 = tanhf(gin + r * ghn);
    const float ho = (1.f - z) * nn2 + z * hv;
    hout[n * D + f] = ho;
    if (hhi) {
        unsigned short hi, lo;
        split_bf16(ho, hi, lo);
        hhi[idx] = hi;
        hlo[idx] = lo;
    }
}

// -------- one Set2Set step: LSTM cell + segment softmax attention, block = graph
__global__ __launch_bounds__(256) void k_s2s(
    const float* __restrict__ h, const int* __restrict__ start,
    float* __restrict__ qstar, float* __restrict__ hl, float* __restrict__ cl,
    const float* __restrict__ Wih, const float* __restrict__ Whh,
    const float* __restrict__ bih, const float* __restrict__ bhh,
    float* __restrict__ ebuf) {
    const int b = blockIdx.x, t = threadIdx.x;
    __shared__ float qst[64], hls[32], gates[128], qs[32];
    __shared__ float red[256];
    __shared__ float rsum[8][33];
    if (t < 64) qst[t] = qstar[b * 64 + t];
    if (t < 32) hls[t] = hl[b * 32 + t];
    __syncthreads();
    if (t < 128) {
        float g = bih[t] + bhh[t];
#pragma unroll 8
        for (int j = 0; j < 64; ++j) g += qst[j] * Wih[t * 64 + j];
#pragma unroll 8
        for (int j = 0; j < 32; ++j) g += hls[j] * Whh[t * 32 + j];
        gates[t] = g;
    }
    __syncthreads();
    if (t < 32) {  // i,f,g,o order
        const float ig = sigf(gates[t]);
        const float fg = sigf(gates[32 + t]);
        const float gg = tanhf(gates[64 + t]);
        const float og = sigf(gates[96 + t]);
        const float c = fg * cl[b * 32 + t] + ig * gg;
        const float q = og * tanhf(c);
        cl[b * 32 + t] = c;
        hl[b * 32 + t] = q;
        qstar[b * 64 + t] = q;
        qs[t] = q;
    }
    __syncthreads();
    const int s0 = start[b], s1 = start[b + 1];
    float lmax = -3.4e38f;
    for (int n = s0 + t; n < s1; n += 256) {
        const float4* hv = (const float4*)(h + (size_t)n * D);
        float e = 0.f;
#pragma unroll
        for (int u = 0; u < 8; ++u) {
            const float4 v = hv[u];
            e += v.x * qs[u * 4] + v.y * qs[u * 4 + 1] + v.z * qs[u * 4 + 2] + v.w * qs[u * 4 + 3];
        }
        ebuf[n] = e;
        lmax = fmaxf(lmax, e);
    }
    red[t] = lmax;
    __syncthreads();
    for (int s = 128; s > 0; s >>= 1) {
        if (t < s) red[t] = fmaxf(red[t], red[t + s]);
        __syncthreads();
    }
    const float smax = red[0];
    __syncthreads();
    float lsum = 0.f;
    for (int n = s0 + t; n < s1; n += 256) {
        const float w = expf(ebuf[n] - smax);
        ebuf[n] = w;
        lsum += w;
    }
    red[t] = lsum;
    __syncthreads();
    for (int s = 128; s > 0; s >>= 1) {
        if (t < s) red[t] += red[t + s];
        __syncthreads();
    }
    const float den = red[0];
    const float inv = (den > 0.f) ? 1.f / den : 0.f;
    const int fl = t & 31, sl = t >> 5;
    float racc = 0.f;
    for (int n = s0 + sl; n < s1; n += 8) racc += ebuf[n] * h[(size_t)n * D + fl];
    rsum[sl][fl] = racc;
    __syncthreads();
    if (sl == 0) {
        float rv = 0.f;
#pragma unroll
        for (int u = 0; u < 8; ++u) rv += rsum[u][fl];
        qstar[b * 64 + 32 + fl] = rv * inv;
    }
}

// -------- out = q_star @ W_out + b_out
__global__ void k_out(const float* __restrict__ qstar, const float* __restrict__ Wout,
                      const float* __restrict__ bout, float* __restrict__ out) {
    int b = threadIdx.x;
    if (b < NB) {
        float acc = bout[0];
#pragma unroll 8
        for (int j = 0; j < 64; ++j) acc += qstar[b * 64 + j] * Wout[j];
        out[b] = acc;
    }
}

extern "C" void kernel_launch(void* const* d_in, const int* in_sizes, int n_in,
                              void* d_out, int out_size, void* d_ws, size_t ws_size,
                              hipStream_t stream) {
    const float* x     = (const float*)d_in[0];
    // d_in[1] adj unused; d_in[2] T == 8 (module constant)
    const float* ed    = (const float*)d_in[3];
    const int*   edges = (const int*)d_in[4];
    const int*   batch = (const int*)d_in[5];
    const float* Wi    = (const float*)d_in[6];
    const float* bi    = (const float*)d_in[7];
    const float* We1   = (const float*)d_in[8];
    const float* be1   = (const float*)d_in[9];
    const float* We2   = (const float*)d_in[10];
    const float* be2   = (const float*)d_in[11];
    const float* Wroot = (const float*)d_in[12];
    const float* bconv = (const float*)d_in[13];
    const float* gWih  = (const float*)d_in[14];
    const float* gWhh  = (const float*)d_in[15];
    const float* gbih  = (const float*)d_in[16];
    const float* gbhh  = (const float*)d_in[17];
    const float* lWih  = (const float*)d_in[18];
    const float* lWhh  = (const float*)d_in[19];
    const float* lbih  = (const float*)d_in[20];
    const float* lbhh  = (const float*)d_in[21];
    const float* Wout  = (const float*)d_in[22];
    const float* bout  = (const float*)d_in[23];
    float* out = (float*)d_out;

    const int* srcp = edges;
    const int* dstp = edges + NE;

    char* ws = (char*)d_ws;
    size_t off = 0;
    auto alloc = [&](size_t bytes) -> char* {
        char* p = ws + off;
        off += (bytes + 255) & ~(size_t)255;
        return p;
    };
    float* hA    = (float*)alloc((size_t)NN * D * 4);
    float* hB    = (float*)alloc((size_t)NN * D * 4);
    float* agg   = (float*)alloc((size_t)NN * D * 4);
    float* ebuf  = (float*)alloc((size_t)NN * 4);
    float* qstar = (float*)alloc((size_t)NB * 64 * 4);  // qstar,hl,cl contiguous
    float* hl    = (float*)alloc((size_t)NB * 32 * 4);
    float* cl    = (float*)alloc((size_t)NB * 32 * 4);
    int*   gst   = (int*)alloc((NB + 1) * 4);
    // MFMA-path extras (~5.6 MB)
    unsigned short* hhiA = (unsigned short*)alloc((size_t)NN * D * 2);
    unsigned short* hloA = (unsigned short*)alloc((size_t)NN * D * 2);
    unsigned short* hhiB = (unsigned short*)alloc((size_t)NN * D * 2);
    unsigned short* hloB = (unsigned short*)alloc((size_t)NN * D * 2);
    unsigned short* wth  = (unsigned short*)alloc((size_t)129 * 1024 * 2);
    unsigned short* wtl  = (unsigned short*)alloc((size_t)129 * 1024 * 2);
    const size_t base_off = off;
    const bool mfma_path = (ws_size >= base_off);
    // v6 extra: precomputed z, k-major [128][NE] fp32 (~164 MB)
    float* zb = (float*)alloc((size_t)128 * NE * 4);
    const bool mfma6_path = (ws_size >= off);

    hipLaunchKernelGGL(k_graph_start, dim3(1), dim3(128), 0, stream, batch, gst);
    hipLaunchKernelGGL(k_input_linear, dim3(NN * D / 256), dim3(256), 0, stream, x, Wi, bi, hA,
                       mfma_path ? hhiA : (unsigned short*)nullptr,
                       mfma_path ? hloA : (unsigned short*)nullptr);
    if (mfma_path)
        hipLaunchKernelGGL(k_prep_w, dim3((129 * 1024 + 255) / 256), dim3(256), 0, stream,
                           We2, be2, wth, wtl);
    if (mfma6_path)
        hipLaunchKernelGGL(k_prep_z, dim3(NE / 256), dim3(256), 0, stream, ed, We1, be1, zb);
    hipMemsetAsync(qstar, 0, (size_t)(NB * 64 + NB * 32 + NB * 32) * 4, stream);

    float* hcur = hA;
    float* hnxt = hB;
    unsigned short *hhic = hhiA, *hloc = hloA, *hhin = hhiB, *hlon = hloB;
    for (int t = 0; t < TST; ++t) {
        hipMemsetAsync(agg, 0, (size_t)NN * D * 4, stream);
        if (mfma6_path)
            hipLaunchKernelGGL(k_msg_mfma6, dim3(NE / 256), dim3(256), 0, stream,
                               zb, wth, wtl, hhic, hloc, srcp, dstp, agg);
        else if (mfma_path)
            hipLaunchKernelGGL(k_msg_mfma, dim3(NE / 64), dim3(256), 0, stream,
                               ed, We1, be1, wth, wtl, hhic, hloc, srcp, dstp, agg);
        else
            hipLaunchKernelGGL(k_msg_fused, dim3(NE / 64), dim3(256), 0, stream,
                               ed, We1, be1, We2, hcur, srcp, dstp, agg);
        hipLaunchKernelGGL(k_gru, dim3(NN * D / 256), dim3(256), 0, stream,
                           hcur, agg, Wroot, bconv, gWih, gWhh, gbih, gbhh, hnxt,
                           mfma_path ? hhin : (unsigned short*)nullptr,
                           mfma_path ? hlon : (unsigned short*)nullptr);
        float* tf = hcur; hcur = hnxt; hnxt = tf;
        unsigned short* ts;
        ts = hhic; hhic = hhin; hhin = ts;
        ts = hloc; hloc = hlon; hlon = ts;
    }

    for (int s = 0; s < S2S; ++s)
        hipLaunchKernelGGL(k_s2s, dim3(NB), dim3(256), 0, stream,
                           hcur, gst, qstar, hl, cl, lWih, lWhh, lbih, lbhh, ebuf);

    hipLaunchKernelGGL(k_out, dim3(1), dim3(64), 0, stream, qstar, Wout, bout, out);
    (void)in_sizes; (void)n_in; (void)out_size;
}

// Round 9
// 2786.899 us; speedup vs baseline: 1.6613x; 1.2511x over previous
//
#include <hip/hip_runtime.h>
#include <hip/hip_bf16.h>

#define NN 20000   // nodes
#define NE 320000  // edges
#define NB 64      // graphs
#define DIN 16
#define DE 8
#define HE 128
#define D 32
#define TST 8
#define S2S 12

typedef __attribute__((ext_vector_type(8))) short short8x;   // 8 bf16 = 4 VGPRs (MFMA A/B frag)
typedef __attribute__((ext_vector_type(4))) float f32x4;     // MFMA C/D frag

__device__ __forceinline__ float sigf(float x) { return 1.f / (1.f + expf(-x)); }

__device__ __forceinline__ void split_bf16(float x, unsigned short& hi, unsigned short& lo) {
    __hip_bfloat16 h = __float2bfloat16(x);
    hi = *(unsigned short*)&h;
    float r = x - __bfloat162float(h);
    __hip_bfloat16 l = __float2bfloat16(r);
    lo = *(unsigned short*)&l;
}

// XOR-swizzled element offset of an A-frag within a 1024-el k-row of Wt.
__device__ __forceinline__ int swz_off(int eidx, int quad, int tile) {
    const int u = eidx * 4 + quad;
    const int s = u ^ ((u >> 3) & 7);
    return tile * 512 + s * 8;
}

// -------- graph segment starts: start[b] = lower_bound(batch, b), start[NB]=NN
__global__ void k_graph_start(const int* __restrict__ batch, int* __restrict__ start) {
    int b = threadIdx.x;
    if (b > NB) return;
    int lo = 0, hi = NN;
    while (lo < hi) {
        int mid = (lo + hi) >> 1;
        if (batch[mid] < b) lo = mid + 1; else hi = mid;
    }
    start[b] = lo;
}

// -------- Wt[k][swz(f,d)] = We2[k][d*32+f] (k<128), row 128 = be2; hi/lo bf16
__global__ __launch_bounds__(256) void k_prep_w(
    const float* __restrict__ We2, const float* __restrict__ be2,
    unsigned short* __restrict__ wth, unsigned short* __restrict__ wtl) {
    int idx = blockIdx.x * 256 + threadIdx.x;
    if (idx >= 129 * 1024) return;
    int k = idx >> 10, rem = idx & 1023, f = rem >> 5, d = rem & 31;
    float v = (k < 128) ? We2[k * 1024 + d * 32 + f] : be2[d * 32 + f];
    unsigned short hi, lo;
    split_bf16(v, hi, lo);
    const int pos = k * 1024 + swz_off(f & 15, d >> 3, f >> 4) + (d & 7);
    wth[pos] = hi;
    wtl[pos] = lo;
}

// -------- counting sort of edges by dst (graph static per call; redo each launch)
__global__ __launch_bounds__(256) void k_hist(const int* __restrict__ dst, int* __restrict__ hist) {
    const int e = blockIdx.x * 256 + threadIdx.x;
    atomicAdd(&hist[dst[e]], 1);
}

__global__ __launch_bounds__(256) void k_scan(const int* __restrict__ hist, int* __restrict__ offs) {
    __shared__ int part[256];
    const int tid = threadIdx.x;
    const int base = tid * 79;  // 256*79 = 20224 >= NN
    int s = 0;
    for (int i = 0; i < 79; ++i) {
        const int b = base + i;
        if (b < NN) s += hist[b];
    }
    part[tid] = s;
    __syncthreads();
    if (tid == 0) {
        int a = 0;
        for (int i = 0; i < 256; ++i) { const int v = part[i]; part[i] = a; a += v; }
    }
    __syncthreads();
    int a = part[tid];
    for (int i = 0; i < 79; ++i) {
        const int b = base + i;
        if (b < NN) { offs[b] = a; a += hist[b]; }
    }
}

__global__ __launch_bounds__(256) void k_scatter(
    const int* __restrict__ src, const int* __restrict__ dst, const float* __restrict__ ed,
    int* __restrict__ offs, int* __restrict__ src_s, int* __restrict__ dst_s,
    float* __restrict__ ed_s) {
    const int e = blockIdx.x * 256 + threadIdx.x;
    const int d = dst[e];
    const int pos = atomicAdd(&offs[d], 1);
    src_s[pos] = src[e];
    dst_s[pos] = d;
    const float4 a = *(const float4*)(ed + (size_t)e * 8);
    const float4 b = *(const float4*)(ed + (size_t)e * 8 + 4);
    *(float4*)(ed_s + (size_t)pos * 8) = a;
    *(float4*)(ed_s + (size_t)pos * 8 + 4) = b;
}

// -------- h0 = x @ W_in + b_in  (+ optional bf16 hi/lo split emit)
__global__ __launch_bounds__(256) void k_input_linear(
    const float* __restrict__ x, const float* __restrict__ Win,
    const float* __restrict__ bin, float* __restrict__ h,
    unsigned short* __restrict__ hhi, unsigned short* __restrict__ hlo) {
    int idx = blockIdx.x * 256 + threadIdx.x;
    int n = idx >> 5, f = idx & 31;
    float acc = bin[f];
#pragma unroll
    for (int d = 0; d < DIN; ++d) acc += x[n * DIN + d] * Win[d * D + f];
    h[idx] = acc;
    if (hhi) {
        unsigned short hi, lo;
        split_bf16(acc, hi, lo);
        hhi[idx] = hi;
        hlo[idx] = lo;
    }
}

// -------- MFMA msg v7: v6's proven 4-k-chunk dbuf pipeline (exact math), plus
// (a) z recomputed in-kernel per chunk (no zb stream), (b) edges dst-sorted +
// LDS segmented pre-reduction epilogue (10x fewer atomics).
#define CHB 20480  // per-chunk buffer: Whi 8K | Wlo 8K | z 4K
__global__ __launch_bounds__(256, 3) void k_msg_mfma7(
    const float* __restrict__ ed_s, const float* __restrict__ We1,
    const float* __restrict__ be1,
    const unsigned short* __restrict__ wth, const unsigned short* __restrict__ wtl,
    const unsigned short* __restrict__ hhi, const unsigned short* __restrict__ hlo,
    const int* __restrict__ src_s, const int* __restrict__ dst_s,
    float* __restrict__ agg) {
    const int tid = threadIdx.x;
    const int e0 = blockIdx.x * 256;

    __shared__ __align__(16) char sW[2][CHB];  // 40 KB dbuf; reused as msg[256][33] in epilogue
    __shared__ float we1s[DE * HE];            // 4 KB
    __shared__ float be1s[HE];
    __shared__ int dsl[256];

    const int lane = tid & 63;
    const int wv = tid >> 6;
    const int eidx = lane & 15;
    const int quad = lane >> 4;
    const int d0 = quad * 8;
    const int swz0 = swz_off(eidx, quad, 0);
    const int swz1 = swz_off(eidx, quad, 1);

    for (int i = tid; i < DE * HE; i += 256) we1s[i] = We1[i];
    if (tid < HE) be1s[tid] = be1[tid];
    dsl[tid] = dst_s[e0 + tid];

    // per-thread edge row (sorted layout, coalesced)
    const float4 ev0 = *(const float4*)(ed_s + (size_t)(e0 + tid) * 8);
    const float4 ev1 = *(const float4*)(ed_s + (size_t)(e0 + tid) * 8 + 4);
    float edr[8];
    edr[0] = ev0.x; edr[1] = ev0.y; edr[2] = ev0.z; edr[3] = ev0.w;
    edr[4] = ev1.x; edr[5] = ev1.y; edr[6] = ev1.z; edr[7] = ev1.w;

    // B-frags (h hi/lo) for 4 e-tiles
    short8x bhi[4], blo[4];
#pragma unroll
    for (int et = 0; et < 4; ++et) {
        const int e = e0 + wv * 64 + et * 16 + eidx;
        const size_t hb = (size_t)src_s[e] * 32 + d0;
        bhi[et] = *(const short8x*)(hhi + hb);
        blo[et] = *(const short8x*)(hlo + hb);
    }

    uint4 rh[2], rl[2];
    auto gload = [&](int c) {
        const char* gh = (const char*)wth + (size_t)c * 8192;
        const char* gl = (const char*)wtl + (size_t)c * 8192;
#pragma unroll
        for (int r = 0; r < 2; ++r) {
            rh[r] = *(const uint4*)(gh + r * 4096 + tid * 16);
            rl[r] = *(const uint4*)(gl + r * 4096 + tid * 16);
        }
    };
    auto lstore = [&](int b) {
        char* p = sW[b];
#pragma unroll
        for (int r = 0; r < 2; ++r) {
            *(uint4*)(p + r * 4096 + tid * 16) = rh[r];
            *(uint4*)(p + 8192 + r * 4096 + tid * 16) = rl[r];
        }
    };
    auto zstore = [&](int c, int b) {  // z for chunk c -> buf b (thread = its edge)
        float* zq = (float*)(sW[b] + 16384);
#pragma unroll
        for (int m = 0; m < 4; ++m) {
            const int k = c * 4 + m;
            float acc = be1s[k];
#pragma unroll
            for (int j = 0; j < 8; ++j) acc += edr[j] * we1s[j * HE + k];
            zq[m * 256 + tid] = fmaxf(acc, 0.f);
        }
    };

    f32x4 macc[4][2];
#pragma unroll
    for (int et = 0; et < 4; ++et) {
        macc[et][0] = (f32x4){0.f, 0.f, 0.f, 0.f};
        macc[et][1] = (f32x4){0.f, 0.f, 0.f, 0.f};
    }

    gload(0);
    __syncthreads();   // we1s/be1s ready (needed by zstore)
    lstore(0);
    zstore(0, 0);
    gload(1);
    __syncthreads();   // buf0 fully visible

    for (int c = 0; c < 32; ++c) {
        const int b = c & 1;
        if (c + 1 < 32) { lstore(b ^ 1); zstore(c + 1, b ^ 1); }
        if (c + 2 < 32) gload(c + 2);

        const unsigned short* whp = (const unsigned short*)sW[b];
        const unsigned short* wlp = (const unsigned short*)(sW[b] + 8192);
        const float* zp = (const float*)(sW[b] + 16384);
#pragma unroll
        for (int m = 0; m < 4; ++m) {
            float zk[4];
#pragma unroll
            for (int et = 0; et < 4; ++et) zk[et] = zp[m * 256 + wv * 64 + et * 16 + eidx];
            const int mb = m * 1024;
            const short8x fh0 = *(const short8x*)(whp + mb + swz0);
            const short8x fh1 = *(const short8x*)(whp + mb + swz1);
            const short8x fl0 = *(const short8x*)(wlp + mb + swz0);
            const short8x fl1 = *(const short8x*)(wlp + mb + swz1);
#pragma unroll
            for (int et = 0; et < 4; ++et) {
                f32x4 t0 = {0.f, 0.f, 0.f, 0.f}, t1 = {0.f, 0.f, 0.f, 0.f};
                t0 = __builtin_amdgcn_mfma_f32_16x16x32_bf16(fh0, bhi[et], t0, 0, 0, 0);
                t1 = __builtin_amdgcn_mfma_f32_16x16x32_bf16(fh1, bhi[et], t1, 0, 0, 0);
                t0 = __builtin_amdgcn_mfma_f32_16x16x32_bf16(fl0, bhi[et], t0, 0, 0, 0);
                t1 = __builtin_amdgcn_mfma_f32_16x16x32_bf16(fl1, bhi[et], t1, 0, 0, 0);
                t0 = __builtin_amdgcn_mfma_f32_16x16x32_bf16(fh0, blo[et], t0, 0, 0, 0);
                t1 = __builtin_amdgcn_mfma_f32_16x16x32_bf16(fh1, blo[et], t1, 0, 0, 0);
                macc[et][0] += zk[et] * t0;
                macc[et][1] += zk[et] * t1;
            }
        }
        __syncthreads();
    }

    {   // k = 128: be2 virtual row, z == 1; frags direct from global (once)
        const unsigned short* bh = wth + 128 * 1024;
        const unsigned short* bl = wtl + 128 * 1024;
        const short8x fh0 = *(const short8x*)(bh + swz0);
        const short8x fh1 = *(const short8x*)(bh + swz1);
        const short8x fl0 = *(const short8x*)(bl + swz0);
        const short8x fl1 = *(const short8x*)(bl + swz1);
#pragma unroll
        for (int et = 0; et < 4; ++et) {
            f32x4 t0 = {0.f, 0.f, 0.f, 0.f}, t1 = {0.f, 0.f, 0.f, 0.f};
            t0 = __builtin_amdgcn_mfma_f32_16x16x32_bf16(fh0, bhi[et], t0, 0, 0, 0);
            t1 = __builtin_amdgcn_mfma_f32_16x16x32_bf16(fh1, bhi[et], t1, 0, 0, 0);
            t0 = __builtin_amdgcn_mfma_f32_16x16x32_bf16(fl0, bhi[et], t0, 0, 0, 0);
            t1 = __builtin_amdgcn_mfma_f32_16x16x32_bf16(fl1, bhi[et], t1, 0, 0, 0);
            t0 = __builtin_amdgcn_mfma_f32_16x16x32_bf16(fh0, blo[et], t0, 0, 0, 0);
            t1 = __builtin_amdgcn_mfma_f32_16x16x32_bf16(fh1, blo[et], t1, 0, 0, 0);
            macc[et][0] += t0;
            macc[et][1] += t1;
        }
    }

    // epilogue: stash msg[e][f] in sW (K-loop done; final barrier already passed),
    // then segmented reduction over dst-sorted runs -> ~1 atomic per run per f.
    float* msgb = (float*)sW;  // 256 x 33 floats = 33792 B < 40960
#pragma unroll
    for (int et = 0; et < 4; ++et) {
        const int eloc = wv * 64 + et * 16 + eidx;
        float* row = msgb + eloc * 33;
        row[quad * 4 + 0] = macc[et][0].x;
        row[quad * 4 + 1] = macc[et][0].y;
        row[quad * 4 + 2] = macc[et][0].z;
        row[quad * 4 + 3] = macc[et][0].w;
        row[16 + quad * 4 + 0] = macc[et][1].x;
        row[16 + quad * 4 + 1] = macc[et][1].y;
        row[16 + quad * 4 + 2] = macc[et][1].z;
        row[16 + quad * 4 + 3] = macc[et][1].w;
    }
    __syncthreads();

    const int g = tid >> 5, f = tid & 31;  // 8 groups x 32 edges each
    const int base = g * 32;
    float acc = 0.f;
    int cur = dsl[base];
    for (int i = 0; i < 32; ++i) {
        const int dnn = dsl[base + i];  // uniform across the group's lanes
        const float v = msgb[(base + i) * 33 + f];
        if (dnn != cur) {
            atomicAdd(&agg[(size_t)cur * 32 + f], acc);
            acc = 0.f;
            cur = dnn;
        }
        acc += v;
    }
    atomicAdd(&agg[(size_t)cur * 32 + f], acc);
}

// -------- MFMA msg v2 (fallback, base ws only): ring prefetch, z in regs
#define LDFRAG(slot, kk)                                          \
    do {                                                          \
        const unsigned short* _ph = wth + ((size_t)(kk) << 10);   \
        const unsigned short* _pl = wtl + ((size_t)(kk) << 10);   \
        ring[slot][0] = *(const short8x*)(_ph + b0);              \
        ring[slot][1] = *(const short8x*)(_ph + b1);              \
        ring[slot][2] = *(const short8x*)(_pl + b0);              \
        ring[slot][3] = *(const short8x*)(_pl + b1);              \
    } while (0)

__global__ __launch_bounds__(256) void k_msg_mfma(
    const float* __restrict__ ed, const float* __restrict__ We1,
    const float* __restrict__ be1,
    const unsigned short* __restrict__ wth, const unsigned short* __restrict__ wtl,
    const unsigned short* __restrict__ hhi, const unsigned short* __restrict__ hlo,
    const int* __restrict__ src, const int* __restrict__ dst,
    float* __restrict__ agg) {
    const int tid = threadIdx.x;
    const int e0 = blockIdx.x * 64;

    __shared__ float we1s[DE * HE];
    __shared__ float be1s[HE];

    for (int i = tid; i < DE * HE; i += 256) we1s[i] = We1[i];
    if (tid < HE) be1s[tid] = be1[tid];

    const int lane = tid & 63;
    const int wv = tid >> 6;
    const int eidx = lane & 15;
    const int quad = lane >> 4;
    const int eloc = wv * 16 + eidx;
    const int e = e0 + eloc;
    const int d0 = quad * 8;

    const int sn = src[e];
    const int dn = dst[e];

    const int b0 = swz_off(eidx, quad, 0);
    const int b1 = swz_off(eidx, quad, 1);

    const size_t hb = (size_t)sn * 32 + d0;
    const short8x bhi = *(const short8x*)(hhi + hb);
    const short8x blo = *(const short8x*)(hlo + hb);
    const float4 edv0 = *(const float4*)(ed + (size_t)e * 8);
    const float4 edv1 = *(const float4*)(ed + (size_t)e * 8 + 4);

    short8x ring[4][4];
    LDFRAG(0, 0);
    LDFRAG(1, 1);
    LDFRAG(2, 2);

    __syncthreads();

    float edr[8];
    edr[0] = edv0.x; edr[1] = edv0.y; edr[2] = edv0.z; edr[3] = edv0.w;
    edr[4] = edv1.x; edr[5] = edv1.y; edr[6] = edv1.z; edr[7] = edv1.w;
    float zreg[32];
#pragma unroll
    for (int m = 0; m < 32; ++m) {
        const int kk = (quad << 5) + m;
        float acc = be1s[kk];
#pragma unroll
        for (int j = 0; j < 8; ++j) acc += edr[j] * we1s[j * 128 + kk];
        zreg[m] = fmaxf(acc, 0.f);
    }

    f32x4 m0 = {0.f, 0.f, 0.f, 0.f}, m1 = {0.f, 0.f, 0.f, 0.f};

    for (int q = 0; q < 4; ++q) {
        const int bsrc = q * 16 + eidx;
#pragma unroll
        for (int m = 0; m < 32; ++m) {
            const int k = q * 32 + m;
            const int slot = m & 3;
            const int pslot = (m + 3) & 3;
            int kn = k + 3;
            kn = (kn > 128) ? 128 : kn;
            LDFRAG(pslot, kn);

            const float zk = __shfl(zreg[m], bsrc);

            f32x4 t0 = {0.f, 0.f, 0.f, 0.f}, t1 = {0.f, 0.f, 0.f, 0.f};
            t0 = __builtin_amdgcn_mfma_f32_16x16x32_bf16(ring[slot][0], bhi, t0, 0, 0, 0);
            t1 = __builtin_amdgcn_mfma_f32_16x16x32_bf16(ring[slot][1], bhi, t1, 0, 0, 0);
            t0 = __builtin_amdgcn_mfma_f32_16x16x32_bf16(ring[slot][2], bhi, t0, 0, 0, 0);
            t1 = __builtin_amdgcn_mfma_f32_16x16x32_bf16(ring[slot][3], bhi, t1, 0, 0, 0);
            t0 = __builtin_amdgcn_mfma_f32_16x16x32_bf16(ring[slot][0], blo, t0, 0, 0, 0);
            t1 = __builtin_amdgcn_mfma_f32_16x16x32_bf16(ring[slot][1], blo, t1, 0, 0, 0);

            m0 += zk * t0;
            m1 += zk * t1;
        }
    }
    {
        f32x4 t0 = {0.f, 0.f, 0.f, 0.f}, t1 = {0.f, 0.f, 0.f, 0.f};
        t0 = __builtin_amdgcn_mfma_f32_16x16x32_bf16(ring[0][0], bhi, t0, 0, 0, 0);
        t1 = __builtin_amdgcn_mfma_f32_16x16x32_bf16(ring[0][1], bhi, t1, 0, 0, 0);
        t0 = __builtin_amdgcn_mfma_f32_16x16x32_bf16(ring[0][2], bhi, t0, 0, 0, 0);
        t1 = __builtin_amdgcn_mfma_f32_16x16x32_bf16(ring[0][3], bhi, t1, 0, 0, 0);
        t0 = __builtin_amdgcn_mfma_f32_16x16x32_bf16(ring[0][0], blo, t0, 0, 0, 0);
        t1 = __builtin_amdgcn_mfma_f32_16x16x32_bf16(ring[0][1], blo, t1, 0, 0, 0);
        m0 += t0;
        m1 += t1;
    }

    float* ap = agg + (size_t)dn * 32 + quad * 4;
    atomicAdd(ap + 0, m0.x);
    atomicAdd(ap + 1, m0.y);
    atomicAdd(ap + 2, m0.z);
    atomicAdd(ap + 3, m0.w);
    atomicAdd(ap + 16 + 0, m1.x);
    atomicAdd(ap + 16 + 1, m1.y);
    atomicAdd(ap + 16 + 2, m1.z);
    atomicAdd(ap + 16 + 3, m1.w);
}

// -------- fallback (proven R2 path): recompute z per edge, fp32 VALU bilinear
__global__ __launch_bounds__(256) void k_msg_fused(
    const float* __restrict__ ed, const float* __restrict__ We1,
    const float* __restrict__ be1, const float* __restrict__ We2,
    const float* __restrict__ h, const int* __restrict__ src,
    const int* __restrict__ dst, float* __restrict__ agg) {
    const int tid = threadIdx.x;
    const int e0 = blockIdx.x * 64;
    __shared__ float we1s[DE * HE];
    __shared__ float be1s[HE];
    __shared__ float eds[64][9];
    __shared__ float zs[HE][64];
    __shared__ float hs[64][33];
    __shared__ float ws2s[4][1024];
    __shared__ int srcs[64];

    for (int i = tid; i < DE * HE; i += 256) we1s[i] = We1[i];
    if (tid < HE) be1s[tid] = be1[tid];
    if (tid < 64) srcs[tid] = src[e0 + tid];
    for (int i = tid; i < 64 * DE; i += 256) eds[i >> 3][i & 7] = ed[(size_t)e0 * DE + i];
    __syncthreads();

    {
        const int e = tid & 63, kb = tid >> 6;
        float edr[8];
#pragma unroll
        for (int j = 0; j < 8; ++j) edr[j] = eds[e][j];
        for (int m = 0; m < 32; ++m) {
            const int k = kb * 32 + m;
            float acc = be1s[k];
#pragma unroll
            for (int j = 0; j < 8; ++j) acc += edr[j] * we1s[j * HE + k];
            zs[k][e] = fmaxf(acc, 0.f);
        }
    }
    for (int i = tid; i < 64 * 32; i += 256) {
        const int e = i >> 5, d = i & 31;
        hs[e][d] = h[(size_t)srcs[e] * D + d];
    }
    __syncthreads();

    const int ep = tid & 31, fg = tid >> 5;
    float hr[2][32];
#pragma unroll
    for (int d = 0; d < 32; ++d) {
        hr[0][d] = hs[ep * 2][d];
        hr[1][d] = hs[ep * 2 + 1][d];
    }
    float acc[2][4];
#pragma unroll
    for (int i = 0; i < 2; ++i)
#pragma unroll
        for (int j = 0; j < 4; ++j) acc[i][j] = 0.f;

    for (int kc = 0; kc < 32; ++kc) {
        __syncthreads();
#pragma unroll
        for (int r = 0; r < 4; ++r) {
            const int idx4 = tid + 256 * r;
            const int kr = idx4 >> 8, c4 = idx4 & 255;
            *(float4*)&ws2s[kr][c4 * 4] =
                *(const float4*)(We2 + (size_t)(kc * 4 + kr) * 1024 + c4 * 4);
        }
        __syncthreads();
#pragma unroll
        for (int kk = 0; kk < 4; ++kk) {
            const int k = kc * 4 + kk;
            const float z0 = zs[k][ep * 2], z1 = zs[k][ep * 2 + 1];
#pragma unroll
            for (int d = 0; d < 32; ++d) {
                const float4 w4 = *(const float4*)&ws2s[kk][d * 32 + fg * 4];
                const float c0 = z0 * hr[0][d], c1 = z1 * hr[1][d];
                acc[0][0] += c0 * w4.x; acc[0][1] += c0 * w4.y;
                acc[0][2] += c0 * w4.z; acc[0][3] += c0 * w4.w;
                acc[1][0] += c1 * w4.x; acc[1][1] += c1 * w4.y;
                acc[1][2] += c1 * w4.z; acc[1][3] += c1 * w4.w;
            }
        }
    }
#pragma unroll
    for (int i = 0; i < 2; ++i) {
        const int e = e0 + ep * 2 + i;
        float* ap = &agg[(size_t)dst[e] * D + fg * 4];
#pragma unroll
        for (int j = 0; j < 4; ++j) atomicAdd(ap + j, acc[i][j]);
    }
}

// -------- GRU cell per node (8 nodes x 32 f per block) (+ optional split emit)
__global__ __launch_bounds__(256) void k_gru(
    const float* __restrict__ h, const float* __restrict__ agg,
    const float* __restrict__ Wroot, const float* __restrict__ bconv,
    const float* __restrict__ Wih, const float* __restrict__ Whh,
    const float* __restrict__ bih, const float* __restrict__ bhh,
    float* __restrict__ hout,
    unsigned short* __restrict__ hhi, unsigned short* __restrict__ hlo) {
    const int idx = blockIdx.x * 256 + threadIdx.x;
    const int n = idx >> 5, f = idx & 31, nl = threadIdx.x >> 5;
    __shared__ float hsh[8][33], msh[8][33];
    const float hv = h[n * D + f];
    hsh[nl][f] = hv;
    __syncthreads();
    float m = bconv[f] + agg[n * D + f];
#pragma unroll
    for (int d = 0; d < 32; ++d) m += hsh[nl][d] * Wroot[d * D + f];
    m = fmaxf(m, 0.f);
    msh[nl][f] = m;
    __syncthreads();
    float gir = bih[f], giz = bih[D + f], gin = bih[2 * D + f];
    float ghr = bhh[f], ghz = bhh[D + f], ghn = bhh[2 * D + f];
#pragma unroll
    for (int d = 0; d < 32; ++d) {
        const float md = msh[nl][d], hd = hsh[nl][d];
        gir += md * Wih[f * D + d];
        giz += md * Wih[(D + f) * D + d];
        gin += md * Wih[(2 * D + f) * D + d];
        ghr += hd * Whh[f * D + d];
        ghz += hd * Whh[(D + f) * D + d];
        ghn += hd * Whh[(2 * D + f) * D + d];
    }
    const float r = sigf(gir + ghr);
    const float z = sigf(giz + ghz);
    const float nn2 = tanhf(gin + r * ghn);
    const float ho = (1.f - z) * nn2 + z * hv;
    hout[n * D + f] = ho;
    if (hhi) {
        unsigned short hi, lo;
        split_bf16(ho, hi, lo);
        hhi[idx] = hi;
        hlo[idx] = lo;
    }
}

// -------- one Set2Set step: LSTM cell + segment softmax attention, block = graph
__global__ __launch_bounds__(256) void k_s2s(
    const float* __restrict__ h, const int* __restrict__ start,
    float* __restrict__ qstar, float* __restrict__ hl, float* __restrict__ cl,
    const float* __restrict__ Wih, const float* __restrict__ Whh,
    const float* __restrict__ bih, const float* __restrict__ bhh,
    float* __restrict__ ebuf) {
    const int b = blockIdx.x, t = threadIdx.x;
    __shared__ float qst[64], hls[32], gates[128], qs[32];
    __shared__ float red[256];
    __shared__ float rsum[8][33];
    if (t < 64) qst[t] = qstar[b * 64 + t];
    if (t < 32) hls[t] = hl[b * 32 + t];
    __syncthreads();
    if (t < 128) {
        float g = bih[t] + bhh[t];
#pragma unroll 8
        for (int j = 0; j < 64; ++j) g += qst[j] * Wih[t * 64 + j];
#pragma unroll 8
        for (int j = 0; j < 32; ++j) g += hls[j] * Whh[t * 32 + j];
        gates[t] = g;
    }
    __syncthreads();
    if (t < 32) {
        const float ig = sigf(gates[t]);
        const float fg = sigf(gates[32 + t]);
        const float gg = tanhf(gates[64 + t]);
        const float og = sigf(gates[96 + t]);
        const float c = fg * cl[b * 32 + t] + ig * gg;
        const float q = og * tanhf(c);
        cl[b * 32 + t] = c;
        hl[b * 32 + t] = q;
        qstar[b * 64 + t] = q;
        qs[t] = q;
    }
    __syncthreads();
    const int s0 = start[b], s1 = start[b + 1];
    float lmax = -3.4e38f;
    for (int n = s0 + t; n < s1; n += 256) {
        const float4* hv = (const float4*)(h + (size_t)n * D);
        float e = 0.f;
#pragma unroll
        for (int u = 0; u < 8; ++u) {
            const float4 v = hv[u];
            e += v.x * qs[u * 4] + v.y * qs[u * 4 + 1] + v.z * qs[u * 4 + 2] + v.w * qs[u * 4 + 3];
        }
        ebuf[n] = e;
        lmax = fmaxf(lmax, e);
    }
    red[t] = lmax;
    __syncthreads();
    for (int s = 128; s > 0; s >>= 1) {
        if (t < s) red[t] = fmaxf(red[t], red[t + s]);
        __syncthreads();
    }
    const float smax = red[0];
    __syncthreads();
    float lsum = 0.f;
    for (int n = s0 + t; n < s1; n += 256) {
        const float w = expf(ebuf[n] - smax);
        ebuf[n] = w;
        lsum += w;
    }
    red[t] = lsum;
    __syncthreads();
    for (int s = 128; s > 0; s >>= 1) {
        if (t < s) red[t] += red[t + s];
        __syncthreads();
    }
    const float den = red[0];
    const float inv = (den > 0.f) ? 1.f / den : 0.f;
    const int fl = t & 31, sl = t >> 5;
    float racc = 0.f;
    for (int n = s0 + sl; n < s1; n += 8) racc += ebuf[n] * h[(size_t)n * D + fl];
    rsum[sl][fl] = racc;
    __syncthreads();
    if (sl == 0) {
        float rv = 0.f;
#pragma unroll
        for (int u = 0; u < 8; ++u) rv += rsum[u][fl];
        qstar[b * 64 + 32 + fl] = rv * inv;
    }
}

// -------- out = q_star @ W_out + b_out
__global__ void k_out(const float* __restrict__ qstar, const float* __restrict__ Wout,
                      const float* __restrict__ bout, float* __restrict__ out) {
    int b = threadIdx.x;
    if (b < NB) {
        float acc = bout[0];
#pragma unroll 8
        for (int j = 0; j < 64; ++j) acc += qstar[b * 64 + j] * Wout[j];
        out[b] = acc;
    }
}

extern "C" void kernel_launch(void* const* d_in, const int* in_sizes, int n_in,
                              void* d_out, int out_size, void* d_ws, size_t ws_size,
                              hipStream_t stream) {
    const float* x     = (const float*)d_in[0];
    const float* ed    = (const float*)d_in[3];
    const int*   edges = (const int*)d_in[4];
    const int*   batch = (const int*)d_in[5];
    const float* Wi    = (const float*)d_in[6];
    const float* bi    = (const float*)d_in[7];
    const float* We1   = (const float*)d_in[8];
    const float* be1   = (const float*)d_in[9];
    const float* We2   = (const float*)d_in[10];
    const float* be2   = (const float*)d_in[11];
    const float* Wroot = (const float*)d_in[12];
    const float* bconv = (const float*)d_in[13];
    const float* gWih  = (const float*)d_in[14];
    const float* gWhh  = (const float*)d_in[15];
    const float* gbih  = (const float*)d_in[16];
    const float* gbhh  = (const float*)d_in[17];
    const float* lWih  = (const float*)d_in[18];
    const float* lWhh  = (const float*)d_in[19];
    const float* lbih  = (const float*)d_in[20];
    const float* lbhh  = (const float*)d_in[21];
    const float* Wout  = (const float*)d_in[22];
    const float* bout  = (const float*)d_in[23];
    float* out = (float*)d_out;

    const int* srcp = edges;
    const int* dstp = edges + NE;

    char* ws = (char*)d_ws;
    size_t off = 0;
    auto alloc = [&](size_t bytes) -> char* {
        char* p = ws + off;
        off += (bytes + 255) & ~(size_t)255;
        return p;
    };
    float* hA    = (float*)alloc((size_t)NN * D * 4);
    float* hB    = (float*)alloc((size_t)NN * D * 4);
    float* agg   = (float*)alloc((size_t)NN * D * 4);
    float* ebuf  = (float*)alloc((size_t)NN * 4);
    float* qstar = (float*)alloc((size_t)NB * 64 * 4);
    float* hl    = (float*)alloc((size_t)NB * 32 * 4);
    float* cl    = (float*)alloc((size_t)NB * 32 * 4);
    int*   gst   = (int*)alloc((NB + 1) * 4);
    unsigned short* hhiA = (unsigned short*)alloc((size_t)NN * D * 2);
    unsigned short* hloA = (unsigned short*)alloc((size_t)NN * D * 2);
    unsigned short* hhiB = (unsigned short*)alloc((size_t)NN * D * 2);
    unsigned short* hloB = (unsigned short*)alloc((size_t)NN * D * 2);
    unsigned short* wth  = (unsigned short*)alloc((size_t)129 * 1024 * 2);
    unsigned short* wtl  = (unsigned short*)alloc((size_t)129 * 1024 * 2);
    const size_t base_off = off;
    const bool mfma_path = (ws_size >= base_off);
    // v7 extras (~14 MB): dst-sorted edge arrays + sort scratch
    int*   hist  = (int*)alloc((size_t)NN * 4);
    int*   offs  = (int*)alloc((size_t)NN * 4);
    int*   src_s = (int*)alloc((size_t)NE * 4);
    int*   dst_s = (int*)alloc((size_t)NE * 4);
    float* ed_s  = (float*)alloc((size_t)NE * 8 * 4);
    const bool mfma7_path = (ws_size >= off);

    hipLaunchKernelGGL(k_graph_start, dim3(1), dim3(128), 0, stream, batch, gst);
    hipLaunchKernelGGL(k_input_linear, dim3(NN * D / 256), dim3(256), 0, stream, x, Wi, bi, hA,
                       mfma_path ? hhiA : (unsigned short*)nullptr,
                       mfma_path ? hloA : (unsigned short*)nullptr);
    if (mfma_path)
        hipLaunchKernelGGL(k_prep_w, dim3((129 * 1024 + 255) / 256), dim3(256), 0, stream,
                           We2, be2, wth, wtl);
    if (mfma7_path) {
        hipMemsetAsync(hist, 0, (size_t)NN * 4, stream);
        hipLaunchKernelGGL(k_hist, dim3(NE / 256), dim3(256), 0, stream, dstp, hist);
        hipLaunchKernelGGL(k_scan, dim3(1), dim3(256), 0, stream, hist, offs);
        hipLaunchKernelGGL(k_scatter, dim3(NE / 256), dim3(256), 0, stream,
                           srcp, dstp, ed, offs, src_s, dst_s, ed_s);
    }
    hipMemsetAsync(qstar, 0, (size_t)(NB * 64 + NB * 32 + NB * 32) * 4, stream);

    float* hcur = hA;
    float* hnxt = hB;
    unsigned short *hhic = hhiA, *hloc = hloA, *hhin = hhiB, *hlon = hloB;
    for (int t = 0; t < TST; ++t) {
        hipMemsetAsync(agg, 0, (size_t)NN * D * 4, stream);
        if (mfma7_path)
            hipLaunchKernelGGL(k_msg_mfma7, dim3(NE / 256), dim3(256), 0, stream,
                               ed_s, We1, be1, wth, wtl, hhic, hloc, src_s, dst_s, agg);
        else if (mfma_path)
            hipLaunchKernelGGL(k_msg_mfma, dim3(NE / 64), dim3(256), 0, stream,
                               ed, We1, be1, wth, wtl, hhic, hloc, srcp, dstp, agg);
        else
            hipLaunchKernelGGL(k_msg_fused, dim3(NE / 64), dim3(256), 0, stream,
                               ed, We1, be1, We2, hcur, srcp, dstp, agg);
        hipLaunchKernelGGL(k_gru, dim3(NN * D / 256), dim3(256), 0, stream,
                           hcur, agg, Wroot, bconv, gWih, gWhh, gbih, gbhh, hnxt,
                           mfma_path ? hhin : (unsigned short*)nullptr,
                           mfma_path ? hlon : (unsigned short*)nullptr);
        float* tf = hcur; hcur = hnxt; hnxt = tf;
        unsigned short* ts;
        ts = hhic; hhic = hhin; hhin = ts;
        ts = hloc; hloc = hlon; hlon = ts;
    }

    for (int s = 0; s < S2S; ++s)
        hipLaunchKernelGGL(k_s2s, dim3(NB), dim3(256), 0, stream,
                           hcur, gst, qstar, hl, cl, lWih, lWhh, lbih, lbhh, ebuf);

    hipLaunchKernelGGL(k_out, dim3(1), dim3(64), 0, stream, qstar, Wout, bout, out);
    (void)in_sizes; (void)n_in; (void)out_size;
}

// Round 10
// 2072.294 us; speedup vs baseline: 2.2342x; 1.3448x over previous
//
#include <hip/hip_runtime.h>
#include <hip/hip_bf16.h>

#define NN 20000   // nodes
#define NE 320000  // edges
#define NB 64      // graphs
#define DIN 16
#define DE 8
#define HE 128
#define D 32
#define TST 8
#define S2S 12

typedef __attribute__((ext_vector_type(8))) short short8x;   // 8 bf16 = 4 VGPRs (MFMA A/B frag)
typedef __attribute__((ext_vector_type(4))) float f32x4;     // MFMA C/D frag

__device__ __forceinline__ float sigf(float x) { return 1.f / (1.f + expf(-x)); }

__device__ __forceinline__ void split_bf16(float x, unsigned short& hi, unsigned short& lo) {
    __hip_bfloat16 h = __float2bfloat16(x);
    hi = *(unsigned short*)&h;
    float r = x - __bfloat162float(h);
    __hip_bfloat16 l = __float2bfloat16(r);
    lo = *(unsigned short*)&l;
}

// XOR-swizzled element offset of an A-frag within a 1024-el k-row of Wt.
__device__ __forceinline__ int swz_off(int eidx, int quad, int tile) {
    const int u = eidx * 4 + quad;
    const int s = u ^ ((u >> 3) & 7);
    return tile * 512 + s * 8;
}

// -------- graph segment starts: start[b] = lower_bound(batch, b), start[NB]=NN
__global__ void k_graph_start(const int* __restrict__ batch, int* __restrict__ start) {
    int b = threadIdx.x;
    if (b > NB) return;
    int lo = 0, hi = NN;
    while (lo < hi) {
        int mid = (lo + hi) >> 1;
        if (batch[mid] < b) lo = mid + 1; else hi = mid;
    }
    start[b] = lo;
}

// -------- Wt[k][swz(f,d)] = We2[k][d*32+f] (k<128), row 128 = be2; hi/lo bf16
__global__ __launch_bounds__(256) void k_prep_w(
    const float* __restrict__ We2, const float* __restrict__ be2,
    unsigned short* __restrict__ wth, unsigned short* __restrict__ wtl) {
    int idx = blockIdx.x * 256 + threadIdx.x;
    if (idx >= 129 * 1024) return;
    int k = idx >> 10, rem = idx & 1023, f = rem >> 5, d = rem & 31;
    float v = (k < 128) ? We2[k * 1024 + d * 32 + f] : be2[d * 32 + f];
    unsigned short hi, lo;
    split_bf16(v, hi, lo);
    const int pos = k * 1024 + swz_off(f & 15, d >> 3, f >> 4) + (d & 7);
    wth[pos] = hi;
    wtl[pos] = lo;
}

// -------- counting sort of edges by dst
__global__ __launch_bounds__(256) void k_hist(const int* __restrict__ dst, int* __restrict__ hist) {
    const int e = blockIdx.x * 256 + threadIdx.x;
    atomicAdd(&hist[dst[e]], 1);
}

__global__ __launch_bounds__(256) void k_scan(const int* __restrict__ hist, int* __restrict__ offs) {
    __shared__ int part[256];
    const int tid = threadIdx.x;
    const int base = tid * 79;  // 256*79 = 20224 >= NN
    int s = 0;
    for (int i = 0; i < 79; ++i) {
        const int b = base + i;
        if (b < NN) s += hist[b];
    }
    part[tid] = s;
    __syncthreads();
    if (tid == 0) {
        int a = 0;
        for (int i = 0; i < 256; ++i) { const int v = part[i]; part[i] = a; a += v; }
    }
    __syncthreads();
    int a = part[tid];
    for (int i = 0; i < 79; ++i) {
        const int b = base + i;
        if (b < NN) { offs[b] = a; a += hist[b]; }
    }
}

__global__ __launch_bounds__(256) void k_scatter(
    const int* __restrict__ src, const int* __restrict__ dst, const float* __restrict__ ed,
    int* __restrict__ offs, int* __restrict__ src_s, int* __restrict__ dst_s,
    float* __restrict__ ed_s) {
    const int e = blockIdx.x * 256 + threadIdx.x;
    const int d = dst[e];
    const int pos = atomicAdd(&offs[d], 1);
    src_s[pos] = src[e];
    dst_s[pos] = d;
    const float4 a = *(const float4*)(ed + (size_t)e * 8);
    const float4 b = *(const float4*)(ed + (size_t)e * 8 + 4);
    *(float4*)(ed_s + (size_t)pos * 8) = a;
    *(float4*)(ed_s + (size_t)pos * 8 + 4) = b;
}

// -------- h0 = x @ W_in + b_in  (+ optional bf16 hi/lo split emit)
__global__ __launch_bounds__(256) void k_input_linear(
    const float* __restrict__ x, const float* __restrict__ Win,
    const float* __restrict__ bin, float* __restrict__ h,
    unsigned short* __restrict__ hhi, unsigned short* __restrict__ hlo) {
    int idx = blockIdx.x * 256 + threadIdx.x;
    int n = idx >> 5, f = idx & 31;
    float acc = bin[f];
#pragma unroll
    for (int d = 0; d < DIN; ++d) acc += x[n * DIN + d] * Win[d * D + f];
    h[idx] = acc;
    if (hhi) {
        unsigned short hi, lo;
        split_bf16(acc, hi, lo);
        hhi[idx] = hi;
        hlo[idx] = lo;
    }
}

// -------- MFMA msg v8: R9's proven pipeline, 2-pass (W single bf16, h hi/lo).
// Per-chunk buffer: Whi 8K | z 4K = 12 KB, dbuf 24 KB; epilogue reuses region.
#define CHB 12288
__global__ __launch_bounds__(256, 3) void k_msg_mfma8(
    const float* __restrict__ ed_s, const float* __restrict__ We1,
    const float* __restrict__ be1,
    const unsigned short* __restrict__ wth,
    const unsigned short* __restrict__ hhi, const unsigned short* __restrict__ hlo,
    const int* __restrict__ src_s, const int* __restrict__ dst_s,
    float* __restrict__ agg) {
    const int tid = threadIdx.x;
    const int e0 = blockIdx.x * 256;

    __shared__ __align__(16) char sW[34048];   // 2*CHB pipeline | 256x33 f32 epilogue
    __shared__ float we1s[DE * HE];
    __shared__ float be1s[HE];
    __shared__ int dsl[256];

    const int lane = tid & 63;
    const int wv = tid >> 6;
    const int eidx = lane & 15;
    const int quad = lane >> 4;
    const int d0 = quad * 8;
    const int swz0 = swz_off(eidx, quad, 0);
    const int swz1 = swz_off(eidx, quad, 1);

    for (int i = tid; i < DE * HE; i += 256) we1s[i] = We1[i];
    if (tid < HE) be1s[tid] = be1[tid];
    dsl[tid] = dst_s[e0 + tid];

    const float4 ev0 = *(const float4*)(ed_s + (size_t)(e0 + tid) * 8);
    const float4 ev1 = *(const float4*)(ed_s + (size_t)(e0 + tid) * 8 + 4);
    float edr[8];
    edr[0] = ev0.x; edr[1] = ev0.y; edr[2] = ev0.z; edr[3] = ev0.w;
    edr[4] = ev1.x; edr[5] = ev1.y; edr[6] = ev1.z; edr[7] = ev1.w;

    short8x bhi[4], blo[4];
#pragma unroll
    for (int et = 0; et < 4; ++et) {
        const int e = e0 + wv * 64 + et * 16 + eidx;
        const size_t hb = (size_t)src_s[e] * 32 + d0;
        bhi[et] = *(const short8x*)(hhi + hb);
        blo[et] = *(const short8x*)(hlo + hb);
    }

    uint4 rh[2];
    auto gload = [&](int c) {
        const char* gh = (const char*)wth + (size_t)c * 8192;
#pragma unroll
        for (int r = 0; r < 2; ++r) rh[r] = *(const uint4*)(gh + r * 4096 + tid * 16);
    };
    auto lstore = [&](int b) {
        char* p = sW + b * CHB;
#pragma unroll
        for (int r = 0; r < 2; ++r) *(uint4*)(p + r * 4096 + tid * 16) = rh[r];
    };
    auto zstore = [&](int c, int b) {  // z for chunk c (4 k) -> buf b, thread = its edge
        float* zq = (float*)(sW + b * CHB + 8192);
#pragma unroll
        for (int m = 0; m < 4; ++m) {
            const int k = c * 4 + m;
            float acc = be1s[k];
#pragma unroll
            for (int j = 0; j < 8; ++j) acc += edr[j] * we1s[j * HE + k];
            zq[m * 256 + tid] = fmaxf(acc, 0.f);
        }
    };

    f32x4 macc[4][2];
#pragma unroll
    for (int et = 0; et < 4; ++et) {
        macc[et][0] = (f32x4){0.f, 0.f, 0.f, 0.f};
        macc[et][1] = (f32x4){0.f, 0.f, 0.f, 0.f};
    }

    gload(0);
    __syncthreads();   // we1s/be1s ready
    lstore(0);
    zstore(0, 0);
    gload(1);
    __syncthreads();   // buf0 visible

    for (int c = 0; c < 32; ++c) {
        const int b = c & 1;
        if (c + 1 < 32) { lstore(b ^ 1); zstore(c + 1, b ^ 1); }
        if (c + 2 < 32) gload(c + 2);

        const unsigned short* whp = (const unsigned short*)(sW + b * CHB);
        const float* zp = (const float*)(sW + b * CHB + 8192);
#pragma unroll
        for (int m = 0; m < 4; ++m) {
            float zk[4];
#pragma unroll
            for (int et = 0; et < 4; ++et) zk[et] = zp[m * 256 + wv * 64 + et * 16 + eidx];
            const int mb = m * 1024;
            const short8x fh0 = *(const short8x*)(whp + mb + swz0);
            const short8x fh1 = *(const short8x*)(whp + mb + swz1);
#pragma unroll
            for (int et = 0; et < 4; ++et) {
                f32x4 t0 = {0.f, 0.f, 0.f, 0.f}, t1 = {0.f, 0.f, 0.f, 0.f};
                t0 = __builtin_amdgcn_mfma_f32_16x16x32_bf16(fh0, bhi[et], t0, 0, 0, 0);
                t1 = __builtin_amdgcn_mfma_f32_16x16x32_bf16(fh1, bhi[et], t1, 0, 0, 0);
                t0 = __builtin_amdgcn_mfma_f32_16x16x32_bf16(fh0, blo[et], t0, 0, 0, 0);
                t1 = __builtin_amdgcn_mfma_f32_16x16x32_bf16(fh1, blo[et], t1, 0, 0, 0);
                macc[et][0] += zk[et] * t0;
                macc[et][1] += zk[et] * t1;
            }
        }
        __syncthreads();
    }

    {   // k = 128: be2 virtual row, z == 1; frags direct from global
        const unsigned short* bh = wth + 128 * 1024;
        const short8x fh0 = *(const short8x*)(bh + swz0);
        const short8x fh1 = *(const short8x*)(bh + swz1);
#pragma unroll
        for (int et = 0; et < 4; ++et) {
            f32x4 t0 = {0.f, 0.f, 0.f, 0.f}, t1 = {0.f, 0.f, 0.f, 0.f};
            t0 = __builtin_amdgcn_mfma_f32_16x16x32_bf16(fh0, bhi[et], t0, 0, 0, 0);
            t1 = __builtin_amdgcn_mfma_f32_16x16x32_bf16(fh1, bhi[et], t1, 0, 0, 0);
            t0 = __builtin_amdgcn_mfma_f32_16x16x32_bf16(fh0, blo[et], t0, 0, 0, 0);
            t1 = __builtin_amdgcn_mfma_f32_16x16x32_bf16(fh1, blo[et], t1, 0, 0, 0);
            macc[et][0] += t0;
            macc[et][1] += t1;
        }
    }

    // epilogue: stash msg in LDS, segmented reduction over dst-sorted runs
    float* msgb = (float*)sW;  // 256 x 33 floats = 33792 B <= 34048
    __syncthreads();
#pragma unroll
    for (int et = 0; et < 4; ++et) {
        const int eloc = wv * 64 + et * 16 + eidx;
        float* row = msgb + eloc * 33;
        row[quad * 4 + 0] = macc[et][0].x;
        row[quad * 4 + 1] = macc[et][0].y;
        row[quad * 4 + 2] = macc[et][0].z;
        row[quad * 4 + 3] = macc[et][0].w;
        row[16 + quad * 4 + 0] = macc[et][1].x;
        row[16 + quad * 4 + 1] = macc[et][1].y;
        row[16 + quad * 4 + 2] = macc[et][1].z;
        row[16 + quad * 4 + 3] = macc[et][1].w;
    }
    __syncthreads();

    const int g = tid >> 5, f = tid & 31;  // 8 groups x 32 edges each
    const int base = g * 32;
    float acc = 0.f;
    int cur = dsl[base];
    for (int i = 0; i < 32; ++i) {
        const int dnn = dsl[base + i];
        const float v = msgb[(base + i) * 33 + f];
        if (dnn != cur) {
            atomicAdd(&agg[(size_t)cur * 32 + f], acc);
            acc = 0.f;
            cur = dnn;
        }
        acc += v;
    }
    atomicAdd(&agg[(size_t)cur * 32 + f], acc);
}

// -------- MFMA msg v2 (fallback, base ws only): ring prefetch, z in regs, 3-pass
#define LDFRAG(slot, kk)                                          \
    do {                                                          \
        const unsigned short* _ph = wth + ((size_t)(kk) << 10);   \
        const unsigned short* _pl = wtl + ((size_t)(kk) << 10);   \
        ring[slot][0] = *(const short8x*)(_ph + b0);              \
        ring[slot][1] = *(const short8x*)(_ph + b1);              \
        ring[slot][2] = *(const short8x*)(_pl + b0);              \
        ring[slot][3] = *(const short8x*)(_pl + b1);              \
    } while (0)

__global__ __launch_bounds__(256) void k_msg_mfma(
    const float* __restrict__ ed, const float* __restrict__ We1,
    const float* __restrict__ be1,
    const unsigned short* __restrict__ wth, const unsigned short* __restrict__ wtl,
    const unsigned short* __restrict__ hhi, const unsigned short* __restrict__ hlo,
    const int* __restrict__ src, const int* __restrict__ dst,
    float* __restrict__ agg) {
    const int tid = threadIdx.x;
    const int e0 = blockIdx.x * 64;

    __shared__ float we1s[DE * HE];
    __shared__ float be1s[HE];

    for (int i = tid; i < DE * HE; i += 256) we1s[i] = We1[i];
    if (tid < HE) be1s[tid] = be1[tid];

    const int lane = tid & 63;
    const int wv = tid >> 6;
    const int eidx = lane & 15;
    const int quad = lane >> 4;
    const int eloc = wv * 16 + eidx;
    const int e = e0 + eloc;
    const int d0 = quad * 8;

    const int sn = src[e];
    const int dn = dst[e];

    const int b0 = swz_off(eidx, quad, 0);
    const int b1 = swz_off(eidx, quad, 1);

    const size_t hb = (size_t)sn * 32 + d0;
    const short8x bhi = *(const short8x*)(hhi + hb);
    const short8x blo = *(const short8x*)(hlo + hb);
    const float4 edv0 = *(const float4*)(ed + (size_t)e * 8);
    const float4 edv1 = *(const float4*)(ed + (size_t)e * 8 + 4);

    short8x ring[4][4];
    LDFRAG(0, 0);
    LDFRAG(1, 1);
    LDFRAG(2, 2);

    __syncthreads();

    float edr[8];
    edr[0] = edv0.x; edr[1] = edv0.y; edr[2] = edv0.z; edr[3] = edv0.w;
    edr[4] = edv1.x; edr[5] = edv1.y; edr[6] = edv1.z; edr[7] = edv1.w;
    float zreg[32];
#pragma unroll
    for (int m = 0; m < 32; ++m) {
        const int kk = (quad << 5) + m;
        float acc = be1s[kk];
#pragma unroll
        for (int j = 0; j < 8; ++j) acc += edr[j] * we1s[j * 128 + kk];
        zreg[m] = fmaxf(acc, 0.f);
    }

    f32x4 m0 = {0.f, 0.f, 0.f, 0.f}, m1 = {0.f, 0.f, 0.f, 0.f};

    for (int q = 0; q < 4; ++q) {
        const int bsrc = q * 16 + eidx;
#pragma unroll
        for (int m = 0; m < 32; ++m) {
            const int k = q * 32 + m;
            const int slot = m & 3;
            const int pslot = (m + 3) & 3;
            int kn = k + 3;
            kn = (kn > 128) ? 128 : kn;
            LDFRAG(pslot, kn);

            const float zk = __shfl(zreg[m], bsrc);

            f32x4 t0 = {0.f, 0.f, 0.f, 0.f}, t1 = {0.f, 0.f, 0.f, 0.f};
            t0 = __builtin_amdgcn_mfma_f32_16x16x32_bf16(ring[slot][0], bhi, t0, 0, 0, 0);
            t1 = __builtin_amdgcn_mfma_f32_16x16x32_bf16(ring[slot][1], bhi, t1, 0, 0, 0);
            t0 = __builtin_amdgcn_mfma_f32_16x16x32_bf16(ring[slot][2], bhi, t0, 0, 0, 0);
            t1 = __builtin_amdgcn_mfma_f32_16x16x32_bf16(ring[slot][3], bhi, t1, 0, 0, 0);
            t0 = __builtin_amdgcn_mfma_f32_16x16x32_bf16(ring[slot][0], blo, t0, 0, 0, 0);
            t1 = __builtin_amdgcn_mfma_f32_16x16x32_bf16(ring[slot][1], blo, t1, 0, 0, 0);

            m0 += zk * t0;
            m1 += zk * t1;
        }
    }
    {
        f32x4 t0 = {0.f, 0.f, 0.f, 0.f}, t1 = {0.f, 0.f, 0.f, 0.f};
        t0 = __builtin_amdgcn_mfma_f32_16x16x32_bf16(ring[0][0], bhi, t0, 0, 0, 0);
        t1 = __builtin_amdgcn_mfma_f32_16x16x32_bf16(ring[0][1], bhi, t1, 0, 0, 0);
        t0 = __builtin_amdgcn_mfma_f32_16x16x32_bf16(ring[0][2], bhi, t0, 0, 0, 0);
        t1 = __builtin_amdgcn_mfma_f32_16x16x32_bf16(ring[0][3], bhi, t1, 0, 0, 0);
        t0 = __builtin_amdgcn_mfma_f32_16x16x32_bf16(ring[0][0], blo, t0, 0, 0, 0);
        t1 = __builtin_amdgcn_mfma_f32_16x16x32_bf16(ring[0][1], blo, t1, 0, 0, 0);
        m0 += t0;
        m1 += t1;
    }

    float* ap = agg + (size_t)dn * 32 + quad * 4;
    atomicAdd(ap + 0, m0.x);
    atomicAdd(ap + 1, m0.y);
    atomicAdd(ap + 2, m0.z);
    atomicAdd(ap + 3, m0.w);
    atomicAdd(ap + 16 + 0, m1.x);
    atomicAdd(ap + 16 + 1, m1.y);
    atomicAdd(ap + 16 + 2, m1.z);
    atomicAdd(ap + 16 + 3, m1.w);
}

// -------- fallback (proven R2 path): recompute z per edge, fp32 VALU bilinear
__global__ __launch_bounds__(256) void k_msg_fused(
    const float* __restrict__ ed, const float* __restrict__ We1,
    const float* __restrict__ be1, const float* __restrict__ We2,
    const float* __restrict__ h, const int* __restrict__ src,
    const int* __restrict__ dst, float* __restrict__ agg) {
    const int tid = threadIdx.x;
    const int e0 = blockIdx.x * 64;
    __shared__ float we1s[DE * HE];
    __shared__ float be1s[HE];
    __shared__ float eds[64][9];
    __shared__ float zs[HE][64];
    __shared__ float hs[64][33];
    __shared__ float ws2s[4][1024];
    __shared__ int srcs[64];

    for (int i = tid; i < DE * HE; i += 256) we1s[i] = We1[i];
    if (tid < HE) be1s[tid] = be1[tid];
    if (tid < 64) srcs[tid] = src[e0 + tid];
    for (int i = tid; i < 64 * DE; i += 256) eds[i >> 3][i & 7] = ed[(size_t)e0 * DE + i];
    __syncthreads();

    {
        const int e = tid & 63, kb = tid >> 6;
        float edr[8];
#pragma unroll
        for (int j = 0; j < 8; ++j) edr[j] = eds[e][j];
        for (int m = 0; m < 32; ++m) {
            const int k = kb * 32 + m;
            float acc = be1s[k];
#pragma unroll
            for (int j = 0; j < 8; ++j) acc += edr[j] * we1s[j * HE + k];
            zs[k][e] = fmaxf(acc, 0.f);
        }
    }
    for (int i = tid; i < 64 * 32; i += 256) {
        const int e = i >> 5, d = i & 31;
        hs[e][d] = h[(size_t)srcs[e] * D + d];
    }
    __syncthreads();

    const int ep = tid & 31, fg = tid >> 5;
    float hr[2][32];
#pragma unroll
    for (int d = 0; d < 32; ++d) {
        hr[0][d] = hs[ep * 2][d];
        hr[1][d] = hs[ep * 2 + 1][d];
    }
    float acc[2][4];
#pragma unroll
    for (int i = 0; i < 2; ++i)
#pragma unroll
        for (int j = 0; j < 4; ++j) acc[i][j] = 0.f;

    for (int kc = 0; kc < 32; ++kc) {
        __syncthreads();
#pragma unroll
        for (int r = 0; r < 4; ++r) {
            const int idx4 = tid + 256 * r;
            const int kr = idx4 >> 8, c4 = idx4 & 255;
            *(float4*)&ws2s[kr][c4 * 4] =
                *(const float4*)(We2 + (size_t)(kc * 4 + kr) * 1024 + c4 * 4);
        }
        __syncthreads();
#pragma unroll
        for (int kk = 0; kk < 4; ++kk) {
            const int k = kc * 4 + kk;
            const float z0 = zs[k][ep * 2], z1 = zs[k][ep * 2 + 1];
#pragma unroll
            for (int d = 0; d < 32; ++d) {
                const float4 w4 = *(const float4*)&ws2s[kk][d * 32 + fg * 4];
                const float c0 = z0 * hr[0][d], c1 = z1 * hr[1][d];
                acc[0][0] += c0 * w4.x; acc[0][1] += c0 * w4.y;
                acc[0][2] += c0 * w4.z; acc[0][3] += c0 * w4.w;
                acc[1][0] += c1 * w4.x; acc[1][1] += c1 * w4.y;
                acc[1][2] += c1 * w4.z; acc[1][3] += c1 * w4.w;
            }
        }
    }
#pragma unroll
    for (int i = 0; i < 2; ++i) {
        const int e = e0 + ep * 2 + i;
        float* ap = &agg[(size_t)dst[e] * D + fg * 4];
#pragma unroll
        for (int j = 0; j < 4; ++j) atomicAdd(ap + j, acc[i][j]);
    }
}

// -------- GRU cell per node; reads agg then re-zeroes it (replaces memsets)
__global__ __launch_bounds__(256) void k_gru(
    const float* __restrict__ h, float* __restrict__ agg,
    const float* __restrict__ Wroot, const float* __restrict__ bconv,
    const float* __restrict__ Wih, const float* __restrict__ Whh,
    const float* __restrict__ bih, const float* __restrict__ bhh,
    float* __restrict__ hout,
    unsigned short* __restrict__ hhi, unsigned short* __restrict__ hlo) {
    const int idx = blockIdx.x * 256 + threadIdx.x;
    const int n = idx >> 5, f = idx & 31, nl = threadIdx.x >> 5;
    __shared__ float hsh[8][33], msh[8][33];
    const float hv = h[n * D + f];
    hsh[nl][f] = hv;
    __syncthreads();
    float m = bconv[f] + agg[n * D + f];
    agg[n * D + f] = 0.f;  // re-zero for next msg step
#pragma unroll
    for (int d = 0; d < 32; ++d) m += hsh[nl][d] * Wroot[d * D + f];
    m = fmaxf(m, 0.f);
    msh[nl][f] = m;
    __syncthreads();
    float gir = bih[f], giz = bih[D + f], gin = bih[2 * D + f];
    float ghr = bhh[f], ghz = bhh[D + f], ghn = bhh[2 * D + f];
#pragma unroll
    for (int d = 0; d < 32; ++d) {
        const float md = msh[nl][d], hd = hsh[nl][d];
        gir += md * Wih[f * D + d];
        giz += md * Wih[(D + f) * D + d];
        gin += md * Wih[(2 * D + f) * D + d];
        ghr += hd * Whh[f * D + d];
        ghz += hd * Whh[(D + f) * D + d];
        ghn += hd * Whh[(2 * D + f) * D + d];
    }
    const float r = sigf(gir + ghr);
    const float z = sigf(giz + ghz);
    const float nn2 = tanhf(gin + r * ghn);
    const float ho = (1.f - z) * nn2 + z * hv;
    hout[n * D + f] = ho;
    if (hhi) {
        unsigned short hi, lo;
        split_bf16(ho, hi, lo);
        hhi[idx] = hi;
        hlo[idx] = lo;
    }
}

// -------- all 12 Set2Set steps in ONE kernel: block = graph, state in LDS
__global__ __launch_bounds__(256) void k_s2s_all(
    const float* __restrict__ h, const int* __restrict__ start,
    float* __restrict__ qstar_out,
    const float* __restrict__ Wih, const float* __restrict__ Whh,
    const float* __restrict__ bih, const float* __restrict__ bhh,
    float* __restrict__ ebuf) {
    const int b = blockIdx.x, t = threadIdx.x;
    __shared__ float qst[64], hls[32], cls[32], gates[128], qs[32];
    __shared__ float red[256];
    __shared__ float rsum[8][33];
    if (t < 64) qst[t] = 0.f;
    if (t < 32) { hls[t] = 0.f; cls[t] = 0.f; }
    const int s0 = start[b], s1 = start[b + 1];
    __syncthreads();

    for (int s = 0; s < S2S; ++s) {
        if (t < 128) {
            float g = bih[t] + bhh[t];
#pragma unroll 8
            for (int j = 0; j < 64; ++j) g += qst[j] * Wih[t * 64 + j];
#pragma unroll 8
            for (int j = 0; j < 32; ++j) g += hls[j] * Whh[t * 32 + j];
            gates[t] = g;
        }
        __syncthreads();
        if (t < 32) {  // i,f,g,o order
            const float ig = sigf(gates[t]);
            const float fg = sigf(gates[32 + t]);
            const float gg = tanhf(gates[64 + t]);
            const float og = sigf(gates[96 + t]);
            const float c = fg * cls[t] + ig * gg;
            const float q = og * tanhf(c);
            cls[t] = c;
            hls[t] = q;
            qst[t] = q;
            qs[t] = q;
        }
        __syncthreads();
        float lmax = -3.4e38f;
        for (int n = s0 + t; n < s1; n += 256) {
            const float4* hv = (const float4*)(h + (size_t)n * D);
            float e = 0.f;
#pragma unroll
            for (int u = 0; u < 8; ++u) {
                const float4 v = hv[u];
                e += v.x * qs[u * 4] + v.y * qs[u * 4 + 1] + v.z * qs[u * 4 + 2] + v.w * qs[u * 4 + 3];
            }
            ebuf[n] = e;
            lmax = fmaxf(lmax, e);
        }
        red[t] = lmax;
        __syncthreads();
        for (int r2 = 128; r2 > 0; r2 >>= 1) {
            if (t < r2) red[t] = fmaxf(red[t], red[t + r2]);
            __syncthreads();
        }
        const float smax = red[0];
        __syncthreads();
        float lsum = 0.f;
        for (int n = s0 + t; n < s1; n += 256) {
            const float w = expf(ebuf[n] - smax);
            ebuf[n] = w;
            lsum += w;
        }
        red[t] = lsum;
        __syncthreads();
        for (int r2 = 128; r2 > 0; r2 >>= 1) {
            if (t < r2) red[t] += red[t + r2];
            __syncthreads();
        }
        const float den = red[0];
        const float inv = (den > 0.f) ? 1.f / den : 0.f;
        const int fl = t & 31, sl = t >> 5;
        float racc = 0.f;
        for (int n = s0 + sl; n < s1; n += 8) racc += ebuf[n] * h[(size_t)n * D + fl];
        rsum[sl][fl] = racc;
        __syncthreads();
        if (sl == 0) {
            float rv = 0.f;
#pragma unroll
            for (int u = 0; u < 8; ++u) rv += rsum[u][fl];
            qst[32 + fl] = rv * inv;
        }
        __syncthreads();  // qst[32..63] visible before next gates phase
    }

    if (t < 64) qstar_out[b * 64 + t] = qst[t];
}

// -------- out = q_star @ W_out + b_out
__global__ void k_out(const float* __restrict__ qstar, const float* __restrict__ Wout,
                      const float* __restrict__ bout, float* __restrict__ out) {
    int b = threadIdx.x;
    if (b < NB) {
        float acc = bout[0];
#pragma unroll 8
        for (int j = 0; j < 64; ++j) acc += qstar[b * 64 + j] * Wout[j];
        out[b] = acc;
    }
}

extern "C" void kernel_launch(void* const* d_in, const int* in_sizes, int n_in,
                              void* d_out, int out_size, void* d_ws, size_t ws_size,
                              hipStream_t stream) {
    const float* x     = (const float*)d_in[0];
    const float* ed    = (const float*)d_in[3];
    const int*   edges = (const int*)d_in[4];
    const int*   batch = (const int*)d_in[5];
    const float* Wi    = (const float*)d_in[6];
    const float* bi    = (const float*)d_in[7];
    const float* We1   = (const float*)d_in[8];
    const float* be1   = (const float*)d_in[9];
    const float* We2   = (const float*)d_in[10];
    const float* be2   = (const float*)d_in[11];
    const float* Wroot = (const float*)d_in[12];
    const float* bconv = (const float*)d_in[13];
    const float* gWih  = (const float*)d_in[14];
    const float* gWhh  = (const float*)d_in[15];
    const float* gbih  = (const float*)d_in[16];
    const float* gbhh  = (const float*)d_in[17];
    const float* lWih  = (const float*)d_in[18];
    const float* lWhh  = (const float*)d_in[19];
    const float* lbih  = (const float*)d_in[20];
    const float* lbhh  = (const float*)d_in[21];
    const float* Wout  = (const float*)d_in[22];
    const float* bout  = (const float*)d_in[23];
    float* out = (float*)d_out;

    const int* srcp = edges;
    const int* dstp = edges + NE;

    char* ws = (char*)d_ws;
    size_t off = 0;
    auto alloc = [&](size_t bytes) -> char* {
        char* p = ws + off;
        off += (bytes + 255) & ~(size_t)255;
        return p;
    };
    float* hA    = (float*)alloc((size_t)NN * D * 4);
    float* hB    = (float*)alloc((size_t)NN * D * 4);
    float* agg   = (float*)alloc((size_t)NN * D * 4);
    float* ebuf  = (float*)alloc((size_t)NN * 4);
    float* qstar = (float*)alloc((size_t)NB * 64 * 4);
    int*   gst   = (int*)alloc((NB + 1) * 4);
    unsigned short* hhiA = (unsigned short*)alloc((size_t)NN * D * 2);
    unsigned short* hloA = (unsigned short*)alloc((size_t)NN * D * 2);
    unsigned short* hhiB = (unsigned short*)alloc((size_t)NN * D * 2);
    unsigned short* hloB = (unsigned short*)alloc((size_t)NN * D * 2);
    unsigned short* wth  = (unsigned short*)alloc((size_t)129 * 1024 * 2);
    unsigned short* wtl  = (unsigned short*)alloc((size_t)129 * 1024 * 2);
    const size_t base_off = off;
    const bool mfma_path = (ws_size >= base_off);
    // sorted-edge extras (~14 MB)
    int*   hist  = (int*)alloc((size_t)NN * 4);
    int*   offs  = (int*)alloc((size_t)NN * 4);
    int*   src_s = (int*)alloc((size_t)NE * 4);
    int*   dst_s = (int*)alloc((size_t)NE * 4);
    float* ed_s  = (float*)alloc((size_t)NE * 8 * 4);
    const bool mfma8_path = (ws_size >= off);

    hipLaunchKernelGGL(k_graph_start, dim3(1), dim3(128), 0, stream, batch, gst);
    hipLaunchKernelGGL(k_input_linear, dim3(NN * D / 256), dim3(256), 0, stream, x, Wi, bi, hA,
                       mfma_path ? hhiA : (unsigned short*)nullptr,
                       mfma_path ? hloA : (unsigned short*)nullptr);
    if (mfma_path)
        hipLaunchKernelGGL(k_prep_w, dim3((129 * 1024 + 255) / 256), dim3(256), 0, stream,
                           We2, be2, wth, wtl);
    if (mfma8_path) {
        hipMemsetAsync(hist, 0, (size_t)NN * 4, stream);
        hipLaunchKernelGGL(k_hist, dim3(NE / 256), dim3(256), 0, stream, dstp, hist);
        hipLaunchKernelGGL(k_scan, dim3(1), dim3(256), 0, stream, hist, offs);
        hipLaunchKernelGGL(k_scatter, dim3(NE / 256), dim3(256), 0, stream,
                           srcp, dstp, ed, offs, src_s, dst_s, ed_s);
    }
    hipMemsetAsync(agg, 0, (size_t)NN * D * 4, stream);  // once; k_gru re-zeroes

    float* hcur = hA;
    float* hnxt = hB;
    unsigned short *hhic = hhiA, *hloc = hloA, *hhin = hhiB, *hlon = hloB;
    for (int t = 0; t < TST; ++t) {
        if (mfma8_path)
            hipLaunchKernelGGL(k_msg_mfma8, dim3(NE / 256), dim3(256), 0, stream,
                               ed_s, We1, be1, wth, hhic, hloc, src_s, dst_s, agg);
        else if (mfma_path)
            hipLaunchKernelGGL(k_msg_mfma, dim3(NE / 64), dim3(256), 0, stream,
                               ed, We1, be1, wth, wtl, hhic, hloc, srcp, dstp, agg);
        else
            hipLaunchKernelGGL(k_msg_fused, dim3(NE / 64), dim3(256), 0, stream,
                               ed, We1, be1, We2, hcur, srcp, dstp, agg);
        hipLaunchKernelGGL(k_gru, dim3(NN * D / 256), dim3(256), 0, stream,
                           hcur, agg, Wroot, bconv, gWih, gWhh, gbih, gbhh, hnxt,
                           mfma_path ? hhin : (unsigned short*)nullptr,
                           mfma_path ? hlon : (unsigned short*)nullptr);
        float* tf = hcur; hcur = hnxt; hnxt = tf;
        unsigned short* ts;
        ts = hhic; hhic = hhin; hhin = ts;
        ts = hloc; hloc = hlon; hlon = ts;
    }

    hipLaunchKernelGGL(k_s2s_all, dim3(NB), dim3(256), 0, stream,
                       hcur, gst, qstar, lWih, lWhh, lbih, lbhh, ebuf);

    hipLaunchKernelGGL(k_out, dim3(1), dim3(64), 0, stream, qstar, Wout, bout, out);
    (void)in_sizes; (void)n_in; (void)out_size;
}

// Round 11
// 1933.899 us; speedup vs baseline: 2.3940x; 1.0716x over previous
//
#include <hip/hip_runtime.h>
#include <hip/hip_bf16.h>

#define NN 20000   // nodes
#define NE 320000  // edges
#define NB 64      // graphs
#define DIN 16
#define DE 8
#define HE 128
#define D 32
#define TST 8
#define S2S 12

typedef __attribute__((ext_vector_type(8))) short short8x;   // 8 bf16 = 4 VGPRs (MFMA A/B frag)
typedef __attribute__((ext_vector_type(4))) float f32x4;     // MFMA C/D frag

__device__ __forceinline__ float sigf(float x) { return 1.f / (1.f + expf(-x)); }

__device__ __forceinline__ void split_bf16(float x, unsigned short& hi, unsigned short& lo) {
    __hip_bfloat16 h = __float2bfloat16(x);
    hi = *(unsigned short*)&h;
    float r = x - __bfloat162float(h);
    __hip_bfloat16 l = __float2bfloat16(r);
    lo = *(unsigned short*)&l;
}

// XOR-swizzled element offset of an A-frag within a 1024-el k-row of Wt.
__device__ __forceinline__ int swz_off(int eidx, int quad, int tile) {
    const int u = eidx * 4 + quad;
    const int s = u ^ ((u >> 3) & 7);
    return tile * 512 + s * 8;
}

// -------- graph segment starts: start[b] = lower_bound(batch, b), start[NB]=NN
__global__ void k_graph_start(const int* __restrict__ batch, int* __restrict__ start) {
    int b = threadIdx.x;
    if (b > NB) return;
    int lo = 0, hi = NN;
    while (lo < hi) {
        int mid = (lo + hi) >> 1;
        if (batch[mid] < b) lo = mid + 1; else hi = mid;
    }
    start[b] = lo;
}

// -------- Wt[k][swz(f,d)] = We2[k][d*32+f] (k<128), row 128 = be2; hi/lo bf16
__global__ __launch_bounds__(256) void k_prep_w(
    const float* __restrict__ We2, const float* __restrict__ be2,
    unsigned short* __restrict__ wth, unsigned short* __restrict__ wtl) {
    int idx = blockIdx.x * 256 + threadIdx.x;
    if (idx >= 129 * 1024) return;
    int k = idx >> 10, rem = idx & 1023, f = rem >> 5, d = rem & 31;
    float v = (k < 128) ? We2[k * 1024 + d * 32 + f] : be2[d * 32 + f];
    unsigned short hi, lo;
    split_bf16(v, hi, lo);
    const int pos = k * 1024 + swz_off(f & 15, d >> 3, f >> 4) + (d & 7);
    wth[pos] = hi;
    wtl[pos] = lo;
}

// -------- counting sort of edges by dst
__global__ __launch_bounds__(256) void k_hist(const int* __restrict__ dst, int* __restrict__ hist) {
    const int e = blockIdx.x * 256 + threadIdx.x;
    atomicAdd(&hist[dst[e]], 1);
}

__global__ __launch_bounds__(256) void k_scan(const int* __restrict__ hist, int* __restrict__ offs) {
    __shared__ int part[256];
    const int tid = threadIdx.x;
    const int base = tid * 79;  // 256*79 = 20224 >= NN
    int s = 0;
    for (int i = 0; i < 79; ++i) {
        const int b = base + i;
        if (b < NN) s += hist[b];
    }
    part[tid] = s;
    __syncthreads();
    if (tid == 0) {
        int a = 0;
        for (int i = 0; i < 256; ++i) { const int v = part[i]; part[i] = a; a += v; }
    }
    __syncthreads();
    int a = part[tid];
    for (int i = 0; i < 79; ++i) {
        const int b = base + i;
        if (b < NN) { offs[b] = a; a += hist[b]; }
    }
}

__global__ __launch_bounds__(256) void k_scatter(
    const int* __restrict__ src, const int* __restrict__ dst, const float* __restrict__ ed,
    int* __restrict__ offs, int* __restrict__ src_s, int* __restrict__ dst_s,
    float* __restrict__ ed_s) {
    const int e = blockIdx.x * 256 + threadIdx.x;
    const int d = dst[e];
    const int pos = atomicAdd(&offs[d], 1);
    src_s[pos] = src[e];
    dst_s[pos] = d;
    const float4 a = *(const float4*)(ed + (size_t)e * 8);
    const float4 b = *(const float4*)(ed + (size_t)e * 8 + 4);
    *(float4*)(ed_s + (size_t)pos * 8) = a;
    *(float4*)(ed_s + (size_t)pos * 8 + 4) = b;
}

// -------- h0 = x @ W_in + b_in  (+ optional bf16 hi/lo split emit)
__global__ __launch_bounds__(256) void k_input_linear(
    const float* __restrict__ x, const float* __restrict__ Win,
    const float* __restrict__ bin, float* __restrict__ h,
    unsigned short* __restrict__ hhi, unsigned short* __restrict__ hlo) {
    int idx = blockIdx.x * 256 + threadIdx.x;
    int n = idx >> 5, f = idx & 31;
    float acc = bin[f];
#pragma unroll
    for (int d = 0; d < DIN; ++d) acc += x[n * DIN + d] * Win[d * D + f];
    h[idx] = acc;
    if (hhi) {
        unsigned short hi, lo;
        split_bf16(acc, hi, lo);
        hhi[idx] = hi;
        hlo[idx] = lo;
    }
}

// -------- MFMA msg v9: barrier-free K-loop. W frags direct from global (L2-hot,
// 4-deep register ring, distance-3 prefetch); z per 8-k chunk in registers
// (lane = its edge) distributed via __shfl; 4 e-tiles x 2-pass = 16 MFMA per
// 2 loads. Sorted edges + wave-private LDS segmented-reduce epilogue.
__global__ __launch_bounds__(256, 3) void k_msg_mfma9(
    const float* __restrict__ ed_s, const float* __restrict__ We1,
    const float* __restrict__ be1,
    const unsigned short* __restrict__ wth,
    const unsigned short* __restrict__ hhi, const unsigned short* __restrict__ hlo,
    const int* __restrict__ src_s, const int* __restrict__ dst_s,
    float* __restrict__ agg) {
    const int tid = threadIdx.x;
    const int e0 = blockIdx.x * 256;

    __shared__ float msgb[256 * 33];  // 33792 B, epilogue only
    __shared__ float we1s[DE * HE];   // 4 KB
    __shared__ float be1s[HE];
    __shared__ int dsl[256];

    const int lane = tid & 63;
    const int wv = tid >> 6;
    const int eidx = lane & 15;
    const int quad = lane >> 4;
    const int d0 = quad * 8;
    const int swz0 = swz_off(eidx, quad, 0);
    const int swz1 = swz_off(eidx, quad, 1);

    for (int i = tid; i < DE * HE; i += 256) we1s[i] = We1[i];
    if (tid < HE) be1s[tid] = be1[tid];
    dsl[tid] = dst_s[e0 + tid];

    // per-thread edge row (lane l of wave wv <-> edge e0 + wv*64 + l)
    const float4 ev0 = *(const float4*)(ed_s + (size_t)(e0 + tid) * 8);
    const float4 ev1 = *(const float4*)(ed_s + (size_t)(e0 + tid) * 8 + 4);
    float edr[8];
    edr[0] = ev0.x; edr[1] = ev0.y; edr[2] = ev0.z; edr[3] = ev0.w;
    edr[4] = ev1.x; edr[5] = ev1.y; edr[6] = ev1.z; edr[7] = ev1.w;

    // B-frags (h hi/lo) for 4 e-tiles
    short8x bhi[4], blo[4];
#pragma unroll
    for (int et = 0; et < 4; ++et) {
        const int e = e0 + wv * 64 + et * 16 + eidx;
        const size_t hb = (size_t)src_s[e] * 32 + d0;
        bhi[et] = *(const short8x*)(hhi + hb);
        blo[et] = *(const short8x*)(hlo + hb);
    }

    // 4-deep W-frag register ring, direct from global (L2-resident)
    short8x ring[4][2];
#define LDW(slot, kk)                                                  \
    do {                                                               \
        const unsigned short* _p = wth + ((size_t)(kk) << 10);         \
        ring[slot][0] = *(const short8x*)(_p + swz0);                  \
        ring[slot][1] = *(const short8x*)(_p + swz1);                  \
    } while (0)
    LDW(0, 0);
    LDW(1, 1);
    LDW(2, 2);

    f32x4 macc[4][2];
#pragma unroll
    for (int et = 0; et < 4; ++et) {
        macc[et][0] = (f32x4){0.f, 0.f, 0.f, 0.f};
        macc[et][1] = (f32x4){0.f, 0.f, 0.f, 0.f};
    }

    __syncthreads();  // we1s/be1s/dsl visible; ONLY barrier before epilogue

#pragma unroll 1
    for (int c = 0; c < 16; ++c) {
        // z for this chunk's 8 k, this lane's edge (exact fp32, same order as R10)
        float zreg[8];
#pragma unroll
        for (int m = 0; m < 8; ++m) {
            const int k = c * 8 + m;
            float acc = be1s[k];
#pragma unroll
            for (int j = 0; j < 8; ++j) acc += edr[j] * we1s[j * HE + k];
            zreg[m] = fmaxf(acc, 0.f);
        }
#pragma unroll
        for (int m = 0; m < 8; ++m) {
            const int k = c * 8 + m;
            const int slot = m & 3;          // == k & 3 (8 ≡ 0 mod 4)
            const int pslot = (m + 3) & 3;
            int kn = k + 3;
            kn = (kn > 128) ? 128 : kn;
            LDW(pslot, kn);

            const short8x fh0 = ring[slot][0];
            const short8x fh1 = ring[slot][1];
#pragma unroll
            for (int et = 0; et < 4; ++et) {
                const float zk = __shfl(zreg[m], et * 16 + eidx);
                f32x4 t0 = {0.f, 0.f, 0.f, 0.f}, t1 = {0.f, 0.f, 0.f, 0.f};
                t0 = __builtin_amdgcn_mfma_f32_16x16x32_bf16(fh0, bhi[et], t0, 0, 0, 0);
                t1 = __builtin_amdgcn_mfma_f32_16x16x32_bf16(fh1, bhi[et], t1, 0, 0, 0);
                t0 = __builtin_amdgcn_mfma_f32_16x16x32_bf16(fh0, blo[et], t0, 0, 0, 0);
                t1 = __builtin_amdgcn_mfma_f32_16x16x32_bf16(fh1, blo[et], t1, 0, 0, 0);
                macc[et][0] += zk * t0;
                macc[et][1] += zk * t1;
            }
        }
    }

    {   // k = 128: be2 virtual row, z == 1; slot 0 holds k=128 (prefetched @k=125)
        const short8x fh0 = ring[0][0];
        const short8x fh1 = ring[0][1];
#pragma unroll
        for (int et = 0; et < 4; ++et) {
            f32x4 t0 = {0.f, 0.f, 0.f, 0.f}, t1 = {0.f, 0.f, 0.f, 0.f};
            t0 = __builtin_amdgcn_mfma_f32_16x16x32_bf16(fh0, bhi[et], t0, 0, 0, 0);
            t1 = __builtin_amdgcn_mfma_f32_16x16x32_bf16(fh1, bhi[et], t1, 0, 0, 0);
            t0 = __builtin_amdgcn_mfma_f32_16x16x32_bf16(fh0, blo[et], t0, 0, 0, 0);
            t1 = __builtin_amdgcn_mfma_f32_16x16x32_bf16(fh1, blo[et], t1, 0, 0, 0);
            macc[et][0] += t0;
            macc[et][1] += t1;
        }
    }
#undef LDW

    // epilogue: stash msg rows (wave-private), segmented reduce over sorted dst
#pragma unroll
    for (int et = 0; et < 4; ++et) {
        const int eloc = wv * 64 + et * 16 + eidx;
        float* row = msgb + eloc * 33;
        row[quad * 4 + 0] = macc[et][0].x;
        row[quad * 4 + 1] = macc[et][0].y;
        row[quad * 4 + 2] = macc[et][0].z;
        row[quad * 4 + 3] = macc[et][0].w;
        row[16 + quad * 4 + 0] = macc[et][1].x;
        row[16 + quad * 4 + 1] = macc[et][1].y;
        row[16 + quad * 4 + 2] = macc[et][1].z;
        row[16 + quad * 4 + 3] = macc[et][1].w;
    }
    __syncthreads();  // cheap insurance: all msgb writes visible for the reduce

    const int g = tid >> 5, f = tid & 31;  // 8 groups x 32 edges each
    const int base = g * 32;
    float acc = 0.f;
    int cur = dsl[base];
    for (int i = 0; i < 32; ++i) {
        const int dnn = dsl[base + i];
        const float v = msgb[(base + i) * 33 + f];
        if (dnn != cur) {
            atomicAdd(&agg[(size_t)cur * 32 + f], acc);
            acc = 0.f;
            cur = dnn;
        }
        acc += v;
    }
    atomicAdd(&agg[(size_t)cur * 32 + f], acc);
}

// -------- MFMA msg v2 (fallback, base ws only): ring prefetch, z in regs, 3-pass
#define LDFRAG(slot, kk)                                          \
    do {                                                          \
        const unsigned short* _ph = wth + ((size_t)(kk) << 10);   \
        const unsigned short* _pl = wtl + ((size_t)(kk) << 10);   \
        ring[slot][0] = *(const short8x*)(_ph + b0);              \
        ring[slot][1] = *(const short8x*)(_ph + b1);              \
        ring[slot][2] = *(const short8x*)(_pl + b0);              \
        ring[slot][3] = *(const short8x*)(_pl + b1);              \
    } while (0)

__global__ __launch_bounds__(256) void k_msg_mfma(
    const float* __restrict__ ed, const float* __restrict__ We1,
    const float* __restrict__ be1,
    const unsigned short* __restrict__ wth, const unsigned short* __restrict__ wtl,
    const unsigned short* __restrict__ hhi, const unsigned short* __restrict__ hlo,
    const int* __restrict__ src, const int* __restrict__ dst,
    float* __restrict__ agg) {
    const int tid = threadIdx.x;
    const int e0 = blockIdx.x * 64;

    __shared__ float we1s[DE * HE];
    __shared__ float be1s[HE];

    for (int i = tid; i < DE * HE; i += 256) we1s[i] = We1[i];
    if (tid < HE) be1s[tid] = be1[tid];

    const int lane = tid & 63;
    const int wv = tid >> 6;
    const int eidx = lane & 15;
    const int quad = lane >> 4;
    const int eloc = wv * 16 + eidx;
    const int e = e0 + eloc;
    const int d0 = quad * 8;

    const int sn = src[e];
    const int dn = dst[e];

    const int b0 = swz_off(eidx, quad, 0);
    const int b1 = swz_off(eidx, quad, 1);

    const size_t hb = (size_t)sn * 32 + d0;
    const short8x bhi = *(const short8x*)(hhi + hb);
    const short8x blo = *(const short8x*)(hlo + hb);
    const float4 edv0 = *(const float4*)(ed + (size_t)e * 8);
    const float4 edv1 = *(const float4*)(ed + (size_t)e * 8 + 4);

    short8x ring[4][4];
    LDFRAG(0, 0);
    LDFRAG(1, 1);
    LDFRAG(2, 2);

    __syncthreads();

    float edr[8];
    edr[0] = edv0.x; edr[1] = edv0.y; edr[2] = edv0.z; edr[3] = edv0.w;
    edr[4] = edv1.x; edr[5] = edv1.y; edr[6] = edv1.z; edr[7] = edv1.w;
    float zreg[32];
#pragma unroll
    for (int m = 0; m < 32; ++m) {
        const int kk = (quad << 5) + m;
        float acc = be1s[kk];
#pragma unroll
        for (int j = 0; j < 8; ++j) acc += edr[j] * we1s[j * 128 + kk];
        zreg[m] = fmaxf(acc, 0.f);
    }

    f32x4 m0 = {0.f, 0.f, 0.f, 0.f}, m1 = {0.f, 0.f, 0.f, 0.f};

    for (int q = 0; q < 4; ++q) {
        const int bsrc = q * 16 + eidx;
#pragma unroll
        for (int m = 0; m < 32; ++m) {
            const int k = q * 32 + m;
            const int slot = m & 3;
            const int pslot = (m + 3) & 3;
            int kn = k + 3;
            kn = (kn > 128) ? 128 : kn;
            LDFRAG(pslot, kn);

            const float zk = __shfl(zreg[m], bsrc);

            f32x4 t0 = {0.f, 0.f, 0.f, 0.f}, t1 = {0.f, 0.f, 0.f, 0.f};
            t0 = __builtin_amdgcn_mfma_f32_16x16x32_bf16(ring[slot][0], bhi, t0, 0, 0, 0);
            t1 = __builtin_amdgcn_mfma_f32_16x16x32_bf16(ring[slot][1], bhi, t1, 0, 0, 0);
            t0 = __builtin_amdgcn_mfma_f32_16x16x32_bf16(ring[slot][2], bhi, t0, 0, 0, 0);
            t1 = __builtin_amdgcn_mfma_f32_16x16x32_bf16(ring[slot][3], bhi, t1, 0, 0, 0);
            t0 = __builtin_amdgcn_mfma_f32_16x16x32_bf16(ring[slot][0], blo, t0, 0, 0, 0);
            t1 = __builtin_amdgcn_mfma_f32_16x16x32_bf16(ring[slot][1], blo, t1, 0, 0, 0);

            m0 += zk * t0;
            m1 += zk * t1;
        }
    }
    {
        f32x4 t0 = {0.f, 0.f, 0.f, 0.f}, t1 = {0.f, 0.f, 0.f, 0.f};
        t0 = __builtin_amdgcn_mfma_f32_16x16x32_bf16(ring[0][0], bhi, t0, 0, 0, 0);
        t1 = __builtin_amdgcn_mfma_f32_16x16x32_bf16(ring[0][1], bhi, t1, 0, 0, 0);
        t0 = __builtin_amdgcn_mfma_f32_16x16x32_bf16(ring[0][2], bhi, t0, 0, 0, 0);
        t1 = __builtin_amdgcn_mfma_f32_16x16x32_bf16(ring[0][3], bhi, t1, 0, 0, 0);
        t0 = __builtin_amdgcn_mfma_f32_16x16x32_bf16(ring[0][0], blo, t0, 0, 0, 0);
        t1 = __builtin_amdgcn_mfma_f32_16x16x32_bf16(ring[0][1], blo, t1, 0, 0, 0);
        m0 += t0;
        m1 += t1;
    }

    float* ap = agg + (size_t)dn * 32 + quad * 4;
    atomicAdd(ap + 0, m0.x);
    atomicAdd(ap + 1, m0.y);
    atomicAdd(ap + 2, m0.z);
    atomicAdd(ap + 3, m0.w);
    atomicAdd(ap + 16 + 0, m1.x);
    atomicAdd(ap + 16 + 1, m1.y);
    atomicAdd(ap + 16 + 2, m1.z);
    atomicAdd(ap + 16 + 3, m1.w);
}

// -------- fallback (proven R2 path): recompute z per edge, fp32 VALU bilinear
__global__ __launch_bounds__(256) void k_msg_fused(
    const float* __restrict__ ed, const float* __restrict__ We1,
    const float* __restrict__ be1, const float* __restrict__ We2,
    const float* __restrict__ h, const int* __restrict__ src,
    const int* __restrict__ dst, float* __restrict__ agg) {
    const int tid = threadIdx.x;
    const int e0 = blockIdx.x * 64;
    __shared__ float we1s[DE * HE];
    __shared__ float be1s[HE];
    __shared__ float eds[64][9];
    __shared__ float zs[HE][64];
    __shared__ float hs[64][33];
    __shared__ float ws2s[4][1024];
    __shared__ int srcs[64];

    for (int i = tid; i < DE * HE; i += 256) we1s[i] = We1[i];
    if (tid < HE) be1s[tid] = be1[tid];
    if (tid < 64) srcs[tid] = src[e0 + tid];
    for (int i = tid; i < 64 * DE; i += 256) eds[i >> 3][i & 7] = ed[(size_t)e0 * DE + i];
    __syncthreads();

    {
        const int e = tid & 63, kb = tid >> 6;
        float edr[8];
#pragma unroll
        for (int j = 0; j < 8; ++j) edr[j] = eds[e][j];
        for (int m = 0; m < 32; ++m) {
            const int k = kb * 32 + m;
            float acc = be1s[k];
#pragma unroll
            for (int j = 0; j < 8; ++j) acc += edr[j] * we1s[j * HE + k];
            zs[k][e] = fmaxf(acc, 0.f);
        }
    }
    for (int i = tid; i < 64 * 32; i += 256) {
        const int e = i >> 5, d = i & 31;
        hs[e][d] = h[(size_t)srcs[e] * D + d];
    }
    __syncthreads();

    const int ep = tid & 31, fg = tid >> 5;
    float hr[2][32];
#pragma unroll
    for (int d = 0; d < 32; ++d) {
        hr[0][d] = hs[ep * 2][d];
        hr[1][d] = hs[ep * 2 + 1][d];
    }
    float acc[2][4];
#pragma unroll
    for (int i = 0; i < 2; ++i)
#pragma unroll
        for (int j = 0; j < 4; ++j) acc[i][j] = 0.f;

    for (int kc = 0; kc < 32; ++kc) {
        __syncthreads();
#pragma unroll
        for (int r = 0; r < 4; ++r) {
            const int idx4 = tid + 256 * r;
            const int kr = idx4 >> 8, c4 = idx4 & 255;
            *(float4*)&ws2s[kr][c4 * 4] =
                *(const float4*)(We2 + (size_t)(kc * 4 + kr) * 1024 + c4 * 4);
        }
        __syncthreads();
#pragma unroll
        for (int kk = 0; kk < 4; ++kk) {
            const int k = kc * 4 + kk;
            const float z0 = zs[k][ep * 2], z1 = zs[k][ep * 2 + 1];
#pragma unroll
            for (int d = 0; d < 32; ++d) {
                const float4 w4 = *(const float4*)&ws2s[kk][d * 32 + fg * 4];
                const float c0 = z0 * hr[0][d], c1 = z1 * hr[1][d];
                acc[0][0] += c0 * w4.x; acc[0][1] += c0 * w4.y;
                acc[0][2] += c0 * w4.z; acc[0][3] += c0 * w4.w;
                acc[1][0] += c1 * w4.x; acc[1][1] += c1 * w4.y;
                acc[1][2] += c1 * w4.z; acc[1][3] += c1 * w4.w;
            }
        }
    }
#pragma unroll
    for (int i = 0; i < 2; ++i) {
        const int e = e0 + ep * 2 + i;
        float* ap = &agg[(size_t)dst[e] * D + fg * 4];
#pragma unroll
        for (int j = 0; j < 4; ++j) atomicAdd(ap + j, acc[i][j]);
    }
}

// -------- GRU cell per node; reads agg then re-zeroes it (replaces memsets)
__global__ __launch_bounds__(256) void k_gru(
    const float* __restrict__ h, float* __restrict__ agg,
    const float* __restrict__ Wroot, const float* __restrict__ bconv,
    const float* __restrict__ Wih, const float* __restrict__ Whh,
    const float* __restrict__ bih, const float* __restrict__ bhh,
    float* __restrict__ hout,
    unsigned short* __restrict__ hhi, unsigned short* __restrict__ hlo) {
    const int idx = blockIdx.x * 256 + threadIdx.x;
    const int n = idx >> 5, f = idx & 31, nl = threadIdx.x >> 5;
    __shared__ float hsh[8][33], msh[8][33];
    const float hv = h[n * D + f];
    hsh[nl][f] = hv;
    __syncthreads();
    float m = bconv[f] + agg[n * D + f];
    agg[n * D + f] = 0.f;  // re-zero for next msg step
#pragma unroll
    for (int d = 0; d < 32; ++d) m += hsh[nl][d] * Wroot[d * D + f];
    m = fmaxf(m, 0.f);
    msh[nl][f] = m;
    __syncthreads();
    float gir = bih[f], giz = bih[D + f], gin = bih[2 * D + f];
    float ghr = bhh[f], ghz = bhh[D + f], ghn = bhh[2 * D + f];
#pragma unroll
    for (int d = 0; d < 32; ++d) {
        const float md = msh[nl][d], hd = hsh[nl][d];
        gir += md * Wih[f * D + d];
        giz += md * Wih[(D + f) * D + d];
        gin += md * Wih[(2 * D + f) * D + d];
        ghr += hd * Whh[f * D + d];
        ghz += hd * Whh[(D + f) * D + d];
        ghn += hd * Whh[(2 * D + f) * D + d];
    }
    const float r = sigf(gir + ghr);
    const float z = sigf(giz + ghz);
    const float nn2 = tanhf(gin + r * ghn);
    const float ho = (1.f - z) * nn2 + z * hv;
    hout[n * D + f] = ho;
    if (hhi) {
        unsigned short hi, lo;
        split_bf16(ho, hi, lo);
        hhi[idx] = hi;
        hlo[idx] = lo;
    }
}

// -------- all 12 Set2Set steps in ONE kernel: block = graph, state in LDS
__global__ __launch_bounds__(256) void k_s2s_all(
    const float* __restrict__ h, const int* __restrict__ start,
    float* __restrict__ qstar_out,
    const float* __restrict__ Wih, const float* __restrict__ Whh,
    const float* __restrict__ bih, const float* __restrict__ bhh,
    float* __restrict__ ebuf) {
    const int b = blockIdx.x, t = threadIdx.x;
    __shared__ float qst[64], hls[32], cls[32], gates[128], qs[32];
    __shared__ float red[256];
    __shared__ float rsum[8][33];
    if (t < 64) qst[t] = 0.f;
    if (t < 32) { hls[t] = 0.f; cls[t] = 0.f; }
    const int s0 = start[b], s1 = start[b + 1];
    __syncthreads();

    for (int s = 0; s < S2S; ++s) {
        if (t < 128) {
            float g = bih[t] + bhh[t];
#pragma unroll 8
            for (int j = 0; j < 64; ++j) g += qst[j] * Wih[t * 64 + j];
#pragma unroll 8
            for (int j = 0; j < 32; ++j) g += hls[j] * Whh[t * 32 + j];
            gates[t] = g;
        }
        __syncthreads();
        if (t < 32) {  // i,f,g,o order
            const float ig = sigf(gates[t]);
            const float fg = sigf(gates[32 + t]);
            const float gg = tanhf(gates[64 + t]);
            const float og = sigf(gates[96 + t]);
            const float c = fg * cls[t] + ig * gg;
            const float q = og * tanhf(c);
            cls[t] = c;
            hls[t] = q;
            qst[t] = q;
            qs[t] = q;
        }
        __syncthreads();
        float lmax = -3.4e38f;
        for (int n = s0 + t; n < s1; n += 256) {
            const float4* hv = (const float4*)(h + (size_t)n * D);
            float e = 0.f;
#pragma unroll
            for (int u = 0; u < 8; ++u) {
                const float4 v = hv[u];
                e += v.x * qs[u * 4] + v.y * qs[u * 4 + 1] + v.z * qs[u * 4 + 2] + v.w * qs[u * 4 + 3];
            }
            ebuf[n] = e;
            lmax = fmaxf(lmax, e);
        }
        red[t] = lmax;
        __syncthreads();
        for (int r2 = 128; r2 > 0; r2 >>= 1) {
            if (t < r2) red[t] = fmaxf(red[t], red[t + r2]);
            __syncthreads();
        }
        const float smax = red[0];
        __syncthreads();
        float lsum = 0.f;
        for (int n = s0 + t; n < s1; n += 256) {
            const float w = expf(ebuf[n] - smax);
            ebuf[n] = w;
            lsum += w;
        }
        red[t] = lsum;
        __syncthreads();
        for (int r2 = 128; r2 > 0; r2 >>= 1) {
            if (t < r2) red[t] += red[t + r2];
            __syncthreads();
        }
        const float den = red[0];
        const float inv = (den > 0.f) ? 1.f / den : 0.f;
        const int fl = t & 31, sl = t >> 5;
        float racc = 0.f;
        for (int n = s0 + sl; n < s1; n += 8) racc += ebuf[n] * h[(size_t)n * D + fl];
        rsum[sl][fl] = racc;
        __syncthreads();
        if (sl == 0) {
            float rv = 0.f;
#pragma unroll
            for (int u = 0; u < 8; ++u) rv += rsum[u][fl];
            qst[32 + fl] = rv * inv;
        }
        __syncthreads();  // qst[32..63] visible before next gates phase
    }

    if (t < 64) qstar_out[b * 64 + t] = qst[t];
}

// -------- out = q_star @ W_out + b_out
__global__ void k_out(const float* __restrict__ qstar, const float* __restrict__ Wout,
                      const float* __restrict__ bout, float* __restrict__ out) {
    int b = threadIdx.x;
    if (b < NB) {
        float acc = bout[0];
#pragma unroll 8
        for (int j = 0; j < 64; ++j) acc += qstar[b * 64 + j] * Wout[j];
        out[b] = acc;
    }
}

extern "C" void kernel_launch(void* const* d_in, const int* in_sizes, int n_in,
                              void* d_out, int out_size, void* d_ws, size_t ws_size,
                              hipStream_t stream) {
    const float* x     = (const float*)d_in[0];
    const float* ed    = (const float*)d_in[3];
    const int*   edges = (const int*)d_in[4];
    const int*   batch = (const int*)d_in[5];
    const float* Wi    = (const float*)d_in[6];
    const float* bi    = (const float*)d_in[7];
    const float* We1   = (const float*)d_in[8];
    const float* be1   = (const float*)d_in[9];
    const float* We2   = (const float*)d_in[10];
    const float* be2   = (const float*)d_in[11];
    const float* Wroot = (const float*)d_in[12];
    const float* bconv = (const float*)d_in[13];
    const float* gWih  = (const float*)d_in[14];
    const float* gWhh  = (const float*)d_in[15];
    const float* gbih  = (const float*)d_in[16];
    const float* gbhh  = (const float*)d_in[17];
    const float* lWih  = (const float*)d_in[18];
    const float* lWhh  = (const float*)d_in[19];
    const float* lbih  = (const float*)d_in[20];
    const float* lbhh  = (const float*)d_in[21];
    const float* Wout  = (const float*)d_in[22];
    const float* bout  = (const float*)d_in[23];
    float* out = (float*)d_out;

    const int* srcp = edges;
    const int* dstp = edges + NE;

    char* ws = (char*)d_ws;
    size_t off = 0;
    auto alloc = [&](size_t bytes) -> char* {
        char* p = ws + off;
        off += (bytes + 255) & ~(size_t)255;
        return p;
    };
    float* hA    = (float*)alloc((size_t)NN * D * 4);
    float* hB    = (float*)alloc((size_t)NN * D * 4);
    float* agg   = (float*)alloc((size_t)NN * D * 4);
    float* ebuf  = (float*)alloc((size_t)NN * 4);
    float* qstar = (float*)alloc((size_t)NB * 64 * 4);
    int*   gst   = (int*)alloc((NB + 1) * 4);
    unsigned short* hhiA = (unsigned short*)alloc((size_t)NN * D * 2);
    unsigned short* hloA = (unsigned short*)alloc((size_t)NN * D * 2);
    unsigned short* hhiB = (unsigned short*)alloc((size_t)NN * D * 2);
    unsigned short* hloB = (unsigned short*)alloc((size_t)NN * D * 2);
    unsigned short* wth  = (unsigned short*)alloc((size_t)129 * 1024 * 2);
    unsigned short* wtl  = (unsigned short*)alloc((size_t)129 * 1024 * 2);
    const size_t base_off = off;
    const bool mfma_path = (ws_size >= base_off);
    // sorted-edge extras (~14 MB)
    int*   hist  = (int*)alloc((size_t)NN * 4);
    int*   offs  = (int*)alloc((size_t)NN * 4);
    int*   src_s = (int*)alloc((size_t)NE * 4);
    int*   dst_s = (int*)alloc((size_t)NE * 4);
    float* ed_s  = (float*)alloc((size_t)NE * 8 * 4);
    const bool mfma9_path = (ws_size >= off);

    hipLaunchKernelGGL(k_graph_start, dim3(1), dim3(128), 0, stream, batch, gst);
    hipLaunchKernelGGL(k_input_linear, dim3(NN * D / 256), dim3(256), 0, stream, x, Wi, bi, hA,
                       mfma_path ? hhiA : (unsigned short*)nullptr,
                       mfma_path ? hloA : (unsigned short*)nullptr);
    if (mfma_path)
        hipLaunchKernelGGL(k_prep_w, dim3((129 * 1024 + 255) / 256), dim3(256), 0, stream,
                           We2, be2, wth, wtl);
    if (mfma9_path) {
        hipMemsetAsync(hist, 0, (size_t)NN * 4, stream);
        hipLaunchKernelGGL(k_hist, dim3(NE / 256), dim3(256), 0, stream, dstp, hist);
        hipLaunchKernelGGL(k_scan, dim3(1), dim3(256), 0, stream, hist, offs);
        hipLaunchKernelGGL(k_scatter, dim3(NE / 256), dim3(256), 0, stream,
                           srcp, dstp, ed, offs, src_s, dst_s, ed_s);
    }
    hipMemsetAsync(agg, 0, (size_t)NN * D * 4, stream);  // once; k_gru re-zeroes

    float* hcur = hA;
    float* hnxt = hB;
    unsigned short *hhic = hhiA, *hloc = hloA, *hhin = hhiB, *hlon = hloB;
    for (int t = 0; t < TST; ++t) {
        if (mfma9_path)
            hipLaunchKernelGGL(k_msg_mfma9, dim3(NE / 256), dim3(256), 0, stream,
                               ed_s, We1, be1, wth, hhic, hloc, src_s, dst_s, agg);
        else if (mfma_path)
            hipLaunchKernelGGL(k_msg_mfma, dim3(NE / 64), dim3(256), 0, stream,
                               ed, We1, be1, wth, wtl, hhic, hloc, srcp, dstp, agg);
        else
            hipLaunchKernelGGL(k_msg_fused, dim3(NE / 64), dim3(256), 0, stream,
                               ed, We1, be1, We2, hcur, srcp, dstp, agg);
        hipLaunchKernelGGL(k_gru, dim3(NN * D / 256), dim3(256), 0, stream,
                           hcur, agg, Wroot, bconv, gWih, gWhh, gbih, gbhh, hnxt,
                           mfma_path ? hhin : (unsigned short*)nullptr,
                           mfma_path ? hlon : (unsigned short*)nullptr);
        float* tf = hcur; hcur = hnxt; hnxt = tf;
        unsigned short* ts;
        ts = hhic; hhic = hhin; hhin = ts;
        ts = hloc; hloc = hlon; hlon = ts;
    }

    hipLaunchKernelGGL(k_s2s_all, dim3(NB), dim3(256), 0, stream,
                       hcur, gst, qstar, lWih, lWhh, lbih, lbhh, ebuf);

    hipLaunchKernelGGL(k_out, dim3(1), dim3(64), 0, stream, qstar, Wout, bout, out);
    (void)in_sizes; (void)n_in; (void)out_size;
}

// Round 12
// 1733.707 us; speedup vs baseline: 2.6705x; 1.1155x over previous
//
#include <hip/hip_runtime.h>
#include <hip/hip_bf16.h>

#define NN 20000   // nodes
#define NE 320000  // edges
#define NB 64      // graphs
#define DIN 16
#define DE 8
#define HE 128
#define D 32
#define TST 8
#define S2S 12

typedef __attribute__((ext_vector_type(8))) short short8x;   // 8 bf16 = 4 VGPRs (MFMA A/B frag)
typedef __attribute__((ext_vector_type(4))) float f32x4;     // MFMA C/D frag

__device__ __forceinline__ float sigf(float x) { return 1.f / (1.f + expf(-x)); }

__device__ __forceinline__ void split_bf16(float x, unsigned short& hi, unsigned short& lo) {
    __hip_bfloat16 h = __float2bfloat16(x);
    hi = *(unsigned short*)&h;
    float r = x - __bfloat162float(h);
    __hip_bfloat16 l = __float2bfloat16(r);
    lo = *(unsigned short*)&l;
}

// XOR-swizzled element offset of an A-frag within a 1024-el k-row of Wt.
__device__ __forceinline__ int swz_off(int eidx, int quad, int tile) {
    const int u = eidx * 4 + quad;
    const int s = u ^ ((u >> 3) & 7);
    return tile * 512 + s * 8;
}

// -------- Wt[k][swz(f,d)] = We2[k][d*32+f] (k<128), row 128 = be2; hi/lo bf16
__global__ __launch_bounds__(256) void k_prep_w(
    const float* __restrict__ We2, const float* __restrict__ be2,
    unsigned short* __restrict__ wth, unsigned short* __restrict__ wtl) {
    int idx = blockIdx.x * 256 + threadIdx.x;
    if (idx >= 129 * 1024) return;
    int k = idx >> 10, rem = idx & 1023, f = rem >> 5, d = rem & 31;
    float v = (k < 128) ? We2[k * 1024 + d * 32 + f] : be2[d * 32 + f];
    unsigned short hi, lo;
    split_bf16(v, hi, lo);
    const int pos = k * 1024 + swz_off(f & 15, d >> 3, f >> 4) + (d & 7);
    wth[pos] = hi;
    wtl[pos] = lo;
}

// -------- counting sort of edges by dst
__global__ __launch_bounds__(256) void k_hist(const int* __restrict__ dst, int* __restrict__ hist) {
    const int e = blockIdx.x * 256 + threadIdx.x;
    atomicAdd(&hist[dst[e]], 1);
}

__global__ __launch_bounds__(256) void k_scan(const int* __restrict__ hist, int* __restrict__ offs) {
    __shared__ int part[256];
    const int tid = threadIdx.x;
    const int base = tid * 79;  // 256*79 = 20224 >= NN
    int s = 0;
    for (int i = 0; i < 79; ++i) {
        const int b = base + i;
        if (b < NN) s += hist[b];
    }
    part[tid] = s;
    __syncthreads();
    if (tid == 0) {
        int a = 0;
        for (int i = 0; i < 256; ++i) { const int v = part[i]; part[i] = a; a += v; }
    }
    __syncthreads();
    int a = part[tid];
    for (int i = 0; i < 79; ++i) {
        const int b = base + i;
        if (b < NN) { offs[b] = a; a += hist[b]; }
    }
}

__global__ __launch_bounds__(256) void k_scatter(
    const int* __restrict__ src, const int* __restrict__ dst, const float* __restrict__ ed,
    int* __restrict__ offs, int* __restrict__ src_s, int* __restrict__ dst_s,
    float* __restrict__ ed_s) {
    const int e = blockIdx.x * 256 + threadIdx.x;
    const int d = dst[e];
    const int pos = atomicAdd(&offs[d], 1);
    src_s[pos] = src[e];
    dst_s[pos] = d;
    const float4 a = *(const float4*)(ed + (size_t)e * 8);
    const float4 b = *(const float4*)(ed + (size_t)e * 8 + 4);
    *(float4*)(ed_s + (size_t)pos * 8) = a;
    *(float4*)(ed_s + (size_t)pos * 8 + 4) = b;
}

// -------- h0 = x @ W_in + b_in  (+ optional bf16 hi/lo split emit)
__global__ __launch_bounds__(256) void k_input_linear(
    const float* __restrict__ x, const float* __restrict__ Win,
    const float* __restrict__ bin, float* __restrict__ h,
    unsigned short* __restrict__ hhi, unsigned short* __restrict__ hlo) {
    int idx = blockIdx.x * 256 + threadIdx.x;
    int n = idx >> 5, f = idx & 31;
    float acc = bin[f];
#pragma unroll
    for (int d = 0; d < DIN; ++d) acc += x[n * DIN + d] * Win[d * D + f];
    h[idx] = acc;
    if (hhi) {
        unsigned short hi, lo;
        split_bf16(acc, hi, lo);
        hhi[idx] = hi;
        hlo[idx] = lo;
    }
}

// -------- MFMA msg v10: barrier-free K-loop, 1-PASS (W bf16 + h bf16-hi only).
// W frags direct from global (L2-hot, 4-deep ring, distance-3 prefetch); z per
// 8-k chunk in registers distributed via __shfl; 4 e-tiles x 1-pass = 8 MFMA
// per 2 loads. Sorted edges + wave-private LDS segmented-reduce epilogue.
__global__ __launch_bounds__(256, 4) void k_msg_mfma10(
    const float* __restrict__ ed_s, const float* __restrict__ We1,
    const float* __restrict__ be1,
    const unsigned short* __restrict__ wth,
    const unsigned short* __restrict__ hhi,
    const int* __restrict__ src_s, const int* __restrict__ dst_s,
    float* __restrict__ agg) {
    const int tid = threadIdx.x;
    const int e0 = blockIdx.x * 256;

    __shared__ float msgb[256 * 33];  // 33792 B, epilogue only
    __shared__ float we1s[DE * HE];   // 4 KB
    __shared__ float be1s[HE];
    __shared__ int dsl[256];

    const int lane = tid & 63;
    const int wv = tid >> 6;
    const int eidx = lane & 15;
    const int quad = lane >> 4;
    const int d0 = quad * 8;
    const int swz0 = swz_off(eidx, quad, 0);
    const int swz1 = swz_off(eidx, quad, 1);

    for (int i = tid; i < DE * HE; i += 256) we1s[i] = We1[i];
    if (tid < HE) be1s[tid] = be1[tid];
    dsl[tid] = dst_s[e0 + tid];

    // per-thread edge row (lane l of wave wv <-> edge e0 + wv*64 + l)
    const float4 ev0 = *(const float4*)(ed_s + (size_t)(e0 + tid) * 8);
    const float4 ev1 = *(const float4*)(ed_s + (size_t)(e0 + tid) * 8 + 4);
    float edr[8];
    edr[0] = ev0.x; edr[1] = ev0.y; edr[2] = ev0.z; edr[3] = ev0.w;
    edr[4] = ev1.x; edr[5] = ev1.y; edr[6] = ev1.z; edr[7] = ev1.w;

    // B-frags (h hi) for 4 e-tiles
    short8x bhi[4];
#pragma unroll
    for (int et = 0; et < 4; ++et) {
        const int e = e0 + wv * 64 + et * 16 + eidx;
        const size_t hb = (size_t)src_s[e] * 32 + d0;
        bhi[et] = *(const short8x*)(hhi + hb);
    }

    // 4-deep W-frag register ring, direct from global (L2-resident)
    short8x ring[4][2];
#define LDW(slot, kk)                                                  \
    do {                                                               \
        const unsigned short* _p = wth + ((size_t)(kk) << 10);         \
        ring[slot][0] = *(const short8x*)(_p + swz0);                  \
        ring[slot][1] = *(const short8x*)(_p + swz1);                  \
    } while (0)
    LDW(0, 0);
    LDW(1, 1);
    LDW(2, 2);

    f32x4 macc[4][2];
#pragma unroll
    for (int et = 0; et < 4; ++et) {
        macc[et][0] = (f32x4){0.f, 0.f, 0.f, 0.f};
        macc[et][1] = (f32x4){0.f, 0.f, 0.f, 0.f};
    }

    __syncthreads();  // we1s/be1s/dsl visible; ONLY barrier before epilogue

#pragma unroll 1
    for (int c = 0; c < 16; ++c) {
        // z for this chunk's 8 k, this lane's edge (exact fp32, same order)
        float zreg[8];
#pragma unroll
        for (int m = 0; m < 8; ++m) {
            const int k = c * 8 + m;
            float acc = be1s[k];
#pragma unroll
            for (int j = 0; j < 8; ++j) acc += edr[j] * we1s[j * HE + k];
            zreg[m] = fmaxf(acc, 0.f);
        }
#pragma unroll
        for (int m = 0; m < 8; ++m) {
            const int k = c * 8 + m;
            const int slot = m & 3;          // == k & 3 (8 ≡ 0 mod 4)
            const int pslot = (m + 3) & 3;
            int kn = k + 3;
            kn = (kn > 128) ? 128 : kn;
            LDW(pslot, kn);

            const short8x fh0 = ring[slot][0];
            const short8x fh1 = ring[slot][1];
#pragma unroll
            for (int et = 0; et < 4; ++et) {
                const float zk = __shfl(zreg[m], et * 16 + eidx);
                f32x4 t0 = {0.f, 0.f, 0.f, 0.f}, t1 = {0.f, 0.f, 0.f, 0.f};
                t0 = __builtin_amdgcn_mfma_f32_16x16x32_bf16(fh0, bhi[et], t0, 0, 0, 0);
                t1 = __builtin_amdgcn_mfma_f32_16x16x32_bf16(fh1, bhi[et], t1, 0, 0, 0);
                macc[et][0] += zk * t0;
                macc[et][1] += zk * t1;
            }
        }
    }

    {   // k = 128: be2 virtual row, z == 1; slot 0 holds k=128 (prefetched @k=125)
        const short8x fh0 = ring[0][0];
        const short8x fh1 = ring[0][1];
#pragma unroll
        for (int et = 0; et < 4; ++et) {
            f32x4 t0 = {0.f, 0.f, 0.f, 0.f}, t1 = {0.f, 0.f, 0.f, 0.f};
            t0 = __builtin_amdgcn_mfma_f32_16x16x32_bf16(fh0, bhi[et], t0, 0, 0, 0);
            t1 = __builtin_amdgcn_mfma_f32_16x16x32_bf16(fh1, bhi[et], t1, 0, 0, 0);
            macc[et][0] += t0;
            macc[et][1] += t1;
        }
    }
#undef LDW

    // epilogue: stash msg rows, segmented reduce over sorted dst
#pragma unroll
    for (int et = 0; et < 4; ++et) {
        const int eloc = wv * 64 + et * 16 + eidx;
        float* row = msgb + eloc * 33;
        row[quad * 4 + 0] = macc[et][0].x;
        row[quad * 4 + 1] = macc[et][0].y;
        row[quad * 4 + 2] = macc[et][0].z;
        row[quad * 4 + 3] = macc[et][0].w;
        row[16 + quad * 4 + 0] = macc[et][1].x;
        row[16 + quad * 4 + 1] = macc[et][1].y;
        row[16 + quad * 4 + 2] = macc[et][1].z;
        row[16 + quad * 4 + 3] = macc[et][1].w;
    }
    __syncthreads();

    const int g = tid >> 5, f = tid & 31;  // 8 groups x 32 edges each
    const int base = g * 32;
    float acc = 0.f;
    int cur = dsl[base];
    for (int i = 0; i < 32; ++i) {
        const int dnn = dsl[base + i];
        const float v = msgb[(base + i) * 33 + f];
        if (dnn != cur) {
            atomicAdd(&agg[(size_t)cur * 32 + f], acc);
            acc = 0.f;
            cur = dnn;
        }
        acc += v;
    }
    atomicAdd(&agg[(size_t)cur * 32 + f], acc);
}

// -------- MFMA msg v2 (fallback, base ws only): ring prefetch, z in regs, 3-pass
#define LDFRAG(slot, kk)                                          \
    do {                                                          \
        const unsigned short* _ph = wth + ((size_t)(kk) << 10);   \
        const unsigned short* _pl = wtl + ((size_t)(kk) << 10);   \
        ring[slot][0] = *(const short8x*)(_ph + b0);              \
        ring[slot][1] = *(const short8x*)(_ph + b1);              \
        ring[slot][2] = *(const short8x*)(_pl + b0);              \
        ring[slot][3] = *(const short8x*)(_pl + b1);              \
    } while (0)

__global__ __launch_bounds__(256) void k_msg_mfma(
    const float* __restrict__ ed, const float* __restrict__ We1,
    const float* __restrict__ be1,
    const unsigned short* __restrict__ wth, const unsigned short* __restrict__ wtl,
    const unsigned short* __restrict__ hhi, const unsigned short* __restrict__ hlo,
    const int* __restrict__ src, const int* __restrict__ dst,
    float* __restrict__ agg) {
    const int tid = threadIdx.x;
    const int e0 = blockIdx.x * 64;

    __shared__ float we1s[DE * HE];
    __shared__ float be1s[HE];

    for (int i = tid; i < DE * HE; i += 256) we1s[i] = We1[i];
    if (tid < HE) be1s[tid] = be1[tid];

    const int lane = tid & 63;
    const int wv = tid >> 6;
    const int eidx = lane & 15;
    const int quad = lane >> 4;
    const int eloc = wv * 16 + eidx;
    const int e = e0 + eloc;
    const int d0 = quad * 8;

    const int sn = src[e];
    const int dn = dst[e];

    const int b0 = swz_off(eidx, quad, 0);
    const int b1 = swz_off(eidx, quad, 1);

    const size_t hb = (size_t)sn * 32 + d0;
    const short8x bhi = *(const short8x*)(hhi + hb);
    const short8x blo = *(const short8x*)(hlo + hb);
    const float4 edv0 = *(const float4*)(ed + (size_t)e * 8);
    const float4 edv1 = *(const float4*)(ed + (size_t)e * 8 + 4);

    short8x ring[4][4];
    LDFRAG(0, 0);
    LDFRAG(1, 1);
    LDFRAG(2, 2);

    __syncthreads();

    float edr[8];
    edr[0] = edv0.x; edr[1] = edv0.y; edr[2] = edv0.z; edr[3] = edv0.w;
    edr[4] = edv1.x; edr[5] = edv1.y; edr[6] = edv1.z; edr[7] = edv1.w;
    float zreg[32];
#pragma unroll
    for (int m = 0; m < 32; ++m) {
        const int kk = (quad << 5) + m;
        float acc = be1s[kk];
#pragma unroll
        for (int j = 0; j < 8; ++j) acc += edr[j] * we1s[j * 128 + kk];
        zreg[m] = fmaxf(acc, 0.f);
    }

    f32x4 m0 = {0.f, 0.f, 0.f, 0.f}, m1 = {0.f, 0.f, 0.f, 0.f};

    for (int q = 0; q < 4; ++q) {
        const int bsrc = q * 16 + eidx;
#pragma unroll
        for (int m = 0; m < 32; ++m) {
            const int k = q * 32 + m;
            const int slot = m & 3;
            const int pslot = (m + 3) & 3;
            int kn = k + 3;
            kn = (kn > 128) ? 128 : kn;
            LDFRAG(pslot, kn);

            const float zk = __shfl(zreg[m], bsrc);

            f32x4 t0 = {0.f, 0.f, 0.f, 0.f}, t1 = {0.f, 0.f, 0.f, 0.f};
            t0 = __builtin_amdgcn_mfma_f32_16x16x32_bf16(ring[slot][0], bhi, t0, 0, 0, 0);
            t1 = __builtin_amdgcn_mfma_f32_16x16x32_bf16(ring[slot][1], bhi, t1, 0, 0, 0);
            t0 = __builtin_amdgcn_mfma_f32_16x16x32_bf16(ring[slot][2], bhi, t0, 0, 0, 0);
            t1 = __builtin_amdgcn_mfma_f32_16x16x32_bf16(ring[slot][3], bhi, t1, 0, 0, 0);
            t0 = __builtin_amdgcn_mfma_f32_16x16x32_bf16(ring[slot][0], blo, t0, 0, 0, 0);
            t1 = __builtin_amdgcn_mfma_f32_16x16x32_bf16(ring[slot][1], blo, t1, 0, 0, 0);

            m0 += zk * t0;
            m1 += zk * t1;
        }
    }
    {
        f32x4 t0 = {0.f, 0.f, 0.f, 0.f}, t1 = {0.f, 0.f, 0.f, 0.f};
        t0 = __builtin_amdgcn_mfma_f32_16x16x32_bf16(ring[0][0], bhi, t0, 0, 0, 0);
        t1 = __builtin_amdgcn_mfma_f32_16x16x32_bf16(ring[0][1], bhi, t1, 0, 0, 0);
        t0 = __builtin_amdgcn_mfma_f32_16x16x32_bf16(ring[0][2], bhi, t0, 0, 0, 0);
        t1 = __builtin_amdgcn_mfma_f32_16x16x32_bf16(ring[0][3], bhi, t1, 0, 0, 0);
        t0 = __builtin_amdgcn_mfma_f32_16x16x32_bf16(ring[0][0], blo, t0, 0, 0, 0);
        t1 = __builtin_amdgcn_mfma_f32_16x16x32_bf16(ring[0][1], blo, t1, 0, 0, 0);
        m0 += t0;
        m1 += t1;
    }

    float* ap = agg + (size_t)dn * 32 + quad * 4;
    atomicAdd(ap + 0, m0.x);
    atomicAdd(ap + 1, m0.y);
    atomicAdd(ap + 2, m0.z);
    atomicAdd(ap + 3, m0.w);
    atomicAdd(ap + 16 + 0, m1.x);
    atomicAdd(ap + 16 + 1, m1.y);
    atomicAdd(ap + 16 + 2, m1.z);
    atomicAdd(ap + 16 + 3, m1.w);
}

// -------- fallback (proven R2 path): recompute z per edge, fp32 VALU bilinear
__global__ __launch_bounds__(256) void k_msg_fused(
    const float* __restrict__ ed, const float* __restrict__ We1,
    const float* __restrict__ be1, const float* __restrict__ We2,
    const float* __restrict__ h, const int* __restrict__ src,
    const int* __restrict__ dst, float* __restrict__ agg) {
    const int tid = threadIdx.x;
    const int e0 = blockIdx.x * 64;
    __shared__ float we1s[DE * HE];
    __shared__ float be1s[HE];
    __shared__ float eds[64][9];
    __shared__ float zs[HE][64];
    __shared__ float hs[64][33];
    __shared__ float ws2s[4][1024];
    __shared__ int srcs[64];

    for (int i = tid; i < DE * HE; i += 256) we1s[i] = We1[i];
    if (tid < HE) be1s[tid] = be1[tid];
    if (tid < 64) srcs[tid] = src[e0 + tid];
    for (int i = tid; i < 64 * DE; i += 256) eds[i >> 3][i & 7] = ed[(size_t)e0 * DE + i];
    __syncthreads();

    {
        const int e = tid & 63, kb = tid >> 6;
        float edr[8];
#pragma unroll
        for (int j = 0; j < 8; ++j) edr[j] = eds[e][j];
        for (int m = 0; m < 32; ++m) {
            const int k = kb * 32 + m;
            float acc = be1s[k];
#pragma unroll
            for (int j = 0; j < 8; ++j) acc += edr[j] * we1s[j * HE + k];
            zs[k][e] = fmaxf(acc, 0.f);
        }
    }
    for (int i = tid; i < 64 * 32; i += 256) {
        const int e = i >> 5, d = i & 31;
        hs[e][d] = h[(size_t)srcs[e] * D + d];
    }
    __syncthreads();

    const int ep = tid & 31, fg = tid >> 5;
    float hr[2][32];
#pragma unroll
    for (int d = 0; d < 32; ++d) {
        hr[0][d] = hs[ep * 2][d];
        hr[1][d] = hs[ep * 2 + 1][d];
    }
    float acc[2][4];
#pragma unroll
    for (int i = 0; i < 2; ++i)
#pragma unroll
        for (int j = 0; j < 4; ++j) acc[i][j] = 0.f;

    for (int kc = 0; kc < 32; ++kc) {
        __syncthreads();
#pragma unroll
        for (int r = 0; r < 4; ++r) {
            const int idx4 = tid + 256 * r;
            const int kr = idx4 >> 8, c4 = idx4 & 255;
            *(float4*)&ws2s[kr][c4 * 4] =
                *(const float4*)(We2 + (size_t)(kc * 4 + kr) * 1024 + c4 * 4);
        }
        __syncthreads();
#pragma unroll
        for (int kk = 0; kk < 4; ++kk) {
            const int k = kc * 4 + kk;
            const float z0 = zs[k][ep * 2], z1 = zs[k][ep * 2 + 1];
#pragma unroll
            for (int d = 0; d < 32; ++d) {
                const float4 w4 = *(const float4*)&ws2s[kk][d * 32 + fg * 4];
                const float c0 = z0 * hr[0][d], c1 = z1 * hr[1][d];
                acc[0][0] += c0 * w4.x; acc[0][1] += c0 * w4.y;
                acc[0][2] += c0 * w4.z; acc[0][3] += c0 * w4.w;
                acc[1][0] += c1 * w4.x; acc[1][1] += c1 * w4.y;
                acc[1][2] += c1 * w4.z; acc[1][3] += c1 * w4.w;
            }
        }
    }
#pragma unroll
    for (int i = 0; i < 2; ++i) {
        const int e = e0 + ep * 2 + i;
        float* ap = &agg[(size_t)dst[e] * D + fg * 4];
#pragma unroll
        for (int j = 0; j < 4; ++j) atomicAdd(ap + j, acc[i][j]);
    }
}

// -------- GRU cell per node; reads agg then re-zeroes it (replaces memsets)
__global__ __launch_bounds__(256) void k_gru(
    const float* __restrict__ h, float* __restrict__ agg,
    const float* __restrict__ Wroot, const float* __restrict__ bconv,
    const float* __restrict__ Wih, const float* __restrict__ Whh,
    const float* __restrict__ bih, const float* __restrict__ bhh,
    float* __restrict__ hout,
    unsigned short* __restrict__ hhi, unsigned short* __restrict__ hlo) {
    const int idx = blockIdx.x * 256 + threadIdx.x;
    const int n = idx >> 5, f = idx & 31, nl = threadIdx.x >> 5;
    __shared__ float hsh[8][33], msh[8][33];
    const float hv = h[n * D + f];
    hsh[nl][f] = hv;
    __syncthreads();
    float m = bconv[f] + agg[n * D + f];
    agg[n * D + f] = 0.f;  // re-zero for next msg step
#pragma unroll
    for (int d = 0; d < 32; ++d) m += hsh[nl][d] * Wroot[d * D + f];
    m = fmaxf(m, 0.f);
    msh[nl][f] = m;
    __syncthreads();
    float gir = bih[f], giz = bih[D + f], gin = bih[2 * D + f];
    float ghr = bhh[f], ghz = bhh[D + f], ghn = bhh[2 * D + f];
#pragma unroll
    for (int d = 0; d < 32; ++d) {
        const float md = msh[nl][d], hd = hsh[nl][d];
        gir += md * Wih[f * D + d];
        giz += md * Wih[(D + f) * D + d];
        gin += md * Wih[(2 * D + f) * D + d];
        ghr += hd * Whh[f * D + d];
        ghz += hd * Whh[(D + f) * D + d];
        ghn += hd * Whh[(2 * D + f) * D + d];
    }
    const float r = sigf(gir + ghr);
    const float z = sigf(giz + ghz);
    const float nn2 = tanhf(gin + r * ghn);
    const float ho = (1.f - z) * nn2 + z * hv;
    hout[n * D + f] = ho;
    if (hhi) {
        unsigned short hi, lo;
        split_bf16(ho, hi, lo);
        hhi[idx] = hi;
        hlo[idx] = lo;
    }
}

// -------- all 12 Set2Set steps + output head in ONE kernel: block = graph
__global__ __launch_bounds__(256) void k_s2s_all(
    const float* __restrict__ h, const int* __restrict__ batch,
    const float* __restrict__ Wih, const float* __restrict__ Whh,
    const float* __restrict__ bih, const float* __restrict__ bhh,
    const float* __restrict__ Wout, const float* __restrict__ bout,
    float* __restrict__ ebuf, float* __restrict__ out) {
    const int b = blockIdx.x, t = threadIdx.x;
    __shared__ float qst[64], hls[32], cls[32], gates[128], qs[32];
    __shared__ float red[256];
    __shared__ float rsum[8][33];
    __shared__ int sse[2];
    if (t < 64) qst[t] = 0.f;
    if (t < 32) { hls[t] = 0.f; cls[t] = 0.f; }
    if (t < 2) {  // own graph segment via binary search on sorted batch
        const int target = b + t;
        int lo = 0, hi = NN;
        while (lo < hi) {
            int mid = (lo + hi) >> 1;
            if (batch[mid] < target) lo = mid + 1; else hi = mid;
        }
        sse[t] = lo;
    }
    __syncthreads();
    const int s0 = sse[0], s1 = sse[1];

    for (int s = 0; s < S2S; ++s) {
        if (t < 128) {
            float g = bih[t] + bhh[t];
#pragma unroll 8
            for (int j = 0; j < 64; ++j) g += qst[j] * Wih[t * 64 + j];
#pragma unroll 8
            for (int j = 0; j < 32; ++j) g += hls[j] * Whh[t * 32 + j];
            gates[t] = g;
        }
        __syncthreads();
        if (t < 32) {  // i,f,g,o order
            const float ig = sigf(gates[t]);
            const float fg = sigf(gates[32 + t]);
            const float gg = tanhf(gates[64 + t]);
            const float og = sigf(gates[96 + t]);
            const float c = fg * cls[t] + ig * gg;
            const float q = og * tanhf(c);
            cls[t] = c;
            hls[t] = q;
            qst[t] = q;
            qs[t] = q;
        }
        __syncthreads();
        float lmax = -3.4e38f;
        for (int n = s0 + t; n < s1; n += 256) {
            const float4* hv = (const float4*)(h + (size_t)n * D);
            float e = 0.f;
#pragma unroll
            for (int u = 0; u < 8; ++u) {
                const float4 v = hv[u];
                e += v.x * qs[u * 4] + v.y * qs[u * 4 + 1] + v.z * qs[u * 4 + 2] + v.w * qs[u * 4 + 3];
            }
            ebuf[n] = e;
            lmax = fmaxf(lmax, e);
        }
        red[t] = lmax;
        __syncthreads();
        for (int r2 = 128; r2 > 0; r2 >>= 1) {
            if (t < r2) red[t] = fmaxf(red[t], red[t + r2]);
            __syncthreads();
        }
        const float smax = red[0];
        __syncthreads();
        float lsum = 0.f;
        for (int n = s0 + t; n < s1; n += 256) {
            const float w = expf(ebuf[n] - smax);
            ebuf[n] = w;
            lsum += w;
        }
        red[t] = lsum;
        __syncthreads();
        for (int r2 = 128; r2 > 0; r2 >>= 1) {
            if (t < r2) red[t] += red[t + r2];
            __syncthreads();
        }
        const float den = red[0];
        const float inv = (den > 0.f) ? 1.f / den : 0.f;
        const int fl = t & 31, sl = t >> 5;
        float racc = 0.f;
        for (int n = s0 + sl; n < s1; n += 8) racc += ebuf[n] * h[(size_t)n * D + fl];
        rsum[sl][fl] = racc;
        __syncthreads();
        if (sl == 0) {
            float rv = 0.f;
#pragma unroll
            for (int u = 0; u < 8; ++u) rv += rsum[u][fl];
            qst[32 + fl] = rv * inv;
        }
        __syncthreads();  // qst[32..63] visible before next gates phase
    }

    if (t == 0) {  // fused output head
        float acc = bout[0];
#pragma unroll 8
        for (int j = 0; j < 64; ++j) acc += qst[j] * Wout[j];
        out[b] = acc;
    }
}

extern "C" void kernel_launch(void* const* d_in, const int* in_sizes, int n_in,
                              void* d_out, int out_size, void* d_ws, size_t ws_size,
                              hipStream_t stream) {
    const float* x     = (const float*)d_in[0];
    const float* ed    = (const float*)d_in[3];
    const int*   edges = (const int*)d_in[4];
    const int*   batch = (const int*)d_in[5];
    const float* Wi    = (const float*)d_in[6];
    const float* bi    = (const float*)d_in[7];
    const float* We1   = (const float*)d_in[8];
    const float* be1   = (const float*)d_in[9];
    const float* We2   = (const float*)d_in[10];
    const float* be2   = (const float*)d_in[11];
    const float* Wroot = (const float*)d_in[12];
    const float* bconv = (const float*)d_in[13];
    const float* gWih  = (const float*)d_in[14];
    const float* gWhh  = (const float*)d_in[15];
    const float* gbih  = (const float*)d_in[16];
    const float* gbhh  = (const float*)d_in[17];
    const float* lWih  = (const float*)d_in[18];
    const float* lWhh  = (const float*)d_in[19];
    const float* lbih  = (const float*)d_in[20];
    const float* lbhh  = (const float*)d_in[21];
    const float* Wout  = (const float*)d_in[22];
    const float* bout  = (const float*)d_in[23];
    float* out = (float*)d_out;

    const int* srcp = edges;
    const int* dstp = edges + NE;

    char* ws = (char*)d_ws;
    size_t off = 0;
    auto alloc = [&](size_t bytes) -> char* {
        char* p = ws + off;
        off += (bytes + 255) & ~(size_t)255;
        return p;
    };
    float* hA    = (float*)alloc((size_t)NN * D * 4);
    float* hB    = (float*)alloc((size_t)NN * D * 4);
    float* agg   = (float*)alloc((size_t)NN * D * 4);
    float* ebuf  = (float*)alloc((size_t)NN * 4);
    unsigned short* hhiA = (unsigned short*)alloc((size_t)NN * D * 2);
    unsigned short* hloA = (unsigned short*)alloc((size_t)NN * D * 2);
    unsigned short* hhiB = (unsigned short*)alloc((size_t)NN * D * 2);
    unsigned short* hloB = (unsigned short*)alloc((size_t)NN * D * 2);
    unsigned short* wth  = (unsigned short*)alloc((size_t)129 * 1024 * 2);
    unsigned short* wtl  = (unsigned short*)alloc((size_t)129 * 1024 * 2);
    const size_t base_off = off;
    const bool mfma_path = (ws_size >= base_off);
    // sorted-edge extras (~14 MB)
    int*   hist  = (int*)alloc((size_t)NN * 4);
    int*   offs  = (int*)alloc((size_t)NN * 4);
    int*   src_s = (int*)alloc((size_t)NE * 4);
    int*   dst_s = (int*)alloc((size_t)NE * 4);
    float* ed_s  = (float*)alloc((size_t)NE * 8 * 4);
    const bool mfma10_path = (ws_size >= off);

    hipLaunchKernelGGL(k_input_linear, dim3(NN * D / 256), dim3(256), 0, stream, x, Wi, bi, hA,
                       mfma_path ? hhiA : (unsigned short*)nullptr,
                       mfma_path ? hloA : (unsigned short*)nullptr);
    if (mfma_path)
        hipLaunchKernelGGL(k_prep_w, dim3((129 * 1024 + 255) / 256), dim3(256), 0, stream,
                           We2, be2, wth, wtl);
    if (mfma10_path) {
        hipMemsetAsync(hist, 0, (size_t)NN * 4, stream);
        hipLaunchKernelGGL(k_hist, dim3(NE / 256), dim3(256), 0, stream, dstp, hist);
        hipLaunchKernelGGL(k_scan, dim3(1), dim3(256), 0, stream, hist, offs);
        hipLaunchKernelGGL(k_scatter, dim3(NE / 256), dim3(256), 0, stream,
                           srcp, dstp, ed, offs, src_s, dst_s, ed_s);
    }
    hipMemsetAsync(agg, 0, (size_t)NN * D * 4, stream);  // once; k_gru re-zeroes

    float* hcur = hA;
    float* hnxt = hB;
    unsigned short *hhic = hhiA, *hloc = hloA, *hhin = hhiB, *hlon = hloB;
    for (int t = 0; t < TST; ++t) {
        if (mfma10_path)
            hipLaunchKernelGGL(k_msg_mfma10, dim3(NE / 256), dim3(256), 0, stream,
                               ed_s, We1, be1, wth, hhic, src_s, dst_s, agg);
        else if (mfma_path)
            hipLaunchKernelGGL(k_msg_mfma, dim3(NE / 64), dim3(256), 0, stream,
                               ed, We1, be1, wth, wtl, hhic, hloc, srcp, dstp, agg);
        else
            hipLaunchKernelGGL(k_msg_fused, dim3(NE / 64), dim3(256), 0, stream,
                               ed, We1, be1, We2, hcur, srcp, dstp, agg);
        hipLaunchKernelGGL(k_gru, dim3(NN * D / 256), dim3(256), 0, stream,
                           hcur, agg, Wroot, bconv, gWih, gWhh, gbih, gbhh, hnxt,
                           mfma_path ? hhin : (unsigned short*)nullptr,
                           mfma_path ? hlon : (unsigned short*)nullptr);
        float* tf = hcur; hcur = hnxt; hnxt = tf;
        unsigned short* ts;
        ts = hhic; hhic = hhin; hhin = ts;
        ts = hloc; hloc = hlon; hlon = ts;
    }

    hipLaunchKernelGGL(k_s2s_all, dim3(NB), dim3(256), 0, stream,
                       hcur, batch, lWih, lWhh, lbih, lbhh, Wout, bout, ebuf, out);
    (void)in_sizes; (void)n_in; (void)out_size;
}